// Round 12
// baseline (691.468 us; speedup 1.0000x reference)
//
#include <hip/hip_runtime.h>
#include <hip/hip_bf16.h>
#include <math.h>

#define N_NODES 16384
#define DIMV 1024
#define NHEADS 16
#define HEADD 64

typedef __attribute__((ext_vector_type(8))) short short8;
typedef __attribute__((ext_vector_type(4))) float f32x4;
typedef unsigned short ushort_t;

// async global->LDS, 16B per lane
#define GLD16(gptr, lptr)                                                                 \
  __builtin_amdgcn_global_load_lds((const __attribute__((address_space(1))) void*)(gptr), \
                                   (__attribute__((address_space(3))) void*)(lptr), 16, 0, 0)

// ---------- helpers ----------

__device__ __forceinline__ float waveReduceSum(float v) {
#pragma unroll
  for (int m = 32; m; m >>= 1) v += __shfl_xor(v, m);
  return v;
}

__device__ __forceinline__ float blockReduceSum(float v, float* red) {
  float w = waveReduceSum(v);
  __syncthreads();
  if ((threadIdx.x & 63) == 0) red[threadIdx.x >> 6] = w;
  __syncthreads();
  return red[0] + red[1] + red[2] + red[3];
}

__device__ __forceinline__ float elup1(float z) {
  return z > 0.0f ? z + 1.0f : expm1f(z) + 1.0f;
}

__device__ __forceinline__ float clampabs(float x, float eps) {
  float s = (x >= 0.0f) ? 1.0f : -1.0f;
  return s * fmaxf(fabsf(x), eps);
}

// fp32 -> bf16 bits, RNE
__device__ __forceinline__ ushort_t f2b(float x) {
  unsigned u = __float_as_uint(x);
  unsigned r = (u + 0x7FFFu + ((u >> 16) & 1u)) >> 16;
  return (ushort_t)r;
}
__device__ __forceinline__ float b2f(ushort_t h) {
  return __uint_as_float(((unsigned)h) << 16);
}

// ---------- X -> bf16 + row sumsq (one block per row) ----------
__global__ __launch_bounds__(256) void cvt_norm_kernel(const float* __restrict__ src,
                                                       ushort_t* __restrict__ dst,
                                                       float* __restrict__ rowsq) {
  __shared__ float red[4];
  const int row = blockIdx.x;
  const int t = threadIdx.x;
  float4 x4 = ((const float4*)(src + (size_t)row * DIMV))[t];
  ushort_t h[4] = {f2b(x4.x), f2b(x4.y), f2b(x4.z), f2b(x4.w)};
  ((uint2*)(dst + (size_t)row * DIMV))[t] = *(uint2*)h;
  float s = x4.x * x4.x + x4.y * x4.y + x4.z * x4.z + x4.w * x4.w;
  s = blockReduceSum(s, red);
  if (t == 0) rowsq[row] = s;
}

// ---------- weight transpose -> bf16 (hi, and optional lo residual) ----------
template <bool LO>
__global__ __launch_bounds__(256) void transW_kernel(const float* __restrict__ src,
                                                     ushort_t* __restrict__ hi,
                                                     ushort_t* __restrict__ lo) {
  __shared__ float tile[32][33];
  const int bx = blockIdx.x * 32, by = blockIdx.y * 32;
  const int tx = threadIdx.x & 31, ty = threadIdx.x >> 5;
#pragma unroll
  for (int i = 0; i < 32; i += 8) tile[ty + i][tx] = src[(size_t)(by + ty + i) * DIMV + bx + tx];
  __syncthreads();
#pragma unroll
  for (int i = 0; i < 32; i += 8) {
    float v = tile[tx][ty + i];
    ushort_t h = f2b(v);
    hi[(size_t)(bx + ty + i) * DIMV + by + tx] = h;
    if (LO) lo[(size_t)(bx + ty + i) * DIMV + by + tx] = f2b(v - b2f(h));
  }
}

// A-LDS k-unit swizzle (16B units within a 64B row, r8-verified):
// staging thread: src k-unit = (lane&3)^((lane>>3)&3); LDS dest linear.
// frag read: unit (lane>>4) of row (..+l15) at unit (lane>>4)^((lane>>1)&3) -> 2 lanes/bank.

// ---------- bf16 MFMA GEMM: 128x128, BK=32, 4 waves; A in LDS dbuf (16 KB), B DIRECT ----
// from global/L2 (weights are 2-4 MB, L2-resident per XCD -> staging them is pure overhead).
// B-frags prefetched one K-tile ahead in regs. 2-barrier loop (m97 structure).
// EPI 0: Cq = bf16(acc); EPI 3: QK fused (v1 / v2+v2sum). Coalesced epilogue via LDS.
template <int EPI, int NB>
__global__ __launch_bounds__(256) void gemm_bf(const ushort_t* __restrict__ A,
                                               const ushort_t* __restrict__ Bt,
                                               const float* __restrict__ biasQ,
                                               const float* __restrict__ biasK,
                                               const float* __restrict__ denom,
                                               const float* __restrict__ mask,
                                               float* __restrict__ v2sum,
                                               ushort_t* __restrict__ Cq,
                                               ushort_t* __restrict__ Ck) {
  __shared__ ushort_t LB[16384];  // 32 KB: A dbuf = first 16 KB; epilogue uses all 32 KB
  const int bid = blockIdx.x;
  const int nwg = NB * 128;
  const int swz = (bid & 7) * (nwg / 8) + (bid >> 3);
  const int bm = (swz / NB) * 128;
  const int bn = (swz % NB) * 128;
  const int t = threadIdx.x;
  const int w = t >> 6, lane = t & 63, l15 = lane & 15;
  const int wr = (w >> 1) * 64, wc = (w & 1) * 64;
  const int kk = (lane >> 4) * 8;                                  // B frag k-off (elems)
  const unsigned kswz = (((lane >> 4) ^ ((lane >> 1) & 3)) << 4);  // A frag unit byte off
  const int sksw = (((lane & 3) ^ ((lane >> 3) & 3)) << 3);        // staging src k (elems)

  // A staging: 8 chunks of 16 rows x 64B; wave w stages chunks w and w+4 (2 GLD16/tile).
  const ushort_t* gA0 = A + (size_t)(bm + w * 16 + (lane >> 2)) * DIMV + sksw;
  const ushort_t* gA1 = A + (size_t)(bm + (w + 4) * 16 + (lane >> 2)) * DIMV + sksw;
  char* lA0 = (char*)LB + w * 1024 + lane * 16;
  char* lA1 = (char*)LB + (w + 4) * 1024 + lane * 16;

  // B fragment pointers: direct global (k-contiguous 16B/lane; 16 x 64B segments per load)
  const ushort_t* gB[4];
#pragma unroll
  for (int j = 0; j < 4; ++j) gB[j] = Bt + (size_t)(bn + wc + j * 16 + l15) * DIMV + kk;

  f32x4 acc[4][4];
#pragma unroll
  for (int i = 0; i < 4; ++i)
#pragma unroll
    for (int j = 0; j < 4; ++j) acc[i][j] = (f32x4){0.f, 0.f, 0.f, 0.f};

  // prologue
  GLD16(gA0, lA0);
  GLD16(gA1, lA1);
  short8 bcur[4], bnext[4];
#pragma unroll
  for (int j = 0; j < 4; ++j) bcur[j] = *(const short8*)(gB[j]);
  __syncthreads();

  int buf = 0;
  for (int kt = 0; kt < 32; ++kt) {
    const int k0 = kt * 32;
    if (kt < 31) {
      GLD16(gA0 + k0 + 32, lA0 + (buf ^ 1) * 8192);
      GLD16(gA1 + k0 + 32, lA1 + (buf ^ 1) * 8192);
#pragma unroll
      for (int j = 0; j < 4; ++j) bnext[j] = *(const short8*)(gB[j] + k0 + 32);
    }
    short8 af[4];
#pragma unroll
    for (int f = 0; f < 4; ++f)
      af[f] = *(const short8*)((char*)LB + buf * 8192 + (wr + f * 16 + l15) * 64 + kswz);
#pragma unroll
    for (int i = 0; i < 4; ++i)
#pragma unroll
      for (int j = 0; j < 4; ++j)
        acc[i][j] = __builtin_amdgcn_mfma_f32_16x16x32_bf16(af[i], bcur[j], acc[i][j], 0, 0, 0);
    __syncthreads();  // publishes next A buf; drains stage + bnext (covered by MFMA burst)
    if (kt < 31) {
#pragma unroll
      for (int j = 0; j < 4; ++j) bcur[j] = bnext[j];
    }
    buf ^= 1;
  }

  // ---- epilogue: math -> LDS [128][128] bf16 -> coalesced global stores ----
  const int rbase = (lane >> 4) * 4;
  const bool isK = (EPI == 3) && (bn >= DIMV);
  const int h = ((bn + wc) >> 6) & (NHEADS - 1);
  ushort_t* dst = (EPI == 3 && isK) ? Ck : Cq;
  const int coloff = (EPI == 3) ? (bn & (DIMV - 1)) : bn;
  float bb[4];
#pragma unroll
  for (int j = 0; j < 4; ++j)
    bb[j] = (EPI == 3) ? (isK ? biasK[(bn + wc + j * 16 + l15) & (DIMV - 1)]
                              : biasQ[(bn + wc + j * 16 + l15) & (DIMV - 1)])
                       : 0.0f;
  float csum[4] = {0.f, 0.f, 0.f, 0.f};
#pragma unroll
  for (int i = 0; i < 4; ++i) {
#pragma unroll
    for (int r = 0; r < 4; ++r) {
      const int row_l = wr + i * 16 + rbase + r;
      float invdp = 1.0f, den = 0.f, mk = 0.f;
      if (EPI == 3) {
        invdp = 1.0f / denom[(size_t)h * N_NODES + bm + row_l];
        if (isK) {
          den = clampabs(2.0f * invdp - 1.0f, 1e-10f);
          mk = mask[bm + row_l];
        }
      }
#pragma unroll
      for (int j = 0; j < 4; ++j) {
        float val = acc[i][j][r];
        if (EPI == 3) {
          val = elup1((val + bb[j]) * invdp);
          if (isK) {
            val = den * val * mk;
            csum[j] += val;
          }
        }
        LB[row_l * 128 + wc + j * 16 + l15] = f2b(val);
      }
    }
  }
  __syncthreads();
#pragma unroll
  for (int it = 0; it < 8; ++it) {
    const int idx = it * 256 + t;
    const int row_l = idx >> 4, cq = idx & 15;
    uint4 v = *(const uint4*)&LB[row_l * 128 + cq * 8];
    *(uint4*)(dst + (size_t)(bm + row_l) * DIMV + coloff + cq * 8) = v;
  }
  if (EPI == 3 && isK) {
#pragma unroll
    for (int j = 0; j < 4; ++j)
      atomicAdd(&v2sum[(bn + wc + j * 16 + l15) & (DIMV - 1)], csum[j]);
  }
}

// ---------- fused 3-term split GEMM: C = bf16(AhiBhi + AloBhi + AhiBlo) ----------
// 128x128, BK=32, 4 waves; A (combHi/Lo) staged in 32 KB LDS dbuf; B (WffHi/Lo) direct
// from global/L2. MFMA-dense (48 MFMA/wave/tile) so same-iteration B loads suffice.
__global__ __launch_bounds__(256) void gemm_split3(const ushort_t* __restrict__ Ahi,
                                                   const ushort_t* __restrict__ Alo,
                                                   const ushort_t* __restrict__ Bhi,
                                                   const ushort_t* __restrict__ Blo,
                                                   ushort_t* __restrict__ C) {
  __shared__ ushort_t LB[16384];  // 32 KB: buf b at b*16KB: AH [0,8K), AL [8K,16K)
  const int bid = blockIdx.x;
  const int swz = (bid & 7) * 128 + (bid >> 3);  // nwg = 1024
  const int bm = (swz >> 3) * 128;
  const int bn = (swz & 7) * 128;
  const int t = threadIdx.x;
  const int w = t >> 6, lane = t & 63, l15 = lane & 15;
  const int wr = (w >> 1) * 64, wc = (w & 1) * 64;
  const int kk = (lane >> 4) * 8;
  const unsigned kswz = (((lane >> 4) ^ ((lane >> 1) & 3)) << 4);
  const int sksw = (((lane & 3) ^ ((lane >> 3) & 3)) << 3);

  const size_t goA0 = (size_t)(bm + w * 16 + (lane >> 2)) * DIMV + sksw;
  const size_t goA1 = (size_t)(bm + (w + 4) * 16 + (lane >> 2)) * DIMV + sksw;
  char* lH0 = (char*)LB + w * 1024 + lane * 16;
  char* lH1 = (char*)LB + (w + 4) * 1024 + lane * 16;
  char* lL0 = lH0 + 8192;
  char* lL1 = lH1 + 8192;

  const ushort_t *gBH[4], *gBL[4];
#pragma unroll
  for (int j = 0; j < 4; ++j) {
    gBH[j] = Bhi + (size_t)(bn + wc + j * 16 + l15) * DIMV + kk;
    gBL[j] = Blo + (size_t)(bn + wc + j * 16 + l15) * DIMV + kk;
  }

  f32x4 acc[4][4];
#pragma unroll
  for (int i = 0; i < 4; ++i)
#pragma unroll
    for (int j = 0; j < 4; ++j) acc[i][j] = (f32x4){0.f, 0.f, 0.f, 0.f};

  GLD16(Ahi + goA0, lH0);
  GLD16(Ahi + goA1, lH1);
  GLD16(Alo + goA0, lL0);
  GLD16(Alo + goA1, lL1);
  __syncthreads();

  int buf = 0;
  for (int kt = 0; kt < 32; ++kt) {
    const int k0 = kt * 32;
    if (kt < 31) {
      const int bo = (buf ^ 1) * 16384;
      GLD16(Ahi + goA0 + k0 + 32, lH0 + bo);
      GLD16(Ahi + goA1 + k0 + 32, lH1 + bo);
      GLD16(Alo + goA0 + k0 + 32, lL0 + bo);
      GLD16(Alo + goA1 + k0 + 32, lL1 + bo);
    }
    short8 bH[4], bL[4];
#pragma unroll
    for (int j = 0; j < 4; ++j) {
      bH[j] = *(const short8*)(gBH[j] + k0);
      bL[j] = *(const short8*)(gBL[j] + k0);
    }
    short8 aH[4], aL[4];
#pragma unroll
    for (int f = 0; f < 4; ++f) {
      aH[f] = *(const short8*)((char*)LB + buf * 16384 + (wr + f * 16 + l15) * 64 + kswz);
      aL[f] = *(const short8*)((char*)LB + buf * 16384 + 8192 + (wr + f * 16 + l15) * 64 + kswz);
    }
#pragma unroll
    for (int i = 0; i < 4; ++i)
#pragma unroll
      for (int j = 0; j < 4; ++j) {
        acc[i][j] = __builtin_amdgcn_mfma_f32_16x16x32_bf16(aH[i], bH[j], acc[i][j], 0, 0, 0);
        acc[i][j] = __builtin_amdgcn_mfma_f32_16x16x32_bf16(aL[i], bH[j], acc[i][j], 0, 0, 0);
        acc[i][j] = __builtin_amdgcn_mfma_f32_16x16x32_bf16(aH[i], bL[j], acc[i][j], 0, 0, 0);
      }
    __syncthreads();
    buf ^= 1;
  }

  // coalesced epilogue via LDS [128][128]
  const int rbase = (lane >> 4) * 4;
#pragma unroll
  for (int i = 0; i < 4; ++i)
#pragma unroll
    for (int r = 0; r < 4; ++r) {
      const int row_l = wr + i * 16 + rbase + r;
#pragma unroll
      for (int j = 0; j < 4; ++j) LB[row_l * 128 + wc + j * 16 + l15] = f2b(acc[i][j][r]);
    }
  __syncthreads();
#pragma unroll
  for (int it = 0; it < 8; ++it) {
    const int idx = it * 256 + t;
    const int row_l = idx >> 4, cq = idx & 15;
    uint4 v = *(const uint4*)&LB[row_l * 128 + cq * 8];
    *(uint4*)(C + (size_t)(bm + row_l) * DIMV + bn + cq * 8) = v;
  }
}

// ---------- row transform: mobius_matvec tail + kappa_relu (bf16 msrc, precomputed ||x||^2) ----------
template <bool BFDST>
__global__ __launch_bounds__(256) void rowtrans_kernel(const ushort_t* __restrict__ msrc,
                                                       const float* __restrict__ rowsq,
                                                       void* __restrict__ dstv,
                                                       float* __restrict__ denom) {
  __shared__ float red[4];
  __shared__ float orow[DIMV];
  const int row = blockIdx.x;
  const int t = threadIdx.x;
  uint2 mraw = ((const uint2*)(msrc + (size_t)row * DIMV))[t];
  ushort_t* mh = (ushort_t*)&mraw;
  float4 m4 = make_float4(b2f(mh[0]), b2f(mh[1]), b2f(mh[2]), b2f(mh[3]));
  float sm = m4.x * m4.x + m4.y * m4.y + m4.z * m4.z + m4.w * m4.w;
  sm = blockReduceSum(sm, red);
  float sx = rowsq[row];

  float xn = fmaxf(sqrtf(sx), 1e-15f);
  float mxn = fmaxf(sqrtf(sm), 1e-15f);
  float cx = fminf(xn, 1.0f - 1e-7f);
  float t1 = tanhf(mxn / xn * atanhf(cx));
  float s1 = t1 / mxn;

  float yn = fmaxf(fabsf(t1), 1e-15f);
  float a = atanhf(fminf(yn, 1.0f - 1e-7f)) / yn;
  float k1 = a * s1;
  float4 u = make_float4(fmaxf(k1 * m4.x, 0.0f), fmaxf(k1 * m4.y, 0.0f),
                         fmaxf(k1 * m4.z, 0.0f), fmaxf(k1 * m4.w, 0.0f));
  float su = u.x * u.x + u.y * u.y + u.z * u.z + u.w * u.w;
  su = blockReduceSum(su, red);

  float un = fmaxf(sqrtf(su), 1e-15f);
  float t2 = tanhf(un);
  float s2 = t2 / un;
  if (t2 > 0.996f) s2 *= 0.996f / t2;
  float4 o = make_float4(s2 * u.x, s2 * u.y, s2 * u.z, s2 * u.w);
  if (BFDST) {
    ushort_t h[4] = {f2b(o.x), f2b(o.y), f2b(o.z), f2b(o.w)};
    ((uint2*)((ushort_t*)dstv + (size_t)row * DIMV))[t] = *(uint2*)h;
  } else {
    ((float4*)((float*)dstv + (size_t)row * DIMV))[t] = o;
  }

  if (denom) {
    ((float4*)orow)[t] = o;
    __syncthreads();
    if (t < NHEADS) {
      float s = 0.0f;
#pragma unroll
      for (int i = 0; i < HEADD; ++i) {
        float v = orow[t * HEADD + i];
        s = fmaf(v, v, s);
      }
      denom[t * N_NODES + row] = fmaxf(1.0f - s, 1e-15f);
    }
  }
}

// ---------- ctxT[h][e][d] = sum_n v2[h,n,d] * (gamma/den * mask * V)[h,n,e]  (v2,V bf16) ----------
__global__ __launch_bounds__(256) void context_kernel(const ushort_t* __restrict__ v2buf,
                                                      const ushort_t* __restrict__ vbuf,
                                                      const float* __restrict__ denom,
                                                      const float* __restrict__ mask,
                                                      float* __restrict__ ctxT) {
  __shared__ float s2[64][65];
  __shared__ float sx[64][65];
  const int h = blockIdx.y;
  const int t = threadIdx.x;
  const int d0 = (t >> 4) * 4;
  const int e0 = (t & 15) * 4;
  float acc[4][4];
#pragma unroll
  for (int i = 0; i < 4; ++i)
#pragma unroll
    for (int j = 0; j < 4; ++j) acc[i][j] = 0.0f;

  const int rbase = blockIdx.x * 512;
  for (int c = 0; c < 8; ++c) {
#pragma unroll
    for (int i = 0; i < 4; ++i) {
      int f = i * 256 + t;
      int r = f >> 4;
      int cc = (f & 15) * 4;
      int row = rbase + c * 64 + r;
      uint2 araw = *(const uint2*)(v2buf + (size_t)row * DIMV + h * HEADD + cc);
      ushort_t* ah = (ushort_t*)&araw;
      s2[r][cc + 0] = b2f(ah[0]); s2[r][cc + 1] = b2f(ah[1]);
      s2[r][cc + 2] = b2f(ah[2]); s2[r][cc + 3] = b2f(ah[3]);
      float dp = denom[(size_t)h * N_NODES + row];
      float gamma = 2.0f / dp;
      float den = clampabs(gamma - 1.0f, 1e-10f);
      float c1 = gamma / den * mask[row];
      uint2 braw = *(const uint2*)(vbuf + (size_t)row * DIMV + h * HEADD + cc);
      ushort_t* bh = (ushort_t*)&braw;
      sx[r][cc + 0] = c1 * b2f(bh[0]); sx[r][cc + 1] = c1 * b2f(bh[1]);
      sx[r][cc + 2] = c1 * b2f(bh[2]); sx[r][cc + 3] = c1 * b2f(bh[3]);
    }
    __syncthreads();
    for (int r = 0; r < 64; ++r) {
      float av[4], bv[4];
#pragma unroll
      for (int i = 0; i < 4; ++i) av[i] = s2[r][d0 + i];
#pragma unroll
      for (int j = 0; j < 4; ++j) bv[j] = sx[r][e0 + j];
#pragma unroll
      for (int i = 0; i < 4; ++i)
#pragma unroll
        for (int j = 0; j < 4; ++j) acc[i][j] = fmaf(av[i], bv[j], acc[i][j]);
    }
    __syncthreads();
  }
#pragma unroll
  for (int i = 0; i < 4; ++i)
#pragma unroll
    for (int j = 0; j < 4; ++j)
      atomicAdd(&ctxT[h * 4096 + (e0 + j) * 64 + (d0 + i)], acc[i][j]);
}

// ---------- out (MFMA): [out|D] = v1 @ [ctx|v2sum]; tail; emit combHi/Lo + rownorm atomics ----------
__global__ __launch_bounds__(256) void out_mfma_kernel(const ushort_t* __restrict__ v1bf,
                                                       const float* __restrict__ v2sum,
                                                       const float* __restrict__ ctxT,
                                                       ushort_t* __restrict__ combHi,
                                                       ushort_t* __restrict__ combLo,
                                                       float* __restrict__ combnorm) {
  __shared__ ushort_t Blds[80][88];
  const int h = blockIdx.y;
  const int bm = blockIdx.x * 256;
  const int t = threadIdx.x;
  const int w = t >> 6, lane = t & 63, l15 = lane & 15;
  const int kk = (lane >> 4) * 8;

  for (int idx = t; idx < 80 * 64; idx += 256) {
    int e = idx >> 6, d = idx & 63;
    float v = 0.0f;
    if (e < 64) v = ctxT[h * 4096 + e * 64 + d];
    else if (e == 64) v = v2sum[h * 64 + d];
    Blds[e][d] = f2b(v);
  }
  __syncthreads();

  f32x4 acc[4][5];
#pragma unroll
  for (int i = 0; i < 4; ++i)
#pragma unroll
    for (int j = 0; j < 5; ++j) acc[i][j] = (f32x4){0.f, 0.f, 0.f, 0.f};
#pragma unroll
  for (int ks = 0; ks < 2; ++ks) {
    short8 bfr[5];
#pragma unroll
    for (int j = 0; j < 5; ++j) bfr[j] = *(const short8*)&Blds[j * 16 + l15][ks * 32 + kk];
#pragma unroll
    for (int i = 0; i < 4; ++i) {
      short8 af = *(const short8*)(v1bf + (size_t)(bm + w * 64 + i * 16 + l15) * DIMV +
                                   h * HEADD + ks * 32 + kk);
#pragma unroll
      for (int j = 0; j < 5; ++j)
        acc[i][j] = __builtin_amdgcn_mfma_f32_16x16x32_bf16(af, bfr[j], acc[i][j], 0, 0, 0);
    }
  }

  const int g4 = (lane >> 4) * 4;
#pragma unroll
  for (int i = 0; i < 4; ++i) {
#pragma unroll
    for (int r = 0; r < 4; ++r) {
      const int row = bm + w * 64 + i * 16 + g4 + r;
      float D = __shfl(acc[i][4][r], lane & 48);
      float Dinv = 1.0f / (D == 0.0f ? 1e-5f : D);
      float o[4];
      float s = 0.0f;
#pragma unroll
      for (int j = 0; j < 4; ++j) {
        o[j] = acc[i][j][r] * Dinv;
        s = fmaf(o[j], o[j], s);
      }
      s += __shfl_xor(s, 1); s += __shfl_xor(s, 2);
      s += __shfl_xor(s, 4); s += __shfl_xor(s, 8);
      float n1 = fmaxf(sqrtf(s), 1e-15f);
      float sc = 1.0f;
      if (n1 > 0.996f) sc = 0.996f / n1;
      float xn = fmaxf(fminf(n1, 0.996f), 1e-15f);
      float cx = fminf(xn, 1.0f - 1e-7f);
      float t2 = tanhf(0.5f * atanhf(cx));
      sc *= t2 / xn;
      if (t2 > 0.996f) sc *= 0.996f / t2;
      if (l15 == 0) atomicAdd(&combnorm[row], s * sc * sc);
#pragma unroll
      for (int j = 0; j < 4; ++j) {
        float ov = o[j] * sc;
        size_t off = (size_t)row * DIMV + h * HEADD + j * 16 + l15;
        ushort_t hi = f2b(ov);
        combHi[off] = hi;
        combLo[off] = f2b(ov - b2f(hi));
      }
    }
  }
}

// ---------- launch ----------

extern "C" void kernel_launch(void* const* d_in, const int* in_sizes, int n_in,
                              void* d_out, int out_size, void* d_ws, size_t ws_size,
                              hipStream_t stream) {
  const float* X = (const float*)d_in[0];
  const float* mask = (const float*)d_in[1];
  const float* Wq = (const float*)d_in[2];
  const float* bq = (const float*)d_in[3];
  const float* Wk = (const float*)d_in[4];
  const float* bk = (const float*)d_in[5];
  const float* Wv = (const float*)d_in[6];
  const float* Wff = (const float*)d_in[7];
  float* out = (float*)d_out;

  const size_t MAT = (size_t)N_NODES * DIMV;
  char* p = (char*)d_ws;
  // R1 (64MB): first half v1bf (QK epi out); second half mxV bf16, later combnorm
  ushort_t* v1bf = (ushort_t*)p;
  ushort_t* mxV = (ushort_t*)(p + MAT * 2);
  float* combnorm = (float*)(p + MAT * 2);
  p += MAT * 4;
  // R2 (64MB): xnormsq (early) / v2bf (QK epi out) / combHi+combLo (after context)
  float* xnormsq = (float*)p;
  ushort_t* v2bf = (ushort_t*)p;
  ushort_t* combHi = (ushort_t*)p;
  ushort_t* combLo = combHi + MAT;
  p += MAT * 4;
  // R3 (32MB): Vbf; later WffHi/WffLo
  ushort_t* Vbf = (ushort_t*)p;
  ushort_t* WffHi = Vbf;
  ushort_t* WffLo = Vbf + (size_t)DIMV * DIMV;
  p += MAT * 2;
  // R4 (32MB): Xbf; later outBf (split3 out)
  ushort_t* Xbf = (ushort_t*)p;
  ushort_t* outBf = Xbf;
  p += MAT * 2;
  float* denom = (float*)p;  p += (size_t)NHEADS * N_NODES * 4;
  float* v2sum = (float*)p;  p += 1024 * 4;
  float* ctxT = (float*)p;   p += (size_t)NHEADS * 4096 * 4;
  const size_t need = (size_t)(p - (char*)d_ws);
  if (ws_size < need) return;

  // W^T bf16 scratch inside d_out (free until the final rowtrans writes it):
  ushort_t* Wt = (ushort_t*)d_out;            // Wv^T, later Wq^T (rows 0..1023)
  ushort_t* WtK = Wt + (size_t)DIMV * DIMV;   // Wk^T (rows 1024..2047 of stacked QK)

  dim3 tgrid(32, 32);

  cvt_norm_kernel<<<N_NODES, 256, 0, stream>>>(X, Xbf, xnormsq);
  // V path: mxV bf16, then rowtrans -> Vbf + denom
  transW_kernel<false><<<tgrid, 256, 0, stream>>>(Wv, Wt, nullptr);
  gemm_bf<0, 8><<<1024, 256, 0, stream>>>(Xbf, Wt, nullptr, nullptr, nullptr, nullptr,
                                          nullptr, mxV, nullptr);
  rowtrans_kernel<true><<<N_NODES, 256, 0, stream>>>(mxV, xnormsq, Vbf, denom);
  // zero accumulators (v2sum+ctxT contiguous; combnorm over dead mxV)
  hipMemsetAsync(v2sum, 0, (1024 + 4096 * NHEADS) * sizeof(float), stream);
  hipMemsetAsync(combnorm, 0, N_NODES * sizeof(float), stream);
  // QK fused: stacked [Wq^T; Wk^T], epilogue emits v1 (cols<1024) and v2 + v2sum (cols>=1024)
  transW_kernel<false><<<tgrid, 256, 0, stream>>>(Wq, Wt, nullptr);
  transW_kernel<false><<<tgrid, 256, 0, stream>>>(Wk, WtK, nullptr);
  gemm_bf<3, 16><<<2048, 256, 0, stream>>>(Xbf, Wt, bq, bk, denom, mask, v2sum, v1bf, v2bf);
  // context (transposed output)
  context_kernel<<<dim3(32, NHEADS), 256, 0, stream>>>(v2bf, Vbf, denom, mask, ctxT);
  // attention out -> combHi/Lo + row norms
  out_mfma_kernel<<<dim3(N_NODES / 256, NHEADS), 256, 0, stream>>>(v1bf, v2sum, ctxT, combHi,
                                                                   combLo, combnorm);
  // final: fused 3-term split GEMM -> outBf, then rowtrans -> d_out
  transW_kernel<true><<<tgrid, 256, 0, stream>>>(Wff, WffHi, WffLo);
  gemm_split3<<<1024, 256, 0, stream>>>(combHi, combLo, WffHi, WffLo, outBf);
  rowtrans_kernel<false><<<N_NODES, 256, 0, stream>>>(outBf, combnorm, out, nullptr);
}

// Round 13
// 472.473 us; speedup vs baseline: 1.4635x; 1.4635x over previous
//
#include <hip/hip_runtime.h>
#include <hip/hip_bf16.h>
#include <math.h>

#define N_NODES 16384
#define DIMV 1024
#define NHEADS 16
#define HEADD 64

typedef __attribute__((ext_vector_type(8))) short short8;
typedef __attribute__((ext_vector_type(4))) float f32x4;
typedef unsigned short ushort_t;

// async global->LDS, 16B per lane
#define GLD16(gptr, lptr)                                                                 \
  __builtin_amdgcn_global_load_lds((const __attribute__((address_space(1))) void*)(gptr), \
                                   (__attribute__((address_space(3))) void*)(lptr), 16, 0, 0)

// ---------- helpers ----------

__device__ __forceinline__ float waveReduceSum(float v) {
#pragma unroll
  for (int m = 32; m; m >>= 1) v += __shfl_xor(v, m);
  return v;
}

__device__ __forceinline__ float blockReduceSum(float v, float* red) {
  float w = waveReduceSum(v);
  __syncthreads();
  if ((threadIdx.x & 63) == 0) red[threadIdx.x >> 6] = w;
  __syncthreads();
  return red[0] + red[1] + red[2] + red[3];
}

__device__ __forceinline__ float elup1(float z) {
  return z > 0.0f ? z + 1.0f : expm1f(z) + 1.0f;
}

__device__ __forceinline__ float clampabs(float x, float eps) {
  float s = (x >= 0.0f) ? 1.0f : -1.0f;
  return s * fmaxf(fabsf(x), eps);
}

// fp32 -> bf16 bits, RNE
__device__ __forceinline__ ushort_t f2b(float x) {
  unsigned u = __float_as_uint(x);
  unsigned r = (u + 0x7FFFu + ((u >> 16) & 1u)) >> 16;
  return (ushort_t)r;
}
__device__ __forceinline__ float b2f(ushort_t h) {
  return __uint_as_float(((unsigned)h) << 16);
}

// ---------- X -> bf16 + row sumsq (one block per row) ----------
__global__ __launch_bounds__(256) void cvt_norm_kernel(const float* __restrict__ src,
                                                       ushort_t* __restrict__ dst,
                                                       float* __restrict__ rowsq) {
  __shared__ float red[4];
  const int row = blockIdx.x;
  const int t = threadIdx.x;
  float4 x4 = ((const float4*)(src + (size_t)row * DIMV))[t];
  ushort_t h[4] = {f2b(x4.x), f2b(x4.y), f2b(x4.z), f2b(x4.w)};
  ((uint2*)(dst + (size_t)row * DIMV))[t] = *(uint2*)h;
  float s = x4.x * x4.x + x4.y * x4.y + x4.z * x4.z + x4.w * x4.w;
  s = blockReduceSum(s, red);
  if (t == 0) rowsq[row] = s;
}

// ---------- weight transpose -> bf16 (hi, and optional lo residual) ----------
template <bool LO>
__global__ __launch_bounds__(256) void transW_kernel(const float* __restrict__ src,
                                                     ushort_t* __restrict__ hi,
                                                     ushort_t* __restrict__ lo) {
  __shared__ float tile[32][33];
  const int bx = blockIdx.x * 32, by = blockIdx.y * 32;
  const int tx = threadIdx.x & 31, ty = threadIdx.x >> 5;
#pragma unroll
  for (int i = 0; i < 32; i += 8) tile[ty + i][tx] = src[(size_t)(by + ty + i) * DIMV + bx + tx];
  __syncthreads();
#pragma unroll
  for (int i = 0; i < 32; i += 8) {
    float v = tile[tx][ty + i];
    ushort_t h = f2b(v);
    hi[(size_t)(bx + ty + i) * DIMV + by + tx] = h;
    if (LO) lo[(size_t)(bx + ty + i) * DIMV + by + tx] = f2b(v - b2f(h));
  }
}

// 128B-row k-unit swizzle (BK=64: row = 8 units of 16B): LDS[row][u] = global unit
// u ^ (row&7). Staging thread: row-in-chunk = lane>>3, src unit = (lane&7)^((lane>>3)&7),
// LDS dest linear. Fragment read: k-sub ks, group g=lane>>4 -> LDS unit ((ks*4+g)^(l15&7))
// of row base+l15 -> 8 distinct banks over l15=0..7, 2 lanes/bank (free).

// ---------- bf16 MFMA GEMM, 256x256 tile, BK=64, 8 waves, dbuf 2-phase, swizzled ----------
// r7 structure (best measured: 157us), plain HIP, compiler-scheduled; + bank-conflict fix.
// EPI 0: Cq = bf16(acc)                                  (V path)
// EPI 3: cols < 1024 -> Cq = bf16(v1); cols >= 1024 -> Ck = bf16(v2), v2sum atomics (QK fused)
template <int EPI, int NB>
__global__ __launch_bounds__(512, 2) void gemm_bf(const ushort_t* __restrict__ A,
                                                  const ushort_t* __restrict__ Bt,
                                                  const float* __restrict__ biasQ,
                                                  const float* __restrict__ biasK,
                                                  const float* __restrict__ denom,
                                                  const float* __restrict__ mask,
                                                  float* __restrict__ v2sum,
                                                  ushort_t* __restrict__ Cq,
                                                  ushort_t* __restrict__ Ck) {
  __shared__ ushort_t As[2][256 * 64];  // 32 KB per buf
  __shared__ ushort_t Bs[2][256 * 64];
  const int bid = blockIdx.x;
  const int nwg = NB * 64;
  const int swz = (bid & 7) * (nwg / 8) + (bid >> 3);
  const int bm = (swz / NB) * 256;
  const int bn = (swz % NB) * 256;
  const int t = threadIdx.x;
  const int w = t >> 6, lane = t & 63, l15 = lane & 15;
  const int wr = (w >> 2) * 128;   // wave row base (2 M-groups)
  const int wcn = (w & 3) * 64;    // wave col base (4 N-groups)
  const int g4 = lane >> 4;
  const int e7 = l15 & 7;
  const int uo0 = (g4 ^ e7) * 8;        // ks=0 swizzled unit offset (ushorts)
  const int uo1 = ((4 + g4) ^ e7) * 8;  // ks=1

  // staging: 32 chunks of 1KB (8 rows x 128B) per operand; wave w takes chunks w+8c.
  const int rowin = lane >> 3;
  const int ksh = ((lane & 7) ^ ((lane >> 3) & 7)) * 8;  // swizzled src k-offset
  const ushort_t *gA[4], *gB[4];
  int lofs[4];
#pragma unroll
  for (int c = 0; c < 4; ++c) {
    const int ch = w + 8 * c;
    lofs[c] = ch * 512;
    gA[c] = A + (size_t)(bm + ch * 8 + rowin) * DIMV + ksh;
    gB[c] = Bt + (size_t)(bn + ch * 8 + rowin) * DIMV + ksh;
  }

#define STAGE_G(buf, k0)                              \
  do {                                                \
    _Pragma("unroll") for (int c = 0; c < 4; ++c) {   \
      GLD16(gA[c] + (k0), &As[buf][lofs[c]]);         \
      GLD16(gB[c] + (k0), &Bs[buf][lofs[c]]);         \
    }                                                 \
  } while (0)

  f32x4 acc[8][4];
#pragma unroll
  for (int i = 0; i < 8; ++i)
#pragma unroll
    for (int j = 0; j < 4; ++j) acc[i][j] = (f32x4){0.f, 0.f, 0.f, 0.f};

  STAGE_G(0, 0);
  __syncthreads();  // drains vmcnt(0): buf0 ready
  int cur = 0;
  for (int k0 = 0; k0 < DIMV; k0 += 64) {
    if (k0 + 64 < DIMV) STAGE_G(cur ^ 1, k0 + 64);  // prefetch flies under compute
#pragma unroll
    for (int ks = 0; ks < 2; ++ks) {
      const int uo = ks ? uo1 : uo0;
      short8 bf[4];
#pragma unroll
      for (int j = 0; j < 4; ++j)
        bf[j] = *(const short8*)&Bs[cur][(wcn + j * 16 + l15) * 64 + uo];
#pragma unroll
      for (int i = 0; i < 8; ++i) {
        short8 af = *(const short8*)&As[cur][(wr + i * 16 + l15) * 64 + uo];
#pragma unroll
        for (int j = 0; j < 4; ++j)
          acc[i][j] = __builtin_amdgcn_mfma_f32_16x16x32_bf16(af, bf[j], acc[i][j], 0, 0, 0);
      }
    }
    __syncthreads();  // one barrier/K-tile: drains prefetch + protects buf reuse
    cur ^= 1;
  }
#undef STAGE_G

  // epilogue (r7 form). C/D layout: col = lane&15, row = (lane>>4)*4 + r
  const int rbase = (lane >> 4) * 4;
  if (EPI == 0) {
#pragma unroll
    for (int j = 0; j < 4; ++j) {
      const int col = bn + wcn + j * 16 + l15;
#pragma unroll
      for (int i = 0; i < 8; ++i)
#pragma unroll
        for (int r = 0; r < 4; ++r)
          Cq[(size_t)(bm + wr + i * 16 + rbase + r) * DIMV + col] = f2b(acc[i][j][r]);
    }
  } else {
    const bool isK = (bn >= DIMV);  // block-uniform (bn multiple of 256)
    const int h = ((bn + wcn) >> 6) & (NHEADS - 1);
    int lc[4];
    float bb[4];
#pragma unroll
    for (int j = 0; j < 4; ++j) {
      lc[j] = (bn + wcn + j * 16 + l15) & (DIMV - 1);
      bb[j] = isK ? biasK[lc[j]] : biasQ[lc[j]];
    }
    float csum[4] = {0.f, 0.f, 0.f, 0.f};
#pragma unroll
    for (int i = 0; i < 8; ++i) {
#pragma unroll
      for (int r = 0; r < 4; ++r) {
        const int row = bm + wr + i * 16 + rbase + r;
        const float invdp = 1.0f / denom[(size_t)h * N_NODES + row];
        float den = 0.f, mk = 0.f;
        if (isK) {
          den = clampabs(2.0f * invdp - 1.0f, 1e-10f);
          mk = mask[row];
        }
#pragma unroll
        for (int j = 0; j < 4; ++j) {
          float val = elup1((acc[i][j][r] + bb[j]) * invdp);
          if (isK) {
            val = den * val * mk;
            csum[j] += val;
            Ck[(size_t)row * DIMV + lc[j]] = f2b(val);
          } else {
            Cq[(size_t)row * DIMV + lc[j]] = f2b(val);
          }
        }
      }
    }
    if (isK) {
#pragma unroll
      for (int j = 0; j < 4; ++j) atomicAdd(&v2sum[lc[j]], csum[j]);
    }
  }
}

// ---------- fused 2-term split GEMM: C = bf16(AhiBhi + AloBhi) ----------
// (AhiBlo residual dropped: ~2^-9 relative on mx, within accuracy budget; saves 1/3 MFMA
// and the Blo staging entirely.) 256x256, BK=32, 8 waves, dbuf, swizzled, coalesced epi.
__global__ __launch_bounds__(512, 2) void gemm_split3(const ushort_t* __restrict__ Ahi,
                                                      const ushort_t* __restrict__ Alo,
                                                      const ushort_t* __restrict__ Bhi,
                                                      ushort_t* __restrict__ C) {
  __shared__ ushort_t LB[49152];  // 96 KB: AH:0 AL:16384 BH:32768, each [2][8192]
  const int bid = blockIdx.x;
  const int swz = (bid & 7) * 32 + (bid >> 3);  // nwg = 256
  const int bm = (swz >> 2) * 256;
  const int bn = (swz & 3) * 256;
  const int t = threadIdx.x;
  const int w = t >> 6, lane = t & 63, l15 = lane & 15;
  const int wr = (w >> 2) * 128;
  const int wcn = (w & 3) * 64;
  const int kks = (((lane >> 4) ^ ((lane >> 1) & 3)) << 3);
  const int sksw = (((lane & 3) ^ ((lane >> 3) & 3)) << 3);

  size_t goA[2], goB[2];
  int lofs[2];
#pragma unroll
  for (int c = 0; c < 2; ++c) {
    const int ch = w + 8 * c;
    lofs[c] = ch * 512 + lane * 8;
    goA[c] = (size_t)(bm + ch * 16 + (lane >> 2)) * DIMV + sksw;
    goB[c] = (size_t)(bn + ch * 16 + (lane >> 2)) * DIMV + sksw;
  }

#define STAGE_S(buf, k0)                                             \
  do {                                                               \
    _Pragma("unroll") for (int c = 0; c < 2; ++c) {                  \
      GLD16(Ahi + goA[c] + (k0), &LB[(buf)*8192 + lofs[c]]);         \
      GLD16(Alo + goA[c] + (k0), &LB[16384 + (buf)*8192 + lofs[c]]); \
      GLD16(Bhi + goB[c] + (k0), &LB[32768 + (buf)*8192 + lofs[c]]); \
    }                                                                \
  } while (0)

  f32x4 acc[8][4];
#pragma unroll
  for (int i = 0; i < 8; ++i)
#pragma unroll
    for (int j = 0; j < 4; ++j) acc[i][j] = (f32x4){0.f, 0.f, 0.f, 0.f};

  STAGE_S(0, 0);
  __syncthreads();
  int cur = 0;
  for (int k0 = 0; k0 < DIMV; k0 += 32) {
    if (k0 + 32 < DIMV) STAGE_S(cur ^ 1, k0 + 32);
    short8 bfH[4];
#pragma unroll
    for (int j = 0; j < 4; ++j)
      bfH[j] = *(const short8*)&LB[32768 + cur * 8192 + (wcn + j * 16 + l15) * 32 + kks];
#pragma unroll
    for (int i = 0; i < 8; ++i) {
      short8 afH = *(const short8*)&LB[cur * 8192 + (wr + i * 16 + l15) * 32 + kks];
      short8 afL = *(const short8*)&LB[16384 + cur * 8192 + (wr + i * 16 + l15) * 32 + kks];
#pragma unroll
      for (int j = 0; j < 4; ++j) {
        acc[i][j] = __builtin_amdgcn_mfma_f32_16x16x32_bf16(afH, bfH[j], acc[i][j], 0, 0, 0);
        acc[i][j] = __builtin_amdgcn_mfma_f32_16x16x32_bf16(afL, bfH[j], acc[i][j], 0, 0, 0);
      }
    }
    __syncthreads();
    cur ^= 1;
  }
#undef STAGE_S

  // coalesced epilogue via LDS [128][256] (reuses first 64KB)
  const int rbase = (lane >> 4) * 4;
  const int prow = w >> 2;
#pragma unroll
  for (int p = 0; p < 2; ++p) {
    if (prow == p) {
#pragma unroll
      for (int i = 0; i < 8; ++i)
#pragma unroll
        for (int r = 0; r < 4; ++r) {
          const int row_l = i * 16 + rbase + r;
#pragma unroll
          for (int j = 0; j < 4; ++j)
            LB[row_l * 256 + wcn + j * 16 + l15] = f2b(acc[i][j][r]);
        }
    }
    __syncthreads();
#pragma unroll
    for (int it = 0; it < 8; ++it) {
      const int idx = it * 512 + t;
      const int row_l = idx >> 5, cq = idx & 31;
      uint4 v = *(const uint4*)&LB[row_l * 256 + cq * 8];
      *(uint4*)(C + (size_t)(bm + p * 128 + row_l) * DIMV + bn + cq * 8) = v;
    }
    __syncthreads();
  }
}

// ---------- row transform: mobius_matvec tail + kappa_relu (bf16 msrc, precomputed ||x||^2) ----------
template <bool BFDST>
__global__ __launch_bounds__(256) void rowtrans_kernel(const ushort_t* __restrict__ msrc,
                                                       const float* __restrict__ rowsq,
                                                       void* __restrict__ dstv,
                                                       float* __restrict__ denom) {
  __shared__ float red[4];
  __shared__ float orow[DIMV];
  const int row = blockIdx.x;
  const int t = threadIdx.x;
  uint2 mraw = ((const uint2*)(msrc + (size_t)row * DIMV))[t];
  ushort_t* mh = (ushort_t*)&mraw;
  float4 m4 = make_float4(b2f(mh[0]), b2f(mh[1]), b2f(mh[2]), b2f(mh[3]));
  float sm = m4.x * m4.x + m4.y * m4.y + m4.z * m4.z + m4.w * m4.w;
  sm = blockReduceSum(sm, red);
  float sx = rowsq[row];

  float xn = fmaxf(sqrtf(sx), 1e-15f);
  float mxn = fmaxf(sqrtf(sm), 1e-15f);
  float cx = fminf(xn, 1.0f - 1e-7f);
  float t1 = tanhf(mxn / xn * atanhf(cx));
  float s1 = t1 / mxn;

  float yn = fmaxf(fabsf(t1), 1e-15f);
  float a = atanhf(fminf(yn, 1.0f - 1e-7f)) / yn;
  float k1 = a * s1;
  float4 u = make_float4(fmaxf(k1 * m4.x, 0.0f), fmaxf(k1 * m4.y, 0.0f),
                         fmaxf(k1 * m4.z, 0.0f), fmaxf(k1 * m4.w, 0.0f));
  float su = u.x * u.x + u.y * u.y + u.z * u.z + u.w * u.w;
  su = blockReduceSum(su, red);

  float un = fmaxf(sqrtf(su), 1e-15f);
  float t2 = tanhf(un);
  float s2 = t2 / un;
  if (t2 > 0.996f) s2 *= 0.996f / t2;
  float4 o = make_float4(s2 * u.x, s2 * u.y, s2 * u.z, s2 * u.w);
  if (BFDST) {
    ushort_t h[4] = {f2b(o.x), f2b(o.y), f2b(o.z), f2b(o.w)};
    ((uint2*)((ushort_t*)dstv + (size_t)row * DIMV))[t] = *(uint2*)h;
  } else {
    ((float4*)((float*)dstv + (size_t)row * DIMV))[t] = o;
  }

  if (denom) {
    ((float4*)orow)[t] = o;
    __syncthreads();
    if (t < NHEADS) {
      float s = 0.0f;
#pragma unroll
      for (int i = 0; i < HEADD; ++i) {
        float v = orow[t * HEADD + i];
        s = fmaf(v, v, s);
      }
      denom[t * N_NODES + row] = fmaxf(1.0f - s, 1e-15f);
    }
  }
}

// ---------- ctxT[h][e][d] = sum_n v2[h,n,d] * (gamma/den * mask * V)[h,n,e]  (v2,V bf16) ----------
__global__ __launch_bounds__(256) void context_kernel(const ushort_t* __restrict__ v2buf,
                                                      const ushort_t* __restrict__ vbuf,
                                                      const float* __restrict__ denom,
                                                      const float* __restrict__ mask,
                                                      float* __restrict__ ctxT) {
  __shared__ float s2[64][65];
  __shared__ float sx[64][65];
  const int h = blockIdx.y;
  const int t = threadIdx.x;
  const int d0 = (t >> 4) * 4;
  const int e0 = (t & 15) * 4;
  float acc[4][4];
#pragma unroll
  for (int i = 0; i < 4; ++i)
#pragma unroll
    for (int j = 0; j < 4; ++j) acc[i][j] = 0.0f;

  const int rbase = blockIdx.x * 512;
  for (int c = 0; c < 8; ++c) {
#pragma unroll
    for (int i = 0; i < 4; ++i) {
      int f = i * 256 + t;
      int r = f >> 4;
      int cc = (f & 15) * 4;
      int row = rbase + c * 64 + r;
      uint2 araw = *(const uint2*)(v2buf + (size_t)row * DIMV + h * HEADD + cc);
      ushort_t* ah = (ushort_t*)&araw;
      s2[r][cc + 0] = b2f(ah[0]); s2[r][cc + 1] = b2f(ah[1]);
      s2[r][cc + 2] = b2f(ah[2]); s2[r][cc + 3] = b2f(ah[3]);
      float dp = denom[(size_t)h * N_NODES + row];
      float gamma = 2.0f / dp;
      float den = clampabs(gamma - 1.0f, 1e-10f);
      float c1 = gamma / den * mask[row];
      uint2 braw = *(const uint2*)(vbuf + (size_t)row * DIMV + h * HEADD + cc);
      ushort_t* bh = (ushort_t*)&braw;
      sx[r][cc + 0] = c1 * b2f(bh[0]); sx[r][cc + 1] = c1 * b2f(bh[1]);
      sx[r][cc + 2] = c1 * b2f(bh[2]); sx[r][cc + 3] = c1 * b2f(bh[3]);
    }
    __syncthreads();
    for (int r = 0; r < 64; ++r) {
      float av[4], bv[4];
#pragma unroll
      for (int i = 0; i < 4; ++i) av[i] = s2[r][d0 + i];
#pragma unroll
      for (int j = 0; j < 4; ++j) bv[j] = sx[r][e0 + j];
#pragma unroll
      for (int i = 0; i < 4; ++i)
#pragma unroll
        for (int j = 0; j < 4; ++j) acc[i][j] = fmaf(av[i], bv[j], acc[i][j]);
    }
    __syncthreads();
  }
#pragma unroll
  for (int i = 0; i < 4; ++i)
#pragma unroll
    for (int j = 0; j < 4; ++j)
      atomicAdd(&ctxT[h * 4096 + (e0 + j) * 64 + (d0 + i)], acc[i][j]);
}

// ---------- out (MFMA): [out|D] = v1 @ [ctx|v2sum]; tail; emit combHi/Lo + rownorm atomics ----------
__global__ __launch_bounds__(256) void out_mfma_kernel(const ushort_t* __restrict__ v1bf,
                                                       const float* __restrict__ v2sum,
                                                       const float* __restrict__ ctxT,
                                                       ushort_t* __restrict__ combHi,
                                                       ushort_t* __restrict__ combLo,
                                                       float* __restrict__ combnorm) {
  __shared__ ushort_t Blds[80][88];
  const int h = blockIdx.y;
  const int bm = blockIdx.x * 256;
  const int t = threadIdx.x;
  const int w = t >> 6, lane = t & 63, l15 = lane & 15;
  const int kk = (lane >> 4) * 8;

  for (int idx = t; idx < 80 * 64; idx += 256) {
    int e = idx >> 6, d = idx & 63;
    float v = 0.0f;
    if (e < 64) v = ctxT[h * 4096 + e * 64 + d];
    else if (e == 64) v = v2sum[h * 64 + d];
    Blds[e][d] = f2b(v);
  }
  __syncthreads();

  f32x4 acc[4][5];
#pragma unroll
  for (int i = 0; i < 4; ++i)
#pragma unroll
    for (int j = 0; j < 5; ++j) acc[i][j] = (f32x4){0.f, 0.f, 0.f, 0.f};
#pragma unroll
  for (int ks = 0; ks < 2; ++ks) {
    short8 bfr[5];
#pragma unroll
    for (int j = 0; j < 5; ++j) bfr[j] = *(const short8*)&Blds[j * 16 + l15][ks * 32 + kk];
#pragma unroll
    for (int i = 0; i < 4; ++i) {
      short8 af = *(const short8*)(v1bf + (size_t)(bm + w * 64 + i * 16 + l15) * DIMV +
                                   h * HEADD + ks * 32 + kk);
#pragma unroll
      for (int j = 0; j < 5; ++j)
        acc[i][j] = __builtin_amdgcn_mfma_f32_16x16x32_bf16(af, bfr[j], acc[i][j], 0, 0, 0);
    }
  }

  const int g4 = (lane >> 4) * 4;
#pragma unroll
  for (int i = 0; i < 4; ++i) {
#pragma unroll
    for (int r = 0; r < 4; ++r) {
      const int row = bm + w * 64 + i * 16 + g4 + r;
      float D = __shfl(acc[i][4][r], lane & 48);
      float Dinv = 1.0f / (D == 0.0f ? 1e-5f : D);
      float o[4];
      float s = 0.0f;
#pragma unroll
      for (int j = 0; j < 4; ++j) {
        o[j] = acc[i][j][r] * Dinv;
        s = fmaf(o[j], o[j], s);
      }
      s += __shfl_xor(s, 1); s += __shfl_xor(s, 2);
      s += __shfl_xor(s, 4); s += __shfl_xor(s, 8);
      float n1 = fmaxf(sqrtf(s), 1e-15f);
      float sc = 1.0f;
      if (n1 > 0.996f) sc = 0.996f / n1;
      float xn = fmaxf(fminf(n1, 0.996f), 1e-15f);
      float cx = fminf(xn, 1.0f - 1e-7f);
      float t2 = tanhf(0.5f * atanhf(cx));
      sc *= t2 / xn;
      if (t2 > 0.996f) sc *= 0.996f / t2;
      if (l15 == 0) atomicAdd(&combnorm[row], s * sc * sc);
#pragma unroll
      for (int j = 0; j < 4; ++j) {
        float ov = o[j] * sc;
        size_t off = (size_t)row * DIMV + h * HEADD + j * 16 + l15;
        ushort_t hi = f2b(ov);
        combHi[off] = hi;
        combLo[off] = f2b(ov - b2f(hi));
      }
    }
  }
}

// ---------- launch ----------

extern "C" void kernel_launch(void* const* d_in, const int* in_sizes, int n_in,
                              void* d_out, int out_size, void* d_ws, size_t ws_size,
                              hipStream_t stream) {
  const float* X = (const float*)d_in[0];
  const float* mask = (const float*)d_in[1];
  const float* Wq = (const float*)d_in[2];
  const float* bq = (const float*)d_in[3];
  const float* Wk = (const float*)d_in[4];
  const float* bk = (const float*)d_in[5];
  const float* Wv = (const float*)d_in[6];
  const float* Wff = (const float*)d_in[7];
  float* out = (float*)d_out;

  const size_t MAT = (size_t)N_NODES * DIMV;
  char* p = (char*)d_ws;
  // R1 (64MB): first half v1bf (QK epi out); second half mxV bf16, later combnorm
  ushort_t* v1bf = (ushort_t*)p;
  ushort_t* mxV = (ushort_t*)(p + MAT * 2);
  float* combnorm = (float*)(p + MAT * 2);
  p += MAT * 4;
  // R2 (64MB): xnormsq (early) / v2bf (QK epi out) / combHi+combLo (after context)
  float* xnormsq = (float*)p;
  ushort_t* v2bf = (ushort_t*)p;
  ushort_t* combHi = (ushort_t*)p;
  ushort_t* combLo = combHi + MAT;
  p += MAT * 4;
  // R3 (32MB): Vbf; later WffHi/WffLo
  ushort_t* Vbf = (ushort_t*)p;
  ushort_t* WffHi = Vbf;
  ushort_t* WffLo = Vbf + (size_t)DIMV * DIMV;
  p += MAT * 2;
  // R4 (32MB): Xbf; later outBf (split3 out)
  ushort_t* Xbf = (ushort_t*)p;
  ushort_t* outBf = Xbf;
  p += MAT * 2;
  float* denom = (float*)p;  p += (size_t)NHEADS * N_NODES * 4;
  float* v2sum = (float*)p;  p += 1024 * 4;
  float* ctxT = (float*)p;   p += (size_t)NHEADS * 4096 * 4;
  const size_t need = (size_t)(p - (char*)d_ws);
  if (ws_size < need) return;

  // W^T bf16 scratch inside d_out (free until the final rowtrans writes it):
  ushort_t* Wt = (ushort_t*)d_out;            // Wv^T, later Wq^T (rows 0..1023)
  ushort_t* WtK = Wt + (size_t)DIMV * DIMV;   // Wk^T (rows 1024..2047 of stacked QK)

  dim3 tgrid(32, 32);

  cvt_norm_kernel<<<N_NODES, 256, 0, stream>>>(X, Xbf, xnormsq);
  // V path: mxV bf16, then rowtrans -> Vbf + denom
  transW_kernel<false><<<tgrid, 256, 0, stream>>>(Wv, Wt, nullptr);
  gemm_bf<0, 4><<<256, 512, 0, stream>>>(Xbf, Wt, nullptr, nullptr, nullptr, nullptr,
                                         nullptr, mxV, nullptr);
  rowtrans_kernel<true><<<N_NODES, 256, 0, stream>>>(mxV, xnormsq, Vbf, denom);
  // zero accumulators (v2sum+ctxT contiguous; combnorm over dead mxV)
  hipMemsetAsync(v2sum, 0, (1024 + 4096 * NHEADS) * sizeof(float), stream);
  hipMemsetAsync(combnorm, 0, N_NODES * sizeof(float), stream);
  // QK fused: stacked [Wq^T; Wk^T], epilogue emits v1 (cols<1024) and v2 + v2sum (cols>=1024)
  transW_kernel<false><<<tgrid, 256, 0, stream>>>(Wq, Wt, nullptr);
  transW_kernel<false><<<tgrid, 256, 0, stream>>>(Wk, WtK, nullptr);
  gemm_bf<3, 8><<<512, 512, 0, stream>>>(Xbf, Wt, bq, bk, denom, mask, v2sum, v1bf, v2bf);
  // context (transposed output)
  context_kernel<<<dim3(32, NHEADS), 256, 0, stream>>>(v2bf, Vbf, denom, mask, ctxT);
  // attention out -> combHi/Lo + row norms
  out_mfma_kernel<<<dim3(N_NODES / 256, NHEADS), 256, 0, stream>>>(v1bf, v2sum, ctxT, combHi,
                                                                   combLo, combnorm);
  // final: fused 2-term split GEMM -> outBf, then rowtrans -> d_out
  transW_kernel<true><<<tgrid, 256, 0, stream>>>(Wff, WffHi, WffLo);
  gemm_split3<<<256, 512, 0, stream>>>(combHi, combLo, WffHi, outBf);
  rowtrans_kernel<false><<<N_NODES, 256, 0, stream>>>(outBf, combnorm, out, nullptr);
}

// Round 14
// 400.059 us; speedup vs baseline: 1.7284x; 1.1810x over previous
//
#include <hip/hip_runtime.h>
#include <hip/hip_bf16.h>
#include <math.h>

#define N_NODES 16384
#define DIMV 1024
#define NHEADS 16
#define HEADD 64

typedef __attribute__((ext_vector_type(8))) short short8;
typedef __attribute__((ext_vector_type(4))) float f32x4;
typedef unsigned short ushort_t;

// async global->LDS, 16B per lane
#define GLD16(gptr, lptr)                                                                 \
  __builtin_amdgcn_global_load_lds((const __attribute__((address_space(1))) void*)(gptr), \
                                   (__attribute__((address_space(3))) void*)(lptr), 16, 0, 0)

// ---------- helpers ----------

__device__ __forceinline__ float waveReduceSum(float v) {
#pragma unroll
  for (int m = 32; m; m >>= 1) v += __shfl_xor(v, m);
  return v;
}

__device__ __forceinline__ float blockReduceSum(float v, float* red) {
  float w = waveReduceSum(v);
  __syncthreads();
  if ((threadIdx.x & 63) == 0) red[threadIdx.x >> 6] = w;
  __syncthreads();
  return red[0] + red[1] + red[2] + red[3];
}

__device__ __forceinline__ float elup1(float z) {
  return z > 0.0f ? z + 1.0f : expm1f(z) + 1.0f;
}

__device__ __forceinline__ float clampabs(float x, float eps) {
  float s = (x >= 0.0f) ? 1.0f : -1.0f;
  return s * fmaxf(fabsf(x), eps);
}

// fp32 -> bf16 bits, RNE
__device__ __forceinline__ ushort_t f2b(float x) {
  unsigned u = __float_as_uint(x);
  unsigned r = (u + 0x7FFFu + ((u >> 16) & 1u)) >> 16;
  return (ushort_t)r;
}
__device__ __forceinline__ float b2f(ushort_t h) {
  return __uint_as_float(((unsigned)h) << 16);
}

// ---------- X -> bf16 + row sumsq (one block per row) ----------
__global__ __launch_bounds__(256) void cvt_norm_kernel(const float* __restrict__ src,
                                                       ushort_t* __restrict__ dst,
                                                       float* __restrict__ rowsq) {
  __shared__ float red[4];
  const int row = blockIdx.x;
  const int t = threadIdx.x;
  float4 x4 = ((const float4*)(src + (size_t)row * DIMV))[t];
  ushort_t h[4] = {f2b(x4.x), f2b(x4.y), f2b(x4.z), f2b(x4.w)};
  ((uint2*)(dst + (size_t)row * DIMV))[t] = *(uint2*)h;
  float s = x4.x * x4.x + x4.y * x4.y + x4.z * x4.z + x4.w * x4.w;
  s = blockReduceSum(s, red);
  if (t == 0) rowsq[row] = s;
}

// ---------- weight transpose -> bf16 ----------
__global__ __launch_bounds__(256) void transW_kernel(const float* __restrict__ src,
                                                     ushort_t* __restrict__ hi) {
  __shared__ float tile[32][33];
  const int bx = blockIdx.x * 32, by = blockIdx.y * 32;
  const int tx = threadIdx.x & 31, ty = threadIdx.x >> 5;
#pragma unroll
  for (int i = 0; i < 32; i += 8) tile[ty + i][tx] = src[(size_t)(by + ty + i) * DIMV + bx + tx];
  __syncthreads();
#pragma unroll
  for (int i = 0; i < 32; i += 8)
    hi[(size_t)(bx + ty + i) * DIMV + by + tx] = f2b(tile[tx][ty + i]);
}

// fused triple transpose: z=0 Wq->d0, z=1 Wk->d1, z=2 Wv->d2
__global__ __launch_bounds__(256) void transW3_kernel(const float* __restrict__ s0,
                                                      const float* __restrict__ s1,
                                                      const float* __restrict__ s2,
                                                      ushort_t* __restrict__ d0,
                                                      ushort_t* __restrict__ d1,
                                                      ushort_t* __restrict__ d2) {
  __shared__ float tile[32][33];
  const float* src = (blockIdx.z == 0) ? s0 : (blockIdx.z == 1) ? s1 : s2;
  ushort_t* dst = (blockIdx.z == 0) ? d0 : (blockIdx.z == 1) ? d1 : d2;
  const int bx = blockIdx.x * 32, by = blockIdx.y * 32;
  const int tx = threadIdx.x & 31, ty = threadIdx.x >> 5;
#pragma unroll
  for (int i = 0; i < 32; i += 8) tile[ty + i][tx] = src[(size_t)(by + ty + i) * DIMV + bx + tx];
  __syncthreads();
#pragma unroll
  for (int i = 0; i < 32; i += 8)
    dst[(size_t)(bx + ty + i) * DIMV + by + tx] = f2b(tile[tx][ty + i]);
}

// 128B-row k-unit swizzle (BK=64, r13-verified, bank-conflict = 0):
// LDS[row][u] = global unit u ^ (row&7); staging src unit (lane&7)^((lane>>3)&7);
// fragment read unit ((ks*4+g) ^ (l15&7)).

// ---------- bf16 MFMA GEMM, 256x256 tile, BK=64, 8 waves, dbuf 2-phase, swizzled ----------
// EPI 0: Cq = bf16(acc)                                  (plain: final comb@Wff)
// EPI 3: cols<1024 -> Cq=bf16(v1); cols>=1024 -> Ck=bf16(v2)+v2sum atomics (QK fused)
// EPI 4: Cq = bf16(acc) + per-(row,head) stats {sum mx^2, sum relu(mx)^2} (V path)
template <int EPI, int NB>
__global__ __launch_bounds__(512, 2) void gemm_bf(const ushort_t* __restrict__ A,
                                                  const ushort_t* __restrict__ Bt,
                                                  const float* __restrict__ biasQ,
                                                  const float* __restrict__ biasK,
                                                  const float* __restrict__ denom,
                                                  const float* __restrict__ mask,
                                                  float* __restrict__ v2sum,
                                                  float* __restrict__ mxhsq,
                                                  float* __restrict__ reluhsq,
                                                  ushort_t* __restrict__ Cq,
                                                  ushort_t* __restrict__ Ck) {
  __shared__ ushort_t As[2][256 * 64];  // 32 KB per buf
  __shared__ ushort_t Bs[2][256 * 64];
  const int bid = blockIdx.x;
  const int nwg = NB * 64;
  const int swz = (bid & 7) * (nwg / 8) + (bid >> 3);
  const int bm = (swz / NB) * 256;
  const int bn = (swz % NB) * 256;
  const int t = threadIdx.x;
  const int w = t >> 6, lane = t & 63, l15 = lane & 15;
  const int wr = (w >> 2) * 128;
  const int wcn = (w & 3) * 64;
  const int g4 = lane >> 4;
  const int e7 = l15 & 7;
  const int uo0 = (g4 ^ e7) * 8;
  const int uo1 = ((4 + g4) ^ e7) * 8;

  const int rowin = lane >> 3;
  const int ksh = ((lane & 7) ^ ((lane >> 3) & 7)) * 8;
  const ushort_t *gA[4], *gB[4];
  int lofs[4];
#pragma unroll
  for (int c = 0; c < 4; ++c) {
    const int ch = w + 8 * c;
    lofs[c] = ch * 512;
    gA[c] = A + (size_t)(bm + ch * 8 + rowin) * DIMV + ksh;
    gB[c] = Bt + (size_t)(bn + ch * 8 + rowin) * DIMV + ksh;
  }

#define STAGE_G(buf, k0)                              \
  do {                                                \
    _Pragma("unroll") for (int c = 0; c < 4; ++c) {   \
      GLD16(gA[c] + (k0), &As[buf][lofs[c]]);         \
      GLD16(gB[c] + (k0), &Bs[buf][lofs[c]]);         \
    }                                                 \
  } while (0)

  f32x4 acc[8][4];
#pragma unroll
  for (int i = 0; i < 8; ++i)
#pragma unroll
    for (int j = 0; j < 4; ++j) acc[i][j] = (f32x4){0.f, 0.f, 0.f, 0.f};

  STAGE_G(0, 0);
  __syncthreads();
  int cur = 0;
  for (int k0 = 0; k0 < DIMV; k0 += 64) {
    if (k0 + 64 < DIMV) STAGE_G(cur ^ 1, k0 + 64);
#pragma unroll
    for (int ks = 0; ks < 2; ++ks) {
      const int uo = ks ? uo1 : uo0;
      short8 bf[4];
#pragma unroll
      for (int j = 0; j < 4; ++j)
        bf[j] = *(const short8*)&Bs[cur][(wcn + j * 16 + l15) * 64 + uo];
#pragma unroll
      for (int i = 0; i < 8; ++i) {
        short8 af = *(const short8*)&As[cur][(wr + i * 16 + l15) * 64 + uo];
#pragma unroll
        for (int j = 0; j < 4; ++j)
          acc[i][j] = __builtin_amdgcn_mfma_f32_16x16x32_bf16(af, bf[j], acc[i][j], 0, 0, 0);
      }
    }
    __syncthreads();
    cur ^= 1;
  }
#undef STAGE_G

  // epilogue. C/D layout: col = lane&15, row = (lane>>4)*4 + r
  const int rbase = (lane >> 4) * 4;
  if (EPI == 0) {
#pragma unroll
    for (int j = 0; j < 4; ++j) {
      const int col = bn + wcn + j * 16 + l15;
#pragma unroll
      for (int i = 0; i < 8; ++i)
#pragma unroll
        for (int r = 0; r < 4; ++r)
          Cq[(size_t)(bm + wr + i * 16 + rbase + r) * DIMV + col] = f2b(acc[i][j][r]);
    }
  } else if (EPI == 4) {
    // V path: bf16 store + per-(row,head) stats. Each (row,head) owned by exactly one
    // wave (wr x wcn partition) -> plain stores, no atomics. 16-lane shfl reduce over l15.
    const int h = ((bn + wcn) >> 6) & (NHEADS - 1);
#pragma unroll
    for (int i = 0; i < 8; ++i) {
#pragma unroll
      for (int r = 0; r < 4; ++r) {
        const int row = bm + wr + i * 16 + rbase + r;
        float smx = 0.f, srel = 0.f;
#pragma unroll
        for (int j = 0; j < 4; ++j) {
          float val = acc[i][j][r];
          Cq[(size_t)row * DIMV + bn + wcn + j * 16 + l15] = f2b(val);
          smx = fmaf(val, val, smx);
          float rv = fmaxf(val, 0.f);
          srel = fmaf(rv, rv, srel);
        }
        smx += __shfl_xor(smx, 1); smx += __shfl_xor(smx, 2);
        smx += __shfl_xor(smx, 4); smx += __shfl_xor(smx, 8);
        srel += __shfl_xor(srel, 1); srel += __shfl_xor(srel, 2);
        srel += __shfl_xor(srel, 4); srel += __shfl_xor(srel, 8);
        if (l15 == 0) {
          mxhsq[(size_t)h * N_NODES + row] = smx;
          reluhsq[(size_t)h * N_NODES + row] = srel;
        }
      }
    }
  } else {
    const bool isK = (bn >= DIMV);  // block-uniform
    const int h = ((bn + wcn) >> 6) & (NHEADS - 1);
    int lc[4];
    float bb[4];
#pragma unroll
    for (int j = 0; j < 4; ++j) {
      lc[j] = (bn + wcn + j * 16 + l15) & (DIMV - 1);
      bb[j] = isK ? biasK[lc[j]] : biasQ[lc[j]];
    }
    float csum[4] = {0.f, 0.f, 0.f, 0.f};
#pragma unroll
    for (int i = 0; i < 8; ++i) {
#pragma unroll
      for (int r = 0; r < 4; ++r) {
        const int row = bm + wr + i * 16 + rbase + r;
        const float invdp = 1.0f / denom[(size_t)h * N_NODES + row];
        float den = 0.f, mk = 0.f;
        if (isK) {
          den = clampabs(2.0f * invdp - 1.0f, 1e-10f);
          mk = mask[row];
        }
#pragma unroll
        for (int j = 0; j < 4; ++j) {
          float val = elup1((acc[i][j][r] + bb[j]) * invdp);
          if (isK) {
            val = den * val * mk;
            csum[j] += val;
            Ck[(size_t)row * DIMV + lc[j]] = f2b(val);
          } else {
            Cq[(size_t)row * DIMV + lc[j]] = f2b(val);
          }
        }
      }
    }
    if (isK) {
#pragma unroll
      for (int j = 0; j < 4; ++j) atomicAdd(&v2sum[lc[j]], csum[j]);
    }
  }
}

// ---------- vscale: per-row mobius+kappa scalars from stats; emits scaleV + denom ----------
// u = relu(k1*mx) = k1*relu(mx) (k1>0): V = s2*k1*relu(mx); denom[h] = 1 - sV^2*reluhsq[h].
__global__ __launch_bounds__(256) void vscale_kernel(const float* __restrict__ xnormsq,
                                                     const float* __restrict__ mxhsq,
                                                     const float* __restrict__ reluhsq,
                                                     float* __restrict__ scaleV,
                                                     float* __restrict__ denom) {
  const int row = blockIdx.x * 256 + threadIdx.x;
  float sm = 0.f, sr = 0.f;
  float hs[NHEADS];
#pragma unroll
  for (int h = 0; h < NHEADS; ++h) {
    sm += mxhsq[(size_t)h * N_NODES + row];
    hs[h] = reluhsq[(size_t)h * N_NODES + row];
    sr += hs[h];
  }
  float sx = xnormsq[row];
  float xn = fmaxf(sqrtf(sx), 1e-15f);
  float mxn = fmaxf(sqrtf(sm), 1e-15f);
  float cx = fminf(xn, 1.0f - 1e-7f);
  float t1 = tanhf(mxn / xn * atanhf(cx));
  float s1 = t1 / mxn;
  float yn = fmaxf(fabsf(t1), 1e-15f);
  float a = atanhf(fminf(yn, 1.0f - 1e-7f)) / yn;
  float k1 = a * s1;
  float un = fmaxf(k1 * sqrtf(sr), 1e-15f);
  float t2 = tanhf(un);
  float s2 = t2 / un;
  if (t2 > 0.996f) s2 *= 0.996f / t2;
  float sV = s2 * k1;
  scaleV[row] = sV;
#pragma unroll
  for (int h = 0; h < NHEADS; ++h)
    denom[(size_t)h * N_NODES + row] = fmaxf(1.0f - sV * sV * hs[h], 1e-15f);
}

// ---------- row transform (final): mobius_matvec tail + kappa_relu ----------
__global__ __launch_bounds__(256) void rowtrans_kernel(const ushort_t* __restrict__ msrc,
                                                       const float* __restrict__ rowsq,
                                                       float* __restrict__ dstv) {
  __shared__ float red[4];
  const int row = blockIdx.x;
  const int t = threadIdx.x;
  uint2 mraw = ((const uint2*)(msrc + (size_t)row * DIMV))[t];
  ushort_t* mh = (ushort_t*)&mraw;
  float4 m4 = make_float4(b2f(mh[0]), b2f(mh[1]), b2f(mh[2]), b2f(mh[3]));
  float sm = m4.x * m4.x + m4.y * m4.y + m4.z * m4.z + m4.w * m4.w;
  sm = blockReduceSum(sm, red);
  float sx = rowsq[row];

  float xn = fmaxf(sqrtf(sx), 1e-15f);
  float mxn = fmaxf(sqrtf(sm), 1e-15f);
  float cx = fminf(xn, 1.0f - 1e-7f);
  float t1 = tanhf(mxn / xn * atanhf(cx));
  float s1 = t1 / mxn;

  float yn = fmaxf(fabsf(t1), 1e-15f);
  float a = atanhf(fminf(yn, 1.0f - 1e-7f)) / yn;
  float k1 = a * s1;
  float4 u = make_float4(fmaxf(k1 * m4.x, 0.0f), fmaxf(k1 * m4.y, 0.0f),
                         fmaxf(k1 * m4.z, 0.0f), fmaxf(k1 * m4.w, 0.0f));
  float su = u.x * u.x + u.y * u.y + u.z * u.z + u.w * u.w;
  su = blockReduceSum(su, red);

  float un = fmaxf(sqrtf(su), 1e-15f);
  float t2 = tanhf(un);
  float s2 = t2 / un;
  if (t2 > 0.996f) s2 *= 0.996f / t2;
  float4 o = make_float4(s2 * u.x, s2 * u.y, s2 * u.z, s2 * u.w);
  ((float4*)(dstv + (size_t)row * DIMV))[t] = o;
}

// ---------- ctxT[h][e][d] = sum_n v2[h,n,d] * (gamma/den*mask*sV*relu(mx))[h,n,e] ----------
__global__ __launch_bounds__(256) void context_kernel(const ushort_t* __restrict__ v2buf,
                                                      const ushort_t* __restrict__ mxVbuf,
                                                      const float* __restrict__ scaleV,
                                                      const float* __restrict__ denom,
                                                      const float* __restrict__ mask,
                                                      float* __restrict__ ctxT) {
  __shared__ float s2[64][65];
  __shared__ float sx[64][65];
  const int h = blockIdx.y;
  const int t = threadIdx.x;
  const int d0 = (t >> 4) * 4;
  const int e0 = (t & 15) * 4;
  float acc[4][4];
#pragma unroll
  for (int i = 0; i < 4; ++i)
#pragma unroll
    for (int j = 0; j < 4; ++j) acc[i][j] = 0.0f;

  const int rbase = blockIdx.x * 512;
  for (int c = 0; c < 8; ++c) {
#pragma unroll
    for (int i = 0; i < 4; ++i) {
      int f = i * 256 + t;
      int r = f >> 4;
      int cc = (f & 15) * 4;
      int row = rbase + c * 64 + r;
      uint2 araw = *(const uint2*)(v2buf + (size_t)row * DIMV + h * HEADD + cc);
      ushort_t* ah = (ushort_t*)&araw;
      s2[r][cc + 0] = b2f(ah[0]); s2[r][cc + 1] = b2f(ah[1]);
      s2[r][cc + 2] = b2f(ah[2]); s2[r][cc + 3] = b2f(ah[3]);
      float dp = denom[(size_t)h * N_NODES + row];
      float gamma = 2.0f / dp;
      float den = clampabs(gamma - 1.0f, 1e-10f);
      float c1 = gamma / den * mask[row] * scaleV[row];
      uint2 braw = *(const uint2*)(mxVbuf + (size_t)row * DIMV + h * HEADD + cc);
      ushort_t* bh = (ushort_t*)&braw;
      sx[r][cc + 0] = c1 * fmaxf(b2f(bh[0]), 0.f); sx[r][cc + 1] = c1 * fmaxf(b2f(bh[1]), 0.f);
      sx[r][cc + 2] = c1 * fmaxf(b2f(bh[2]), 0.f); sx[r][cc + 3] = c1 * fmaxf(b2f(bh[3]), 0.f);
    }
    __syncthreads();
    for (int r = 0; r < 64; ++r) {
      float av[4], bv[4];
#pragma unroll
      for (int i = 0; i < 4; ++i) av[i] = s2[r][d0 + i];
#pragma unroll
      for (int j = 0; j < 4; ++j) bv[j] = sx[r][e0 + j];
#pragma unroll
      for (int i = 0; i < 4; ++i)
#pragma unroll
        for (int j = 0; j < 4; ++j) acc[i][j] = fmaf(av[i], bv[j], acc[i][j]);
    }
    __syncthreads();
  }
#pragma unroll
  for (int i = 0; i < 4; ++i)
#pragma unroll
    for (int j = 0; j < 4; ++j)
      atomicAdd(&ctxT[h * 4096 + (e0 + j) * 64 + (d0 + i)], acc[i][j]);
}

// ---------- out (MFMA): [out|D] = v1 @ [ctx|v2sum]; tail; emit combHi + rownorm atomics ----------
__global__ __launch_bounds__(256) void out_mfma_kernel(const ushort_t* __restrict__ v1bf,
                                                       const float* __restrict__ v2sum,
                                                       const float* __restrict__ ctxT,
                                                       ushort_t* __restrict__ combHi,
                                                       float* __restrict__ combnorm) {
  __shared__ ushort_t Blds[80][88];
  const int h = blockIdx.y;
  const int bm = blockIdx.x * 256;
  const int t = threadIdx.x;
  const int w = t >> 6, lane = t & 63, l15 = lane & 15;
  const int kk = (lane >> 4) * 8;

  for (int idx = t; idx < 80 * 64; idx += 256) {
    int e = idx >> 6, d = idx & 63;
    float v = 0.0f;
    if (e < 64) v = ctxT[h * 4096 + e * 64 + d];
    else if (e == 64) v = v2sum[h * 64 + d];
    Blds[e][d] = f2b(v);
  }
  __syncthreads();

  f32x4 acc[4][5];
#pragma unroll
  for (int i = 0; i < 4; ++i)
#pragma unroll
    for (int j = 0; j < 5; ++j) acc[i][j] = (f32x4){0.f, 0.f, 0.f, 0.f};
#pragma unroll
  for (int ks = 0; ks < 2; ++ks) {
    short8 bfr[5];
#pragma unroll
    for (int j = 0; j < 5; ++j) bfr[j] = *(const short8*)&Blds[j * 16 + l15][ks * 32 + kk];
#pragma unroll
    for (int i = 0; i < 4; ++i) {
      short8 af = *(const short8*)(v1bf + (size_t)(bm + w * 64 + i * 16 + l15) * DIMV +
                                   h * HEADD + ks * 32 + kk);
#pragma unroll
      for (int j = 0; j < 5; ++j)
        acc[i][j] = __builtin_amdgcn_mfma_f32_16x16x32_bf16(af, bfr[j], acc[i][j], 0, 0, 0);
    }
  }

  const int g4 = (lane >> 4) * 4;
#pragma unroll
  for (int i = 0; i < 4; ++i) {
#pragma unroll
    for (int r = 0; r < 4; ++r) {
      const int row = bm + w * 64 + i * 16 + g4 + r;
      float D = __shfl(acc[i][4][r], lane & 48);
      float Dinv = 1.0f / (D == 0.0f ? 1e-5f : D);
      float o[4];
      float s = 0.0f;
#pragma unroll
      for (int j = 0; j < 4; ++j) {
        o[j] = acc[i][j][r] * Dinv;
        s = fmaf(o[j], o[j], s);
      }
      s += __shfl_xor(s, 1); s += __shfl_xor(s, 2);
      s += __shfl_xor(s, 4); s += __shfl_xor(s, 8);
      float n1 = fmaxf(sqrtf(s), 1e-15f);
      float sc = 1.0f;
      if (n1 > 0.996f) sc = 0.996f / n1;
      float xn = fmaxf(fminf(n1, 0.996f), 1e-15f);
      float cx = fminf(xn, 1.0f - 1e-7f);
      float t2 = tanhf(0.5f * atanhf(cx));
      sc *= t2 / xn;
      if (t2 > 0.996f) sc *= 0.996f / t2;
      if (l15 == 0) atomicAdd(&combnorm[row], s * sc * sc);
#pragma unroll
      for (int j = 0; j < 4; ++j) {
        float ov = o[j] * sc;
        combHi[(size_t)row * DIMV + h * HEADD + j * 16 + l15] = f2b(ov);
      }
    }
  }
}

// ---------- launch ----------

extern "C" void kernel_launch(void* const* d_in, const int* in_sizes, int n_in,
                              void* d_out, int out_size, void* d_ws, size_t ws_size,
                              hipStream_t stream) {
  const float* X = (const float*)d_in[0];
  const float* mask = (const float*)d_in[1];
  const float* Wq = (const float*)d_in[2];
  const float* bq = (const float*)d_in[3];
  const float* Wk = (const float*)d_in[4];
  const float* bk = (const float*)d_in[5];
  const float* Wv = (const float*)d_in[6];
  const float* Wff = (const float*)d_in[7];
  float* out = (float*)d_out;

  const size_t MAT = (size_t)N_NODES * DIMV;
  char* p = (char*)d_ws;
  // R1 (64MB): first half v1bf (QK epi out); second half mxV bf16, later combnorm
  ushort_t* v1bf = (ushort_t*)p;
  ushort_t* mxV = (ushort_t*)(p + MAT * 2);
  float* combnorm = (float*)(p + MAT * 2);
  p += MAT * 4;
  // R2 (64MB): xnormsq (early) / v2bf (QK epi out) / combHi (after context)
  float* xnormsq = (float*)p;
  ushort_t* v2bf = (ushort_t*)p;
  ushort_t* combHi = (ushort_t*)p;
  p += MAT * 4;
  // R3 (32MB): WffHi
  ushort_t* WffHi = (ushort_t*)p;
  p += MAT * 2;
  // R4 (32MB): Xbf; later outBf (final gemm out)
  ushort_t* Xbf = (ushort_t*)p;
  ushort_t* outBf = Xbf;
  p += MAT * 2;
  float* denom = (float*)p;   p += (size_t)NHEADS * N_NODES * 4;
  float* v2sum = (float*)p;   p += 1024 * 4;
  float* ctxT = (float*)p;    p += (size_t)NHEADS * 4096 * 4;
  float* mxhsq = (float*)p;   p += (size_t)NHEADS * N_NODES * 4;
  float* reluhsq = (float*)p; p += (size_t)NHEADS * N_NODES * 4;
  float* scaleV = (float*)p;  p += (size_t)N_NODES * 4;
  const size_t need = (size_t)(p - (char*)d_ws);
  if (ws_size < need) return;

  // W^T bf16 scratch inside d_out (free until the final rowtrans writes it):
  ushort_t* Wt = (ushort_t*)d_out;            // Wq^T (rows 0..1023 of stacked QK)
  ushort_t* WtK = Wt + (size_t)DIMV * DIMV;   // Wk^T (rows 1024..2047)
  ushort_t* WtV = WtK + (size_t)DIMV * DIMV;  // Wv^T

  dim3 tgrid(32, 32);

  cvt_norm_kernel<<<N_NODES, 256, 0, stream>>>(X, Xbf, xnormsq);
  transW3_kernel<<<dim3(32, 32, 3), 256, 0, stream>>>(Wq, Wk, Wv, Wt, WtK, WtV);
  // V path: mxV bf16 + per-(row,head) stats; then closed-form scaleV + denom
  gemm_bf<4, 4><<<256, 512, 0, stream>>>(Xbf, WtV, nullptr, nullptr, nullptr, nullptr,
                                         nullptr, mxhsq, reluhsq, mxV, nullptr);
  vscale_kernel<<<N_NODES / 256, 256, 0, stream>>>(xnormsq, mxhsq, reluhsq, scaleV, denom);
  // zero v2sum + ctxT (contiguous)
  hipMemsetAsync(v2sum, 0, (1024 + 4096 * NHEADS) * sizeof(float), stream);
  // QK fused: stacked [Wq^T; Wk^T]; emits v1 (cols<1024) and v2 + v2sum (cols>=1024)
  gemm_bf<3, 8><<<512, 512, 0, stream>>>(Xbf, Wt, bq, bk, denom, mask, v2sum, nullptr,
                                         nullptr, v1bf, v2bf);
  // context (reads mxV with inline sV*relu)
  context_kernel<<<dim3(32, NHEADS), 256, 0, stream>>>(v2bf, mxV, scaleV, denom, mask, ctxT);
  // combnorm aliases mxV: zero only after context consumed mxV
  hipMemsetAsync(combnorm, 0, N_NODES * sizeof(float), stream);
  // attention out -> combHi + row norms
  out_mfma_kernel<<<dim3(N_NODES / 256, NHEADS), 256, 0, stream>>>(v1bf, v2sum, ctxT, combHi,
                                                                   combnorm);
  // final: single bf16 GEMM comb@Wff -> outBf, then rowtrans -> d_out
  transW_kernel<<<tgrid, 256, 0, stream>>>(Wff, WffHi);
  gemm_bf<0, 4><<<256, 512, 0, stream>>>(combHi, WffHi, nullptr, nullptr, nullptr, nullptr,
                                         nullptr, nullptr, nullptr, outBf, nullptr);
  rowtrans_kernel<<<N_NODES, 256, 0, stream>>>(outBf, combnorm, out);
}

// Round 15
// 370.242 us; speedup vs baseline: 1.8676x; 1.0805x over previous
//
#include <hip/hip_runtime.h>
#include <hip/hip_bf16.h>
#include <math.h>

#define N_NODES 16384
#define DIMV 1024
#define NHEADS 16
#define HEADD 64

typedef __attribute__((ext_vector_type(8))) short short8;
typedef __attribute__((ext_vector_type(4))) float f32x4;
typedef unsigned short ushort_t;

// async global->LDS, 16B per lane
#define GLD16(gptr, lptr)                                                                 \
  __builtin_amdgcn_global_load_lds((const __attribute__((address_space(1))) void*)(gptr), \
                                   (__attribute__((address_space(3))) void*)(lptr), 16, 0, 0)

// ---------- helpers ----------

__device__ __forceinline__ float waveReduceSum(float v) {
#pragma unroll
  for (int m = 32; m; m >>= 1) v += __shfl_xor(v, m);
  return v;
}

__device__ __forceinline__ float blockReduceSum(float v, float* red) {
  float w = waveReduceSum(v);
  __syncthreads();
  if ((threadIdx.x & 63) == 0) red[threadIdx.x >> 6] = w;
  __syncthreads();
  return red[0] + red[1] + red[2] + red[3];
}

// elu(z)+1: z>0 -> z+1; z<=0 -> expm1(z)+1 == e^z (exact identity).
// __expf = v_mul + v_exp_f32 (~1e-6 rel, far below bf16 rounding of v1/v2).
__device__ __forceinline__ float elup1_fast(float z) {
  return z > 0.0f ? z + 1.0f : __expf(z);
}

__device__ __forceinline__ float clampabs(float x, float eps) {
  float s = (x >= 0.0f) ? 1.0f : -1.0f;
  return s * fmaxf(fabsf(x), eps);
}

// fp32 -> bf16 bits, RNE
__device__ __forceinline__ ushort_t f2b(float x) {
  unsigned u = __float_as_uint(x);
  unsigned r = (u + 0x7FFFu + ((u >> 16) & 1u)) >> 16;
  return (ushort_t)r;
}
__device__ __forceinline__ float b2f(ushort_t h) {
  return __uint_as_float(((unsigned)h) << 16);
}

// ---------- X -> bf16 + row sumsq (one block per row) ----------
__global__ __launch_bounds__(256) void cvt_norm_kernel(const float* __restrict__ src,
                                                       ushort_t* __restrict__ dst,
                                                       float* __restrict__ rowsq) {
  __shared__ float red[4];
  const int row = blockIdx.x;
  const int t = threadIdx.x;
  float4 x4 = ((const float4*)(src + (size_t)row * DIMV))[t];
  ushort_t h[4] = {f2b(x4.x), f2b(x4.y), f2b(x4.z), f2b(x4.w)};
  ((uint2*)(dst + (size_t)row * DIMV))[t] = *(uint2*)h;
  float s = x4.x * x4.x + x4.y * x4.y + x4.z * x4.z + x4.w * x4.w;
  s = blockReduceSum(s, red);
  if (t == 0) rowsq[row] = s;
}

// ---------- weight transpose -> bf16 ----------
__global__ __launch_bounds__(256) void transW_kernel(const float* __restrict__ src,
                                                     ushort_t* __restrict__ hi) {
  __shared__ float tile[32][33];
  const int bx = blockIdx.x * 32, by = blockIdx.y * 32;
  const int tx = threadIdx.x & 31, ty = threadIdx.x >> 5;
#pragma unroll
  for (int i = 0; i < 32; i += 8) tile[ty + i][tx] = src[(size_t)(by + ty + i) * DIMV + bx + tx];
  __syncthreads();
#pragma unroll
  for (int i = 0; i < 32; i += 8)
    hi[(size_t)(bx + ty + i) * DIMV + by + tx] = f2b(tile[tx][ty + i]);
}

// fused triple transpose: z=0 Wq->d0, z=1 Wk->d1, z=2 Wv->d2
__global__ __launch_bounds__(256) void transW3_kernel(const float* __restrict__ s0,
                                                      const float* __restrict__ s1,
                                                      const float* __restrict__ s2,
                                                      ushort_t* __restrict__ d0,
                                                      ushort_t* __restrict__ d1,
                                                      ushort_t* __restrict__ d2) {
  __shared__ float tile[32][33];
  const float* src = (blockIdx.z == 0) ? s0 : (blockIdx.z == 1) ? s1 : s2;
  ushort_t* dst = (blockIdx.z == 0) ? d0 : (blockIdx.z == 1) ? d1 : d2;
  const int bx = blockIdx.x * 32, by = blockIdx.y * 32;
  const int tx = threadIdx.x & 31, ty = threadIdx.x >> 5;
#pragma unroll
  for (int i = 0; i < 32; i += 8) tile[ty + i][tx] = src[(size_t)(by + ty + i) * DIMV + bx + tx];
  __syncthreads();
#pragma unroll
  for (int i = 0; i < 32; i += 8)
    dst[(size_t)(bx + ty + i) * DIMV + by + tx] = f2b(tile[tx][ty + i]);
}

// 128B-row k-unit swizzle (BK=64, r13-verified, bank-conflict = 0):
// LDS[row][u] = global unit u ^ (row&7); staging src unit (lane&7)^((lane>>3)&7);
// fragment read unit ((ks*4+g) ^ (l15&7)).

// ---------- bf16 MFMA GEMM, 256x256 tile, BK=64, 8 waves, dbuf 2-phase, swizzled ----------
// EPI 0: Cq = bf16(acc)                                  (plain: final comb@Wff)
// EPI 3: cols<1024 -> Cq=bf16(v1); cols>=1024 -> Ck=bf16(v2)+v2sum atomics (QK fused)
// EPI 4: Cq = bf16(acc) + per-(row,head) stats {sum mx^2, sum relu(mx)^2} (V path)
template <int EPI, int NB>
__global__ __launch_bounds__(512, 2) void gemm_bf(const ushort_t* __restrict__ A,
                                                  const ushort_t* __restrict__ Bt,
                                                  const float* __restrict__ biasQ,
                                                  const float* __restrict__ biasK,
                                                  const float* __restrict__ denom,
                                                  const float* __restrict__ mask,
                                                  float* __restrict__ v2sum,
                                                  float* __restrict__ mxhsq,
                                                  float* __restrict__ reluhsq,
                                                  ushort_t* __restrict__ Cq,
                                                  ushort_t* __restrict__ Ck) {
  __shared__ ushort_t As[2][256 * 64];  // 32 KB per buf
  __shared__ ushort_t Bs[2][256 * 64];
  const int bid = blockIdx.x;
  const int nwg = NB * 64;
  const int swz = (bid & 7) * (nwg / 8) + (bid >> 3);
  const int bm = (swz / NB) * 256;
  const int bn = (swz % NB) * 256;
  const int t = threadIdx.x;
  const int w = t >> 6, lane = t & 63, l15 = lane & 15;
  const int wr = (w >> 2) * 128;
  const int wcn = (w & 3) * 64;
  const int g4 = lane >> 4;
  const int e7 = l15 & 7;
  const int uo0 = (g4 ^ e7) * 8;
  const int uo1 = ((4 + g4) ^ e7) * 8;

  const int rowin = lane >> 3;
  const int ksh = ((lane & 7) ^ ((lane >> 3) & 7)) * 8;
  const ushort_t *gA[4], *gB[4];
  int lofs[4];
#pragma unroll
  for (int c = 0; c < 4; ++c) {
    const int ch = w + 8 * c;
    lofs[c] = ch * 512;
    gA[c] = A + (size_t)(bm + ch * 8 + rowin) * DIMV + ksh;
    gB[c] = Bt + (size_t)(bn + ch * 8 + rowin) * DIMV + ksh;
  }

#define STAGE_G(buf, k0)                              \
  do {                                                \
    _Pragma("unroll") for (int c = 0; c < 4; ++c) {   \
      GLD16(gA[c] + (k0), &As[buf][lofs[c]]);         \
      GLD16(gB[c] + (k0), &Bs[buf][lofs[c]]);         \
    }                                                 \
  } while (0)

  f32x4 acc[8][4];
#pragma unroll
  for (int i = 0; i < 8; ++i)
#pragma unroll
    for (int j = 0; j < 4; ++j) acc[i][j] = (f32x4){0.f, 0.f, 0.f, 0.f};

  STAGE_G(0, 0);
  __syncthreads();
  int cur = 0;
  for (int k0 = 0; k0 < DIMV; k0 += 64) {
    if (k0 + 64 < DIMV) STAGE_G(cur ^ 1, k0 + 64);
#pragma unroll
    for (int ks = 0; ks < 2; ++ks) {
      const int uo = ks ? uo1 : uo0;
      short8 bf[4];
#pragma unroll
      for (int j = 0; j < 4; ++j)
        bf[j] = *(const short8*)&Bs[cur][(wcn + j * 16 + l15) * 64 + uo];
#pragma unroll
      for (int i = 0; i < 8; ++i) {
        short8 af = *(const short8*)&As[cur][(wr + i * 16 + l15) * 64 + uo];
#pragma unroll
        for (int j = 0; j < 4; ++j)
          acc[i][j] = __builtin_amdgcn_mfma_f32_16x16x32_bf16(af, bf[j], acc[i][j], 0, 0, 0);
      }
    }
    __syncthreads();
    cur ^= 1;
  }
#undef STAGE_G

  // epilogue. C/D layout: col = lane&15, row = (lane>>4)*4 + r
  const int rbase = (lane >> 4) * 4;
  if (EPI == 0) {
#pragma unroll
    for (int j = 0; j < 4; ++j) {
      const int col = bn + wcn + j * 16 + l15;
#pragma unroll
      for (int i = 0; i < 8; ++i)
#pragma unroll
        for (int r = 0; r < 4; ++r)
          Cq[(size_t)(bm + wr + i * 16 + rbase + r) * DIMV + col] = f2b(acc[i][j][r]);
    }
  } else if (EPI == 4) {
    // V path: bf16 store + per-(row,head) stats. Each (row,head) owned by exactly one
    // wave (wr x wcn partition) -> plain stores, no atomics. 16-lane shfl reduce over l15.
    const int h = ((bn + wcn) >> 6) & (NHEADS - 1);
#pragma unroll
    for (int i = 0; i < 8; ++i) {
#pragma unroll
      for (int r = 0; r < 4; ++r) {
        const int row = bm + wr + i * 16 + rbase + r;
        float smx = 0.f, srel = 0.f;
#pragma unroll
        for (int j = 0; j < 4; ++j) {
          float val = acc[i][j][r];
          Cq[(size_t)row * DIMV + bn + wcn + j * 16 + l15] = f2b(val);
          smx = fmaf(val, val, smx);
          float rv = fmaxf(val, 0.f);
          srel = fmaf(rv, rv, srel);
        }
        smx += __shfl_xor(smx, 1); smx += __shfl_xor(smx, 2);
        smx += __shfl_xor(smx, 4); smx += __shfl_xor(smx, 8);
        srel += __shfl_xor(srel, 1); srel += __shfl_xor(srel, 2);
        srel += __shfl_xor(srel, 4); srel += __shfl_xor(srel, 8);
        if (l15 == 0) {
          mxhsq[(size_t)h * N_NODES + row] = smx;
          reluhsq[(size_t)h * N_NODES + row] = srel;
        }
      }
    }
  } else {
    const bool isK = (bn >= DIMV);  // block-uniform
    const int h = ((bn + wcn) >> 6) & (NHEADS - 1);
    int lc[4];
    float bb[4];
#pragma unroll
    for (int j = 0; j < 4; ++j) {
      lc[j] = (bn + wcn + j * 16 + l15) & (DIMV - 1);
      bb[j] = isK ? biasK[lc[j]] : biasQ[lc[j]];
    }
    float csum[4] = {0.f, 0.f, 0.f, 0.f};
#pragma unroll
    for (int i = 0; i < 8; ++i) {
#pragma unroll
      for (int r = 0; r < 4; ++r) {
        const int row = bm + wr + i * 16 + rbase + r;
        const float invdp = 1.0f / denom[(size_t)h * N_NODES + row];
        float den = 0.f, mk = 0.f;
        if (isK) {
          den = clampabs(2.0f * invdp - 1.0f, 1e-10f);
          mk = mask[row];
        }
#pragma unroll
        for (int j = 0; j < 4; ++j) {
          float val = elup1_fast((acc[i][j][r] + bb[j]) * invdp);
          if (isK) {
            val = den * val * mk;
            csum[j] += val;
            Ck[(size_t)row * DIMV + lc[j]] = f2b(val);
          } else {
            Cq[(size_t)row * DIMV + lc[j]] = f2b(val);
          }
        }
      }
    }
    if (isK) {
#pragma unroll
      for (int j = 0; j < 4; ++j) atomicAdd(&v2sum[lc[j]], csum[j]);
    }
  }
}

// ---------- vscale: per-row mobius+kappa scalars from stats; emits scaleV + denom ----------
__global__ __launch_bounds__(256) void vscale_kernel(const float* __restrict__ xnormsq,
                                                     const float* __restrict__ mxhsq,
                                                     const float* __restrict__ reluhsq,
                                                     float* __restrict__ scaleV,
                                                     float* __restrict__ denom) {
  const int row = blockIdx.x * 256 + threadIdx.x;
  float sm = 0.f, sr = 0.f;
  float hs[NHEADS];
#pragma unroll
  for (int h = 0; h < NHEADS; ++h) {
    sm += mxhsq[(size_t)h * N_NODES + row];
    hs[h] = reluhsq[(size_t)h * N_NODES + row];
    sr += hs[h];
  }
  float sx = xnormsq[row];
  float xn = fmaxf(sqrtf(sx), 1e-15f);
  float mxn = fmaxf(sqrtf(sm), 1e-15f);
  float cx = fminf(xn, 1.0f - 1e-7f);
  float t1 = tanhf(mxn / xn * atanhf(cx));
  float s1 = t1 / mxn;
  float yn = fmaxf(fabsf(t1), 1e-15f);
  float a = atanhf(fminf(yn, 1.0f - 1e-7f)) / yn;
  float k1 = a * s1;
  float un = fmaxf(k1 * sqrtf(sr), 1e-15f);
  float t2 = tanhf(un);
  float s2 = t2 / un;
  if (t2 > 0.996f) s2 *= 0.996f / t2;
  float sV = s2 * k1;
  scaleV[row] = sV;
#pragma unroll
  for (int h = 0; h < NHEADS; ++h)
    denom[(size_t)h * N_NODES + row] = fmaxf(1.0f - sV * sV * hs[h], 1e-15f);
}

// ---------- row transform (final): mobius_matvec tail + kappa_relu ----------
__global__ __launch_bounds__(256) void rowtrans_kernel(const ushort_t* __restrict__ msrc,
                                                       const float* __restrict__ rowsq,
                                                       float* __restrict__ dstv) {
  __shared__ float red[4];
  const int row = blockIdx.x;
  const int t = threadIdx.x;
  uint2 mraw = ((const uint2*)(msrc + (size_t)row * DIMV))[t];
  ushort_t* mh = (ushort_t*)&mraw;
  float4 m4 = make_float4(b2f(mh[0]), b2f(mh[1]), b2f(mh[2]), b2f(mh[3]));
  float sm = m4.x * m4.x + m4.y * m4.y + m4.z * m4.z + m4.w * m4.w;
  sm = blockReduceSum(sm, red);
  float sx = rowsq[row];

  float xn = fmaxf(sqrtf(sx), 1e-15f);
  float mxn = fmaxf(sqrtf(sm), 1e-15f);
  float cx = fminf(xn, 1.0f - 1e-7f);
  float t1 = tanhf(mxn / xn * atanhf(cx));
  float s1 = t1 / mxn;

  float yn = fmaxf(fabsf(t1), 1e-15f);
  float a = atanhf(fminf(yn, 1.0f - 1e-7f)) / yn;
  float k1 = a * s1;
  float4 u = make_float4(fmaxf(k1 * m4.x, 0.0f), fmaxf(k1 * m4.y, 0.0f),
                         fmaxf(k1 * m4.z, 0.0f), fmaxf(k1 * m4.w, 0.0f));
  float su = u.x * u.x + u.y * u.y + u.z * u.z + u.w * u.w;
  su = blockReduceSum(su, red);

  float un = fmaxf(sqrtf(su), 1e-15f);
  float t2 = tanhf(un);
  float s2 = t2 / un;
  if (t2 > 0.996f) s2 *= 0.996f / t2;
  float4 o = make_float4(s2 * u.x, s2 * u.y, s2 * u.z, s2 * u.w);
  ((float4*)(dstv + (size_t)row * DIMV))[t] = o;
}

// ---------- ctxT[h][e][d] = sum_n v2[h,n,d] * (gamma/den*mask*sV*relu(mx))[h,n,e] ----------
__global__ __launch_bounds__(256) void context_kernel(const ushort_t* __restrict__ v2buf,
                                                      const ushort_t* __restrict__ mxVbuf,
                                                      const float* __restrict__ scaleV,
                                                      const float* __restrict__ denom,
                                                      const float* __restrict__ mask,
                                                      float* __restrict__ ctxT) {
  __shared__ float s2[64][65];
  __shared__ float sx[64][65];
  const int h = blockIdx.y;
  const int t = threadIdx.x;
  const int d0 = (t >> 4) * 4;
  const int e0 = (t & 15) * 4;
  float acc[4][4];
#pragma unroll
  for (int i = 0; i < 4; ++i)
#pragma unroll
    for (int j = 0; j < 4; ++j) acc[i][j] = 0.0f;

  const int rbase = blockIdx.x * 512;
  for (int c = 0; c < 8; ++c) {
#pragma unroll
    for (int i = 0; i < 4; ++i) {
      int f = i * 256 + t;
      int r = f >> 4;
      int cc = (f & 15) * 4;
      int row = rbase + c * 64 + r;
      uint2 araw = *(const uint2*)(v2buf + (size_t)row * DIMV + h * HEADD + cc);
      ushort_t* ah = (ushort_t*)&araw;
      s2[r][cc + 0] = b2f(ah[0]); s2[r][cc + 1] = b2f(ah[1]);
      s2[r][cc + 2] = b2f(ah[2]); s2[r][cc + 3] = b2f(ah[3]);
      float dp = denom[(size_t)h * N_NODES + row];
      float gamma = 2.0f / dp;
      float den = clampabs(gamma - 1.0f, 1e-10f);
      float c1 = gamma / den * mask[row] * scaleV[row];
      uint2 braw = *(const uint2*)(mxVbuf + (size_t)row * DIMV + h * HEADD + cc);
      ushort_t* bh = (ushort_t*)&braw;
      sx[r][cc + 0] = c1 * fmaxf(b2f(bh[0]), 0.f); sx[r][cc + 1] = c1 * fmaxf(b2f(bh[1]), 0.f);
      sx[r][cc + 2] = c1 * fmaxf(b2f(bh[2]), 0.f); sx[r][cc + 3] = c1 * fmaxf(b2f(bh[3]), 0.f);
    }
    __syncthreads();
    for (int r = 0; r < 64; ++r) {
      float av[4], bv[4];
#pragma unroll
      for (int i = 0; i < 4; ++i) av[i] = s2[r][d0 + i];
#pragma unroll
      for (int j = 0; j < 4; ++j) bv[j] = sx[r][e0 + j];
#pragma unroll
      for (int i = 0; i < 4; ++i)
#pragma unroll
        for (int j = 0; j < 4; ++j) acc[i][j] = fmaf(av[i], bv[j], acc[i][j]);
    }
    __syncthreads();
  }
#pragma unroll
  for (int i = 0; i < 4; ++i)
#pragma unroll
    for (int j = 0; j < 4; ++j)
      atomicAdd(&ctxT[h * 4096 + (e0 + j) * 64 + (d0 + i)], acc[i][j]);
}

// ---------- out (MFMA): [out|D] = v1 @ [ctx|v2sum]; tail; emit combHi + rownorm atomics ----------
__global__ __launch_bounds__(256) void out_mfma_kernel(const ushort_t* __restrict__ v1bf,
                                                       const float* __restrict__ v2sum,
                                                       const float* __restrict__ ctxT,
                                                       ushort_t* __restrict__ combHi,
                                                       float* __restrict__ combnorm) {
  __shared__ ushort_t Blds[80][88];
  const int h = blockIdx.y;
  const int bm = blockIdx.x * 256;
  const int t = threadIdx.x;
  const int w = t >> 6, lane = t & 63, l15 = lane & 15;
  const int kk = (lane >> 4) * 8;

  for (int idx = t; idx < 80 * 64; idx += 256) {
    int e = idx >> 6, d = idx & 63;
    float v = 0.0f;
    if (e < 64) v = ctxT[h * 4096 + e * 64 + d];
    else if (e == 64) v = v2sum[h * 64 + d];
    Blds[e][d] = f2b(v);
  }
  __syncthreads();

  f32x4 acc[4][5];
#pragma unroll
  for (int i = 0; i < 4; ++i)
#pragma unroll
    for (int j = 0; j < 5; ++j) acc[i][j] = (f32x4){0.f, 0.f, 0.f, 0.f};
#pragma unroll
  for (int ks = 0; ks < 2; ++ks) {
    short8 bfr[5];
#pragma unroll
    for (int j = 0; j < 5; ++j) bfr[j] = *(const short8*)&Blds[j * 16 + l15][ks * 32 + kk];
#pragma unroll
    for (int i = 0; i < 4; ++i) {
      short8 af = *(const short8*)(v1bf + (size_t)(bm + w * 64 + i * 16 + l15) * DIMV +
                                   h * HEADD + ks * 32 + kk);
#pragma unroll
      for (int j = 0; j < 5; ++j)
        acc[i][j] = __builtin_amdgcn_mfma_f32_16x16x32_bf16(af, bfr[j], acc[i][j], 0, 0, 0);
    }
  }

  const int g4 = (lane >> 4) * 4;
#pragma unroll
  for (int i = 0; i < 4; ++i) {
#pragma unroll
    for (int r = 0; r < 4; ++r) {
      const int row = bm + w * 64 + i * 16 + g4 + r;
      float D = __shfl(acc[i][4][r], lane & 48);
      float Dinv = 1.0f / (D == 0.0f ? 1e-5f : D);
      float o[4];
      float s = 0.0f;
#pragma unroll
      for (int j = 0; j < 4; ++j) {
        o[j] = acc[i][j][r] * Dinv;
        s = fmaf(o[j], o[j], s);
      }
      s += __shfl_xor(s, 1); s += __shfl_xor(s, 2);
      s += __shfl_xor(s, 4); s += __shfl_xor(s, 8);
      float n1 = fmaxf(sqrtf(s), 1e-15f);
      float sc = 1.0f;
      if (n1 > 0.996f) sc = 0.996f / n1;
      float xn = fmaxf(fminf(n1, 0.996f), 1e-15f);
      float cx = fminf(xn, 1.0f - 1e-7f);
      // tanh(0.5*atanh(cx)) == cx / (1 + sqrt(1 - cx^2))  [exact identity];
      // t2 <= 0.915 < 0.996 so the post-mobius projection can never fire.
      float t2 = cx / (1.0f + sqrtf(1.0f - cx * cx));
      sc *= t2 / xn;
      if (l15 == 0) atomicAdd(&combnorm[row], s * sc * sc);
#pragma unroll
      for (int j = 0; j < 4; ++j) {
        float ov = o[j] * sc;
        combHi[(size_t)row * DIMV + h * HEADD + j * 16 + l15] = f2b(ov);
      }
    }
  }
}

// ---------- launch ----------

extern "C" void kernel_launch(void* const* d_in, const int* in_sizes, int n_in,
                              void* d_out, int out_size, void* d_ws, size_t ws_size,
                              hipStream_t stream) {
  const float* X = (const float*)d_in[0];
  const float* mask = (const float*)d_in[1];
  const float* Wq = (const float*)d_in[2];
  const float* bq = (const float*)d_in[3];
  const float* Wk = (const float*)d_in[4];
  const float* bk = (const float*)d_in[5];
  const float* Wv = (const float*)d_in[6];
  const float* Wff = (const float*)d_in[7];
  float* out = (float*)d_out;

  const size_t MAT = (size_t)N_NODES * DIMV;
  char* p = (char*)d_ws;
  // R1 (64MB): first half v1bf (QK epi out); second half mxV bf16, later combnorm
  ushort_t* v1bf = (ushort_t*)p;
  ushort_t* mxV = (ushort_t*)(p + MAT * 2);
  float* combnorm = (float*)(p + MAT * 2);
  p += MAT * 4;
  // R2 (64MB): xnormsq (early) / v2bf (QK epi out) / combHi (after context)
  float* xnormsq = (float*)p;
  ushort_t* v2bf = (ushort_t*)p;
  ushort_t* combHi = (ushort_t*)p;
  p += MAT * 4;
  // R3 (32MB): WffHi
  ushort_t* WffHi = (ushort_t*)p;
  p += MAT * 2;
  // R4 (32MB): Xbf; later outBf (final gemm out)
  ushort_t* Xbf = (ushort_t*)p;
  ushort_t* outBf = Xbf;
  p += MAT * 2;
  float* denom = (float*)p;   p += (size_t)NHEADS * N_NODES * 4;
  float* v2sum = (float*)p;   p += 1024 * 4;
  float* ctxT = (float*)p;    p += (size_t)NHEADS * 4096 * 4;
  float* mxhsq = (float*)p;   p += (size_t)NHEADS * N_NODES * 4;
  float* reluhsq = (float*)p; p += (size_t)NHEADS * N_NODES * 4;
  float* scaleV = (float*)p;  p += (size_t)N_NODES * 4;
  const size_t need = (size_t)(p - (char*)d_ws);
  if (ws_size < need) return;

  // W^T bf16 scratch inside d_out (free until the final rowtrans writes it):
  ushort_t* Wt = (ushort_t*)d_out;            // Wq^T (rows 0..1023 of stacked QK)
  ushort_t* WtK = Wt + (size_t)DIMV * DIMV;   // Wk^T (rows 1024..2047)
  ushort_t* WtV = WtK + (size_t)DIMV * DIMV;  // Wv^T

  dim3 tgrid(32, 32);

  cvt_norm_kernel<<<N_NODES, 256, 0, stream>>>(X, Xbf, xnormsq);
  transW3_kernel<<<dim3(32, 32, 3), 256, 0, stream>>>(Wq, Wk, Wv, Wt, WtK, WtV);
  // V path: mxV bf16 + per-(row,head) stats; then closed-form scaleV + denom
  gemm_bf<4, 4><<<256, 512, 0, stream>>>(Xbf, WtV, nullptr, nullptr, nullptr, nullptr,
                                         nullptr, mxhsq, reluhsq, mxV, nullptr);
  vscale_kernel<<<N_NODES / 256, 256, 0, stream>>>(xnormsq, mxhsq, reluhsq, scaleV, denom);
  // zero v2sum + ctxT (contiguous)
  hipMemsetAsync(v2sum, 0, (1024 + 4096 * NHEADS) * sizeof(float), stream);
  // QK fused: stacked [Wq^T; Wk^T]; emits v1 (cols<1024) and v2 + v2sum (cols>=1024)
  gemm_bf<3, 8><<<512, 512, 0, stream>>>(Xbf, Wt, bq, bk, denom, mask, v2sum, nullptr,
                                         nullptr, v1bf, v2bf);
  // context (reads mxV with inline sV*relu)
  context_kernel<<<dim3(32, NHEADS), 256, 0, stream>>>(v2bf, mxV, scaleV, denom, mask, ctxT);
  // combnorm aliases mxV: zero only after context consumed mxV
  hipMemsetAsync(combnorm, 0, N_NODES * sizeof(float), stream);
  // attention out -> combHi + row norms
  out_mfma_kernel<<<dim3(N_NODES / 256, NHEADS), 256, 0, stream>>>(v1bf, v2sum, ctxT, combHi,
                                                                   combnorm);
  // final: single bf16 GEMM comb@Wff -> outBf, then rowtrans -> d_out
  transW_kernel<<<tgrid, 256, 0, stream>>>(Wff, WffHi);
  gemm_bf<0, 4><<<256, 512, 0, stream>>>(combHi, WffHi, nullptr, nullptr, nullptr, nullptr,
                                         nullptr, nullptr, nullptr, outBf, nullptr);
  rowtrans_kernel<<<N_NODES, 256, 0, stream>>>(outBf, combnorm, out);
}

// Round 16
// 350.157 us; speedup vs baseline: 1.9747x; 1.0574x over previous
//
#include <hip/hip_runtime.h>
#include <hip/hip_bf16.h>
#include <math.h>

#define N_NODES 16384
#define DIMV 1024
#define NHEADS 16
#define HEADD 64

typedef __attribute__((ext_vector_type(8))) short short8;
typedef __attribute__((ext_vector_type(4))) float f32x4;
typedef unsigned short ushort_t;

// async global->LDS, 16B per lane
#define GLD16(gptr, lptr)                                                                 \
  __builtin_amdgcn_global_load_lds((const __attribute__((address_space(1))) void*)(gptr), \
                                   (__attribute__((address_space(3))) void*)(lptr), 16, 0, 0)

// ---------- helpers ----------

__device__ __forceinline__ float waveReduceSum(float v) {
#pragma unroll
  for (int m = 32; m; m >>= 1) v += __shfl_xor(v, m);
  return v;
}

__device__ __forceinline__ float blockReduceSum(float v, float* red) {
  float w = waveReduceSum(v);
  __syncthreads();
  if ((threadIdx.x & 63) == 0) red[threadIdx.x >> 6] = w;
  __syncthreads();
  return red[0] + red[1] + red[2] + red[3];
}

// elu(z)+1: z>0 -> z+1; z<=0 -> expm1(z)+1 == e^z (exact identity).
__device__ __forceinline__ float elup1_fast(float z) {
  return z > 0.0f ? z + 1.0f : __expf(z);
}

__device__ __forceinline__ float clampabs(float x, float eps) {
  float s = (x >= 0.0f) ? 1.0f : -1.0f;
  return s * fmaxf(fabsf(x), eps);
}

// fp32 -> bf16 bits, RNE
__device__ __forceinline__ ushort_t f2b(float x) {
  unsigned u = __float_as_uint(x);
  unsigned r = (u + 0x7FFFu + ((u >> 16) & 1u)) >> 16;
  return (ushort_t)r;
}
__device__ __forceinline__ float b2f(ushort_t h) {
  return __uint_as_float(((unsigned)h) << 16);
}

// ---------- X -> bf16 + row sumsq (one block per row) ----------
__global__ __launch_bounds__(256) void cvt_norm_kernel(const float* __restrict__ src,
                                                       ushort_t* __restrict__ dst,
                                                       float* __restrict__ rowsq) {
  __shared__ float red[4];
  const int row = blockIdx.x;
  const int t = threadIdx.x;
  float4 x4 = ((const float4*)(src + (size_t)row * DIMV))[t];
  ushort_t h[4] = {f2b(x4.x), f2b(x4.y), f2b(x4.z), f2b(x4.w)};
  ((uint2*)(dst + (size_t)row * DIMV))[t] = *(uint2*)h;
  float s = x4.x * x4.x + x4.y * x4.y + x4.z * x4.z + x4.w * x4.w;
  s = blockReduceSum(s, red);
  if (t == 0) rowsq[row] = s;
}

// ---------- weight transpose -> bf16 ----------
__global__ __launch_bounds__(256) void transW_kernel(const float* __restrict__ src,
                                                     ushort_t* __restrict__ hi) {
  __shared__ float tile[32][33];
  const int bx = blockIdx.x * 32, by = blockIdx.y * 32;
  const int tx = threadIdx.x & 31, ty = threadIdx.x >> 5;
#pragma unroll
  for (int i = 0; i < 32; i += 8) tile[ty + i][tx] = src[(size_t)(by + ty + i) * DIMV + bx + tx];
  __syncthreads();
#pragma unroll
  for (int i = 0; i < 32; i += 8)
    hi[(size_t)(bx + ty + i) * DIMV + by + tx] = f2b(tile[tx][ty + i]);
}

// fused triple transpose: z=0 Wq->d0, z=1 Wk->d1, z=2 Wv->d2
__global__ __launch_bounds__(256) void transW3_kernel(const float* __restrict__ s0,
                                                      const float* __restrict__ s1,
                                                      const float* __restrict__ s2,
                                                      ushort_t* __restrict__ d0,
                                                      ushort_t* __restrict__ d1,
                                                      ushort_t* __restrict__ d2) {
  __shared__ float tile[32][33];
  const float* src = (blockIdx.z == 0) ? s0 : (blockIdx.z == 1) ? s1 : s2;
  ushort_t* dst = (blockIdx.z == 0) ? d0 : (blockIdx.z == 1) ? d1 : d2;
  const int bx = blockIdx.x * 32, by = blockIdx.y * 32;
  const int tx = threadIdx.x & 31, ty = threadIdx.x >> 5;
#pragma unroll
  for (int i = 0; i < 32; i += 8) tile[ty + i][tx] = src[(size_t)(by + ty + i) * DIMV + bx + tx];
  __syncthreads();
#pragma unroll
  for (int i = 0; i < 32; i += 8)
    dst[(size_t)(bx + ty + i) * DIMV + by + tx] = f2b(tile[tx][ty + i]);
}

// 128B-row k-unit swizzle (BK=64, r13-verified, bank-conflict = 0):
// LDS[row][u] = global unit u ^ (row&7); staging src unit (lane&7)^((lane>>3)&7);
// fragment read unit ((ks*4+g) ^ (l15&7)).

// ---------- bf16 MFMA GEMM, 256x256 tile, BK=64, 8 waves, dbuf 2-phase, swizzled ----------
// EPI 0: Cq = bf16(acc)                                  (plain: final comb@Wff)
// EPI 3: cols<1024 -> Cq=bf16(v1); cols>=1024 -> Ck=bf16(v2)+v2sum atomics (QK fused)
// EPI 4: Cq = bf16(acc) + per-(row,head) stats {sum mx^2, sum relu(mx)^2} (V path)
template <int EPI, int NB>
__global__ __launch_bounds__(512, 2) void gemm_bf(const ushort_t* __restrict__ A,
                                                  const ushort_t* __restrict__ Bt,
                                                  const float* __restrict__ biasQ,
                                                  const float* __restrict__ biasK,
                                                  const float* __restrict__ denom,
                                                  const float* __restrict__ mask,
                                                  float* __restrict__ v2sum,
                                                  float* __restrict__ mxhsq,
                                                  float* __restrict__ reluhsq,
                                                  ushort_t* __restrict__ Cq,
                                                  ushort_t* __restrict__ Ck) {
  __shared__ ushort_t As[2][256 * 64];  // 32 KB per buf
  __shared__ ushort_t Bs[2][256 * 64];
  const int bid = blockIdx.x;
  const int nwg = NB * 64;
  const int swz = (bid & 7) * (nwg / 8) + (bid >> 3);
  const int bm = (swz / NB) * 256;
  const int bn = (swz % NB) * 256;
  const int t = threadIdx.x;
  const int w = t >> 6, lane = t & 63, l15 = lane & 15;
  const int wr = (w >> 2) * 128;
  const int wcn = (w & 3) * 64;
  const int g4 = lane >> 4;
  const int e7 = l15 & 7;
  const int uo0 = (g4 ^ e7) * 8;
  const int uo1 = ((4 + g4) ^ e7) * 8;

  const int rowin = lane >> 3;
  const int ksh = ((lane & 7) ^ ((lane >> 3) & 7)) * 8;
  const ushort_t *gA[4], *gB[4];
  int lofs[4];
#pragma unroll
  for (int c = 0; c < 4; ++c) {
    const int ch = w + 8 * c;
    lofs[c] = ch * 512;
    gA[c] = A + (size_t)(bm + ch * 8 + rowin) * DIMV + ksh;
    gB[c] = Bt + (size_t)(bn + ch * 8 + rowin) * DIMV + ksh;
  }

#define STAGE_G(buf, k0)                              \
  do {                                                \
    _Pragma("unroll") for (int c = 0; c < 4; ++c) {   \
      GLD16(gA[c] + (k0), &As[buf][lofs[c]]);         \
      GLD16(gB[c] + (k0), &Bs[buf][lofs[c]]);         \
    }                                                 \
  } while (0)

  f32x4 acc[8][4];
#pragma unroll
  for (int i = 0; i < 8; ++i)
#pragma unroll
    for (int j = 0; j < 4; ++j) acc[i][j] = (f32x4){0.f, 0.f, 0.f, 0.f};

  STAGE_G(0, 0);
  __syncthreads();
  int cur = 0;
  for (int k0 = 0; k0 < DIMV; k0 += 64) {
    if (k0 + 64 < DIMV) STAGE_G(cur ^ 1, k0 + 64);
#pragma unroll
    for (int ks = 0; ks < 2; ++ks) {
      const int uo = ks ? uo1 : uo0;
      short8 bf[4];
#pragma unroll
      for (int j = 0; j < 4; ++j)
        bf[j] = *(const short8*)&Bs[cur][(wcn + j * 16 + l15) * 64 + uo];
#pragma unroll
      for (int i = 0; i < 8; ++i) {
        short8 af = *(const short8*)&As[cur][(wr + i * 16 + l15) * 64 + uo];
#pragma unroll
        for (int j = 0; j < 4; ++j)
          acc[i][j] = __builtin_amdgcn_mfma_f32_16x16x32_bf16(af, bf[j], acc[i][j], 0, 0, 0);
      }
    }
    __syncthreads();
    cur ^= 1;
  }
#undef STAGE_G

  // epilogue. C/D layout: col = lane&15, row = (lane>>4)*4 + r
  const int rbase = (lane >> 4) * 4;
  if (EPI == 0) {
#pragma unroll
    for (int j = 0; j < 4; ++j) {
      const int col = bn + wcn + j * 16 + l15;
#pragma unroll
      for (int i = 0; i < 8; ++i)
#pragma unroll
        for (int r = 0; r < 4; ++r)
          Cq[(size_t)(bm + wr + i * 16 + rbase + r) * DIMV + col] = f2b(acc[i][j][r]);
    }
  } else if (EPI == 4) {
    const int h = ((bn + wcn) >> 6) & (NHEADS - 1);
#pragma unroll
    for (int i = 0; i < 8; ++i) {
#pragma unroll
      for (int r = 0; r < 4; ++r) {
        const int row = bm + wr + i * 16 + rbase + r;
        float smx = 0.f, srel = 0.f;
#pragma unroll
        for (int j = 0; j < 4; ++j) {
          float val = acc[i][j][r];
          Cq[(size_t)row * DIMV + bn + wcn + j * 16 + l15] = f2b(val);
          smx = fmaf(val, val, smx);
          float rv = fmaxf(val, 0.f);
          srel = fmaf(rv, rv, srel);
        }
        smx += __shfl_xor(smx, 1); smx += __shfl_xor(smx, 2);
        smx += __shfl_xor(smx, 4); smx += __shfl_xor(smx, 8);
        srel += __shfl_xor(srel, 1); srel += __shfl_xor(srel, 2);
        srel += __shfl_xor(srel, 4); srel += __shfl_xor(srel, 8);
        if (l15 == 0) {
          mxhsq[(size_t)h * N_NODES + row] = smx;
          reluhsq[(size_t)h * N_NODES + row] = srel;
        }
      }
    }
  } else {
    const bool isK = (bn >= DIMV);  // block-uniform
    const int h = ((bn + wcn) >> 6) & (NHEADS - 1);
    int lc[4];
    float bb[4];
#pragma unroll
    for (int j = 0; j < 4; ++j) {
      lc[j] = (bn + wcn + j * 16 + l15) & (DIMV - 1);
      bb[j] = isK ? biasK[lc[j]] : biasQ[lc[j]];
    }
    float csum[4] = {0.f, 0.f, 0.f, 0.f};
#pragma unroll
    for (int i = 0; i < 8; ++i) {
#pragma unroll
      for (int r = 0; r < 4; ++r) {
        const int row = bm + wr + i * 16 + rbase + r;
        const float invdp = 1.0f / denom[(size_t)h * N_NODES + row];
        float den = 0.f, mk = 0.f;
        if (isK) {
          den = clampabs(2.0f * invdp - 1.0f, 1e-10f);
          mk = mask[row];
        }
#pragma unroll
        for (int j = 0; j < 4; ++j) {
          float val = elup1_fast((acc[i][j][r] + bb[j]) * invdp);
          if (isK) {
            val = den * val * mk;
            csum[j] += val;
            Ck[(size_t)row * DIMV + lc[j]] = f2b(val);
          } else {
            Cq[(size_t)row * DIMV + lc[j]] = f2b(val);
          }
        }
      }
    }
    if (isK) {
#pragma unroll
      for (int j = 0; j < 4; ++j) atomicAdd(&v2sum[lc[j]], csum[j]);
    }
  }
}

// ---------- vscale: per-row mobius+kappa scalars from stats; emits scaleV + denom ----------
__global__ __launch_bounds__(256) void vscale_kernel(const float* __restrict__ xnormsq,
                                                     const float* __restrict__ mxhsq,
                                                     const float* __restrict__ reluhsq,
                                                     float* __restrict__ scaleV,
                                                     float* __restrict__ denom) {
  const int row = blockIdx.x * 256 + threadIdx.x;
  float sm = 0.f, sr = 0.f;
  float hs[NHEADS];
#pragma unroll
  for (int h = 0; h < NHEADS; ++h) {
    sm += mxhsq[(size_t)h * N_NODES + row];
    hs[h] = reluhsq[(size_t)h * N_NODES + row];
    sr += hs[h];
  }
  float sx = xnormsq[row];
  float xn = fmaxf(sqrtf(sx), 1e-15f);
  float mxn = fmaxf(sqrtf(sm), 1e-15f);
  float cx = fminf(xn, 1.0f - 1e-7f);
  float t1 = tanhf(mxn / xn * atanhf(cx));
  float s1 = t1 / mxn;
  float yn = fmaxf(fabsf(t1), 1e-15f);
  float a = atanhf(fminf(yn, 1.0f - 1e-7f)) / yn;
  float k1 = a * s1;
  float un = fmaxf(k1 * sqrtf(sr), 1e-15f);
  float t2 = tanhf(un);
  float s2 = t2 / un;
  if (t2 > 0.996f) s2 *= 0.996f / t2;
  float sV = s2 * k1;
  scaleV[row] = sV;
#pragma unroll
  for (int h = 0; h < NHEADS; ++h)
    denom[(size_t)h * N_NODES + row] = fmaxf(1.0f - sV * sV * hs[h], 1e-15f);
}

// ---------- row transform (final): mobius_matvec tail + kappa_relu ----------
__global__ __launch_bounds__(256) void rowtrans_kernel(const ushort_t* __restrict__ msrc,
                                                       const float* __restrict__ rowsq,
                                                       float* __restrict__ dstv) {
  __shared__ float red[4];
  const int row = blockIdx.x;
  const int t = threadIdx.x;
  uint2 mraw = ((const uint2*)(msrc + (size_t)row * DIMV))[t];
  ushort_t* mh = (ushort_t*)&mraw;
  float4 m4 = make_float4(b2f(mh[0]), b2f(mh[1]), b2f(mh[2]), b2f(mh[3]));
  float sm = m4.x * m4.x + m4.y * m4.y + m4.z * m4.z + m4.w * m4.w;
  sm = blockReduceSum(sm, red);
  float sx = rowsq[row];

  float xn = fmaxf(sqrtf(sx), 1e-15f);
  float mxn = fmaxf(sqrtf(sm), 1e-15f);
  float cx = fminf(xn, 1.0f - 1e-7f);
  float t1 = tanhf(mxn / xn * atanhf(cx));
  float s1 = t1 / mxn;

  float yn = fmaxf(fabsf(t1), 1e-15f);
  float a = atanhf(fminf(yn, 1.0f - 1e-7f)) / yn;
  float k1 = a * s1;
  float4 u = make_float4(fmaxf(k1 * m4.x, 0.0f), fmaxf(k1 * m4.y, 0.0f),
                         fmaxf(k1 * m4.z, 0.0f), fmaxf(k1 * m4.w, 0.0f));
  float su = u.x * u.x + u.y * u.y + u.z * u.z + u.w * u.w;
  su = blockReduceSum(su, red);

  float un = fmaxf(sqrtf(su), 1e-15f);
  float t2 = tanhf(un);
  float s2 = t2 / un;
  if (t2 > 0.996f) s2 *= 0.996f / t2;
  float4 o = make_float4(s2 * u.x, s2 * u.y, s2 * u.z, s2 * u.w);
  ((float4*)(dstv + (size_t)row * DIMV))[t] = o;
}

// ---------- context (MFMA): ctxT[h][e][d] = sum_n v2[h,n,d]*(c1*relu(mx))[h,n,e] ----------
// Both operands staged TRANSPOSED ([d][n] / [e][n]) with the r13 XOR unit-swizzle
// (unit u stored at u^(row&7); read unit (ks*4+g)^(l15&7)). Per 64-row chunk each wave
// does 10 ds_read_b128 + 8 MFMA (vs 1024 VALU FMA before).
__global__ __launch_bounds__(256) void context_kernel(const ushort_t* __restrict__ v2buf,
                                                      const ushort_t* __restrict__ mxVbuf,
                                                      const float* __restrict__ scaleV,
                                                      const float* __restrict__ denom,
                                                      const float* __restrict__ mask,
                                                      float* __restrict__ ctxT) {
  __shared__ ushort_t s2T[64 * 64];  // [d][n-swz], 8 KB
  __shared__ ushort_t sxT[64 * 64];  // [e][n-swz], 8 KB
  const int h = blockIdx.y;
  const int t = threadIdx.x;
  const int w = t >> 6, lane = t & 63, l15 = lane & 15, g = lane >> 4;
  const int e7 = l15 & 7;
  const int uo0 = (g ^ e7) * 8;        // ks=0 swizzled unit offset (elems)
  const int uo1 = ((4 + g) ^ e7) * 8;  // ks=1

  f32x4 acc[4];
#pragma unroll
  for (int j = 0; j < 4; ++j) acc[j] = (f32x4){0.f, 0.f, 0.f, 0.f};

  const int rbase = blockIdx.x * 512;
  for (int c = 0; c < 8; ++c) {
#pragma unroll
    for (int i = 0; i < 4; ++i) {
      int f = i * 256 + t;
      int r = f >> 4;          // n within chunk (0..63)
      int cc = (f & 15) * 4;   // d/e base
      int row = rbase + c * 64 + r;
      uint2 araw = *(const uint2*)(v2buf + (size_t)row * DIMV + h * HEADD + cc);
      ushort_t* ah = (ushort_t*)&araw;
      float dp = denom[(size_t)h * N_NODES + row];
      float gamma = 2.0f / dp;
      float den = clampabs(gamma - 1.0f, 1e-10f);
      float c1 = gamma / den * mask[row] * scaleV[row];
      uint2 braw = *(const uint2*)(mxVbuf + (size_t)row * DIMV + h * HEADD + cc);
      ushort_t* bh = (ushort_t*)&braw;
      const int rhi = r >> 3, rlo = r & 7;
#pragma unroll
      for (int q = 0; q < 4; ++q) {
        const int d = cc + q;
        const int pos = d * 64 + ((rhi ^ (d & 7)) << 3) + rlo;
        s2T[pos] = ah[q];
        sxT[pos] = f2b(c1 * fmaxf(b2f(bh[q]), 0.f));
      }
    }
    __syncthreads();
#pragma unroll
    for (int ks = 0; ks < 2; ++ks) {
      const int uo = ks ? uo1 : uo0;
      short8 af = *(const short8*)&s2T[(w * 16 + l15) * 64 + uo];
#pragma unroll
      for (int j = 0; j < 4; ++j) {
        short8 bfv = *(const short8*)&sxT[(j * 16 + l15) * 64 + uo];
        acc[j] = __builtin_amdgcn_mfma_f32_16x16x32_bf16(af, bfv, acc[j], 0, 0, 0);
      }
    }
    __syncthreads();
  }
  // D layout: col(e_local)=l15, row(d_local)=g*4+r; wave w owns d-block w.
#pragma unroll
  for (int j = 0; j < 4; ++j)
#pragma unroll
    for (int r = 0; r < 4; ++r)
      atomicAdd(&ctxT[h * 4096 + (j * 16 + l15) * 64 + w * 16 + g * 4 + r], acc[j][r]);
}

// ---------- out (MFMA): [out|D] = v1 @ [ctx|v2sum]; tail; emit combHi + rownorm atomics ----------
__global__ __launch_bounds__(256) void out_mfma_kernel(const ushort_t* __restrict__ v1bf,
                                                       const float* __restrict__ v2sum,
                                                       const float* __restrict__ ctxT,
                                                       ushort_t* __restrict__ combHi,
                                                       float* __restrict__ combnorm) {
  __shared__ ushort_t Blds[80][88];
  const int h = blockIdx.y;
  const int bm = blockIdx.x * 256;
  const int t = threadIdx.x;
  const int w = t >> 6, lane = t & 63, l15 = lane & 15;
  const int kk = (lane >> 4) * 8;

  for (int idx = t; idx < 80 * 64; idx += 256) {
    int e = idx >> 6, d = idx & 63;
    float v = 0.0f;
    if (e < 64) v = ctxT[h * 4096 + e * 64 + d];
    else if (e == 64) v = v2sum[h * 64 + d];
    Blds[e][d] = f2b(v);
  }
  __syncthreads();

  f32x4 acc[4][5];
#pragma unroll
  for (int i = 0; i < 4; ++i)
#pragma unroll
    for (int j = 0; j < 5; ++j) acc[i][j] = (f32x4){0.f, 0.f, 0.f, 0.f};
#pragma unroll
  for (int ks = 0; ks < 2; ++ks) {
    short8 bfr[5];
#pragma unroll
    for (int j = 0; j < 5; ++j) bfr[j] = *(const short8*)&Blds[j * 16 + l15][ks * 32 + kk];
#pragma unroll
    for (int i = 0; i < 4; ++i) {
      short8 af = *(const short8*)(v1bf + (size_t)(bm + w * 64 + i * 16 + l15) * DIMV +
                                   h * HEADD + ks * 32 + kk);
#pragma unroll
      for (int j = 0; j < 5; ++j)
        acc[i][j] = __builtin_amdgcn_mfma_f32_16x16x32_bf16(af, bfr[j], acc[i][j], 0, 0, 0);
    }
  }

  const int g4 = (lane >> 4) * 4;
#pragma unroll
  for (int i = 0; i < 4; ++i) {
#pragma unroll
    for (int r = 0; r < 4; ++r) {
      const int row = bm + w * 64 + i * 16 + g4 + r;
      float D = __shfl(acc[i][4][r], lane & 48);
      float Dinv = 1.0f / (D == 0.0f ? 1e-5f : D);
      float o[4];
      float s = 0.0f;
#pragma unroll
      for (int j = 0; j < 4; ++j) {
        o[j] = acc[i][j][r] * Dinv;
        s = fmaf(o[j], o[j], s);
      }
      s += __shfl_xor(s, 1); s += __shfl_xor(s, 2);
      s += __shfl_xor(s, 4); s += __shfl_xor(s, 8);
      float n1 = fmaxf(sqrtf(s), 1e-15f);
      float sc = 1.0f;
      if (n1 > 0.996f) sc = 0.996f / n1;
      float xn = fmaxf(fminf(n1, 0.996f), 1e-15f);
      float cx = fminf(xn, 1.0f - 1e-7f);
      // tanh(0.5*atanh(cx)) == cx / (1 + sqrt(1 - cx^2)); t2 <= 0.915 -> no reprojection.
      float t2 = cx / (1.0f + sqrtf(1.0f - cx * cx));
      sc *= t2 / xn;
      if (l15 == 0) atomicAdd(&combnorm[row], s * sc * sc);
#pragma unroll
      for (int j = 0; j < 4; ++j) {
        float ov = o[j] * sc;
        combHi[(size_t)row * DIMV + h * HEADD + j * 16 + l15] = f2b(ov);
      }
    }
  }
}

// ---------- launch ----------

extern "C" void kernel_launch(void* const* d_in, const int* in_sizes, int n_in,
                              void* d_out, int out_size, void* d_ws, size_t ws_size,
                              hipStream_t stream) {
  const float* X = (const float*)d_in[0];
  const float* mask = (const float*)d_in[1];
  const float* Wq = (const float*)d_in[2];
  const float* bq = (const float*)d_in[3];
  const float* Wk = (const float*)d_in[4];
  const float* bk = (const float*)d_in[5];
  const float* Wv = (const float*)d_in[6];
  const float* Wff = (const float*)d_in[7];
  float* out = (float*)d_out;

  const size_t MAT = (size_t)N_NODES * DIMV;
  char* p = (char*)d_ws;
  // R1 (64MB): first half v1bf (QK epi out); second half mxV bf16, later combnorm
  ushort_t* v1bf = (ushort_t*)p;
  ushort_t* mxV = (ushort_t*)(p + MAT * 2);
  float* combnorm = (float*)(p + MAT * 2);
  p += MAT * 4;
  // R2 (64MB): xnormsq (early) / v2bf (QK epi out) / combHi (after context)
  float* xnormsq = (float*)p;
  ushort_t* v2bf = (ushort_t*)p;
  ushort_t* combHi = (ushort_t*)p;
  p += MAT * 4;
  // R3 (32MB): WffHi
  ushort_t* WffHi = (ushort_t*)p;
  p += MAT * 2;
  // R4 (32MB): Xbf; later outBf (final gemm out)
  ushort_t* Xbf = (ushort_t*)p;
  ushort_t* outBf = Xbf;
  p += MAT * 2;
  float* denom = (float*)p;   p += (size_t)NHEADS * N_NODES * 4;
  float* v2sum = (float*)p;   p += 1024 * 4;
  float* ctxT = (float*)p;    p += (size_t)NHEADS * 4096 * 4;
  float* mxhsq = (float*)p;   p += (size_t)NHEADS * N_NODES * 4;
  float* reluhsq = (float*)p; p += (size_t)NHEADS * N_NODES * 4;
  float* scaleV = (float*)p;  p += (size_t)N_NODES * 4;
  const size_t need = (size_t)(p - (char*)d_ws);
  if (ws_size < need) return;

  // W^T bf16 scratch inside d_out (free until the final rowtrans writes it):
  ushort_t* Wt = (ushort_t*)d_out;            // Wq^T (rows 0..1023 of stacked QK)
  ushort_t* WtK = Wt + (size_t)DIMV * DIMV;   // Wk^T (rows 1024..2047)
  ushort_t* WtV = WtK + (size_t)DIMV * DIMV;  // Wv^T

  dim3 tgrid(32, 32);

  cvt_norm_kernel<<<N_NODES, 256, 0, stream>>>(X, Xbf, xnormsq);
  transW3_kernel<<<dim3(32, 32, 3), 256, 0, stream>>>(Wq, Wk, Wv, Wt, WtK, WtV);
  // V path: mxV bf16 + per-(row,head) stats; then closed-form scaleV + denom
  gemm_bf<4, 4><<<256, 512, 0, stream>>>(Xbf, WtV, nullptr, nullptr, nullptr, nullptr,
                                         nullptr, mxhsq, reluhsq, mxV, nullptr);
  vscale_kernel<<<N_NODES / 256, 256, 0, stream>>>(xnormsq, mxhsq, reluhsq, scaleV, denom);
  // zero v2sum + ctxT (contiguous)
  hipMemsetAsync(v2sum, 0, (1024 + 4096 * NHEADS) * sizeof(float), stream);
  // QK fused: stacked [Wq^T; Wk^T]; emits v1 (cols<1024) and v2 + v2sum (cols>=1024)
  gemm_bf<3, 8><<<512, 512, 0, stream>>>(Xbf, Wt, bq, bk, denom, mask, v2sum, nullptr,
                                         nullptr, v1bf, v2bf);
  // context (MFMA; reads mxV with inline sV*relu)
  context_kernel<<<dim3(32, NHEADS), 256, 0, stream>>>(v2bf, mxV, scaleV, denom, mask, ctxT);
  // combnorm aliases mxV: zero only after context consumed mxV
  hipMemsetAsync(combnorm, 0, N_NODES * sizeof(float), stream);
  // attention out -> combHi + row norms
  out_mfma_kernel<<<dim3(N_NODES / 256, NHEADS), 256, 0, stream>>>(v1bf, v2sum, ctxT, combHi,
                                                                   combnorm);
  // final: single bf16 GEMM comb@Wff -> outBf, then rowtrans -> d_out
  transW_kernel<<<tgrid, 256, 0, stream>>>(Wff, WffHi);
  gemm_bf<0, 4><<<256, 512, 0, stream>>>(combHi, WffHi, nullptr, nullptr, nullptr, nullptr,
                                         nullptr, nullptr, nullptr, outBf, nullptr);
  rowtrans_kernel<<<N_NODES, 256, 0, stream>>>(outBf, combnorm, out);
}

// Round 17
// 342.027 us; speedup vs baseline: 2.0217x; 1.0238x over previous
//
#include <hip/hip_runtime.h>
#include <hip/hip_bf16.h>
#include <math.h>

#define N_NODES 16384
#define DIMV 1024
#define NHEADS 16
#define HEADD 64

typedef __attribute__((ext_vector_type(8))) short short8;
typedef __attribute__((ext_vector_type(4))) float f32x4;
typedef __attribute__((ext_vector_type(2))) long long2_t;
typedef unsigned short ushort_t;
typedef unsigned char uchar_t;

// async global->LDS, 16B per lane
#define GLD16(gptr, lptr)                                                                 \
  __builtin_amdgcn_global_load_lds((const __attribute__((address_space(1))) void*)(gptr), \
                                   (__attribute__((address_space(3))) void*)(lptr), 16, 0, 0)

// ---------- helpers ----------

__device__ __forceinline__ float waveReduceSum(float v) {
#pragma unroll
  for (int m = 32; m; m >>= 1) v += __shfl_xor(v, m);
  return v;
}

__device__ __forceinline__ float blockReduceSum(float v, float* red) {
  float w = waveReduceSum(v);
  __syncthreads();
  if ((threadIdx.x & 63) == 0) red[threadIdx.x >> 6] = w;
  __syncthreads();
  return red[0] + red[1] + red[2] + red[3];
}

// elu(z)+1: z>0 -> z+1; z<=0 -> expm1(z)+1 == e^z (exact identity).
__device__ __forceinline__ float elup1_fast(float z) {
  return z > 0.0f ? z + 1.0f : __expf(z);
}

__device__ __forceinline__ float clampabs(float x, float eps) {
  float s = (x >= 0.0f) ? 1.0f : -1.0f;
  return s * fmaxf(fabsf(x), eps);
}

// fp32 -> bf16 bits, RNE
__device__ __forceinline__ ushort_t f2b(float x) {
  unsigned u = __float_as_uint(x);
  unsigned r = (u + 0x7FFFu + ((u >> 16) & 1u)) >> 16;
  return (ushort_t)r;
}
__device__ __forceinline__ float b2f(ushort_t h) {
  return __uint_as_float(((unsigned)h) << 16);
}

// fp32 -> OCP e4m3 (RNE, flush-to-zero below 2^-6, clamp at 448). Inputs pre-scaled
// so |x| sits in the normal range; FTZ loss is negligible in K=1024 dot products.
__device__ __forceinline__ uchar_t f2e4m3(float x) {
  unsigned u = __float_as_uint(x);
  unsigned s = (u >> 24) & 0x80u;
  unsigned a = u & 0x7fffffffu;
  if (a < 0x3c800000u) return (uchar_t)s;            // |x| < 2^-6 -> 0
  if (a > 0x43e00000u) return (uchar_t)(s | 0x7eu);  // clamp to 448
  unsigned lsb = (a >> 20) & 1u;
  a += 0x7ffffu + lsb;                               // RNE into 3-bit mantissa
  unsigned e = (a >> 23) - 120u;                     // -127 + bias 7
  unsigned m = (a >> 20) & 7u;
  return (uchar_t)(s | (e << 3) | m);
}

// ---------- X -> bf16 + fp8(16x, permuted/swizzled) + row sumsq ----------
// fp8 global layout (per row n, per 64-k block): byte = (g^((n>>1)&3))*16 + ks*8 + e
// where k = k64*64 + ks*32 + g*8 + e. This IS the LDS layout -> GLD16 stays linear,
// and b128 fragment reads are 2 lanes/bank (free).
__global__ __launch_bounds__(256) void cvt_norm_kernel(const float* __restrict__ src,
                                                       ushort_t* __restrict__ dst,
                                                       uchar_t* __restrict__ xf8,
                                                       float* __restrict__ rowsq) {
  __shared__ float red[4];
  const int row = blockIdx.x;
  const int t = threadIdx.x;
  float4 x4 = ((const float4*)(src + (size_t)row * DIMV))[t];
  ushort_t h[4] = {f2b(x4.x), f2b(x4.y), f2b(x4.z), f2b(x4.w)};
  ((uint2*)(dst + (size_t)row * DIMV))[t] = *(uint2*)h;
  unsigned pk = (unsigned)f2e4m3(x4.x * 16.f) | ((unsigned)f2e4m3(x4.y * 16.f) << 8) |
                ((unsigned)f2e4m3(x4.z * 16.f) << 16) | ((unsigned)f2e4m3(x4.w * 16.f) << 24);
  const int g = (t >> 1) & 3, ks = (t >> 3) & 1, k64 = t >> 4, e0 = (t & 1) << 2;
  *(unsigned*)(xf8 + (size_t)row * DIMV + k64 * 64 + ((g ^ ((row >> 1) & 3)) << 4) +
               (ks << 3) + e0) = pk;
  float s = x4.x * x4.x + x4.y * x4.y + x4.z * x4.z + x4.w * x4.w;
  s = blockReduceSum(s, red);
  if (t == 0) rowsq[row] = s;
}

// fused quad transpose: z=0 Wq->fp8(16x, permuted), z=1 Wk->fp8, z=2 Wv->bf16, z=3 Wff->bf16
__global__ __launch_bounds__(256) void transW4_kernel(const float* __restrict__ s0,
                                                      const float* __restrict__ s1,
                                                      const float* __restrict__ s2,
                                                      const float* __restrict__ s3,
                                                      uchar_t* __restrict__ d0,
                                                      uchar_t* __restrict__ d1,
                                                      ushort_t* __restrict__ d2,
                                                      ushort_t* __restrict__ d3) {
  __shared__ float tile[32][33];
  const int z = blockIdx.z;
  const float* src = (z == 0) ? s0 : (z == 1) ? s1 : (z == 2) ? s2 : s3;
  const int bx = blockIdx.x * 32, by = blockIdx.y * 32;
  const int tx = threadIdx.x & 31, ty = threadIdx.x >> 5;
#pragma unroll
  for (int i = 0; i < 32; i += 8) tile[ty + i][tx] = src[(size_t)(by + ty + i) * DIMV + bx + tx];
  __syncthreads();
  if (z < 2) {
    uchar_t* dst = z ? d1 : d0;
#pragma unroll
    for (int i = 0; i < 32; i += 8) {
      const int n = bx + ty + i, k = by + tx;
      const size_t byte = (size_t)n * DIMV + ((k >> 6) << 6) +
                          ((((k >> 3) & 3) ^ ((n >> 1) & 3)) << 4) + (((k >> 5) & 1) << 3) +
                          (k & 7);
      dst[byte] = f2e4m3(16.f * tile[tx][ty + i]);
    }
  } else {
    ushort_t* dst = (z == 2) ? d2 : d3;
#pragma unroll
    for (int i = 0; i < 32; i += 8)
      dst[(size_t)(bx + ty + i) * DIMV + by + tx] = f2b(tile[tx][ty + i]);
  }
}

// 128B-row k-unit swizzle for bf16 GEMM (BK=64, r13-verified, bank-conflict = 0):
// LDS[row][u] = global unit u ^ (row&7); staging src unit (lane&7)^((lane>>3)&7);
// fragment read unit ((ks*4+g) ^ (l15&7)).

// ---------- bf16 MFMA GEMM, 256x256 tile, BK=64, 8 waves, dbuf 2-phase, swizzled ----------
// EPI 0: Cq = bf16(acc)                                  (plain: final comb@Wff)
// EPI 4: Cq = bf16(acc) + per-(row,head) stats {sum mx^2, sum relu(mx)^2} (V path)
template <int EPI, int NB>
__global__ __launch_bounds__(512, 2) void gemm_bf(const ushort_t* __restrict__ A,
                                                  const ushort_t* __restrict__ Bt,
                                                  float* __restrict__ mxhsq,
                                                  float* __restrict__ reluhsq,
                                                  ushort_t* __restrict__ Cq) {
  __shared__ ushort_t As[2][256 * 64];  // 32 KB per buf
  __shared__ ushort_t Bs[2][256 * 64];
  const int bid = blockIdx.x;
  const int nwg = NB * 64;
  const int swz = (bid & 7) * (nwg / 8) + (bid >> 3);
  const int bm = (swz / NB) * 256;
  const int bn = (swz % NB) * 256;
  const int t = threadIdx.x;
  const int w = t >> 6, lane = t & 63, l15 = lane & 15;
  const int wr = (w >> 2) * 128;
  const int wcn = (w & 3) * 64;
  const int g4 = lane >> 4;
  const int e7 = l15 & 7;
  const int uo0 = (g4 ^ e7) * 8;
  const int uo1 = ((4 + g4) ^ e7) * 8;

  const int rowin = lane >> 3;
  const int ksh = ((lane & 7) ^ ((lane >> 3) & 7)) * 8;
  const ushort_t *gA[4], *gB[4];
  int lofs[4];
#pragma unroll
  for (int c = 0; c < 4; ++c) {
    const int ch = w + 8 * c;
    lofs[c] = ch * 512;
    gA[c] = A + (size_t)(bm + ch * 8 + rowin) * DIMV + ksh;
    gB[c] = Bt + (size_t)(bn + ch * 8 + rowin) * DIMV + ksh;
  }

#define STAGE_G(buf, k0)                              \
  do {                                                \
    _Pragma("unroll") for (int c = 0; c < 4; ++c) {   \
      GLD16(gA[c] + (k0), &As[buf][lofs[c]]);         \
      GLD16(gB[c] + (k0), &Bs[buf][lofs[c]]);         \
    }                                                 \
  } while (0)

  f32x4 acc[8][4];
#pragma unroll
  for (int i = 0; i < 8; ++i)
#pragma unroll
    for (int j = 0; j < 4; ++j) acc[i][j] = (f32x4){0.f, 0.f, 0.f, 0.f};

  STAGE_G(0, 0);
  __syncthreads();
  int cur = 0;
  for (int k0 = 0; k0 < DIMV; k0 += 64) {
    if (k0 + 64 < DIMV) STAGE_G(cur ^ 1, k0 + 64);
#pragma unroll
    for (int ks = 0; ks < 2; ++ks) {
      const int uo = ks ? uo1 : uo0;
      short8 bf[4];
#pragma unroll
      for (int j = 0; j < 4; ++j)
        bf[j] = *(const short8*)&Bs[cur][(wcn + j * 16 + l15) * 64 + uo];
#pragma unroll
      for (int i = 0; i < 8; ++i) {
        short8 af = *(const short8*)&As[cur][(wr + i * 16 + l15) * 64 + uo];
#pragma unroll
        for (int j = 0; j < 4; ++j)
          acc[i][j] = __builtin_amdgcn_mfma_f32_16x16x32_bf16(af, bf[j], acc[i][j], 0, 0, 0);
      }
    }
    __syncthreads();
    cur ^= 1;
  }
#undef STAGE_G

  // epilogue. C/D layout: col = lane&15, row = (lane>>4)*4 + r
  const int rbase = (lane >> 4) * 4;
  if (EPI == 0) {
#pragma unroll
    for (int j = 0; j < 4; ++j) {
      const int col = bn + wcn + j * 16 + l15;
#pragma unroll
      for (int i = 0; i < 8; ++i)
#pragma unroll
        for (int r = 0; r < 4; ++r)
          Cq[(size_t)(bm + wr + i * 16 + rbase + r) * DIMV + col] = f2b(acc[i][j][r]);
    }
  } else {
    const int h = ((bn + wcn) >> 6) & (NHEADS - 1);
#pragma unroll
    for (int i = 0; i < 8; ++i) {
#pragma unroll
      for (int r = 0; r < 4; ++r) {
        const int row = bm + wr + i * 16 + rbase + r;
        float smx = 0.f, srel = 0.f;
#pragma unroll
        for (int j = 0; j < 4; ++j) {
          float val = acc[i][j][r];
          Cq[(size_t)row * DIMV + bn + wcn + j * 16 + l15] = f2b(val);
          smx = fmaf(val, val, smx);
          float rv = fmaxf(val, 0.f);
          srel = fmaf(rv, rv, srel);
        }
        smx += __shfl_xor(smx, 1); smx += __shfl_xor(smx, 2);
        smx += __shfl_xor(smx, 4); smx += __shfl_xor(smx, 8);
        srel += __shfl_xor(srel, 1); srel += __shfl_xor(srel, 2);
        srel += __shfl_xor(srel, 4); srel += __shfl_xor(srel, 8);
        if (l15 == 0) {
          mxhsq[(size_t)h * N_NODES + row] = smx;
          reluhsq[(size_t)h * N_NODES + row] = srel;
        }
      }
    }
  }
}

// ---------- fp8 MFMA GEMM (QK fused): 256x256 tile, BK=64, 8 waves, dbuf 2-phase ----------
// Operands pre-scaled x16 and pre-permuted (see cvt_norm); acc scaled by 1/256 in epilogue.
// LDS: rows of 64B, granule-16B XOR swizzle g^((row>>1)&3); one b128 read = both ks-frags.
// cols<1024 -> Cq = bf16(v1); cols>=1024 -> Ck = bf16(v2) + v2sum atomics.
template <int NB>
__global__ __launch_bounds__(512, 2) void gemm_f8qk(const uchar_t* __restrict__ Xf8,
                                                    const uchar_t* __restrict__ Bt8,
                                                    const float* __restrict__ biasQ,
                                                    const float* __restrict__ biasK,
                                                    const float* __restrict__ denom,
                                                    const float* __restrict__ mask,
                                                    float* __restrict__ v2sum,
                                                    ushort_t* __restrict__ Cq,
                                                    ushort_t* __restrict__ Ck) {
  __shared__ uchar_t LB[65536];  // A: buf*16384, B: 32768 + buf*16384
  const int bid = blockIdx.x;
  const int nwg = NB * 64;
  const int swz = (bid & 7) * (nwg / 8) + (bid >> 3);
  const int bm = (swz / NB) * 256;
  const int bn = (swz % NB) * 256;
  const int t = threadIdx.x;
  const int w = t >> 6, lane = t & 63, l15 = lane & 15;
  const int wr = (w >> 2) * 128;
  const int wcn = (w & 3) * 64;
  const int g = lane >> 4;
  const int aoff = ((g ^ ((l15 >> 1) & 3)) << 4);  // swizzled granule byte offset

  const uchar_t *gA[2], *gB[2];
  int lofs[2];
#pragma unroll
  for (int c = 0; c < 2; ++c) {
    const int row = (t >> 2) + c * 128;
    lofs[c] = t * 16 + c * 8192;
    gA[c] = Xf8 + (size_t)(bm + row) * DIMV + (t & 3) * 16;
    gB[c] = Bt8 + (size_t)(bn + row) * DIMV + (t & 3) * 16;
  }

#define STAGE_F(buf, kb)                                        \
  do {                                                          \
    _Pragma("unroll") for (int c = 0; c < 2; ++c) {             \
      GLD16(gA[c] + (kb), &LB[(buf) * 16384 + lofs[c]]);        \
      GLD16(gB[c] + (kb), &LB[32768 + (buf) * 16384 + lofs[c]]); \
    }                                                           \
  } while (0)

  f32x4 acc[8][4];
#pragma unroll
  for (int i = 0; i < 8; ++i)
#pragma unroll
    for (int j = 0; j < 4; ++j) acc[i][j] = (f32x4){0.f, 0.f, 0.f, 0.f};

  STAGE_F(0, 0);
  __syncthreads();
  int cur = 0;
  for (int kt = 0; kt < 16; ++kt) {
    if (kt < 15) STAGE_F(cur ^ 1, (kt + 1) * 64);
    long2_t bf[4];
#pragma unroll
    for (int j = 0; j < 4; ++j)
      bf[j] = *(const long2_t*)&LB[32768 + cur * 16384 + (wcn + j * 16 + l15) * 64 + aoff];
#pragma unroll
    for (int i = 0; i < 8; ++i) {
      long2_t af = *(const long2_t*)&LB[cur * 16384 + (wr + i * 16 + l15) * 64 + aoff];
#pragma unroll
      for (int j = 0; j < 4; ++j) {
        acc[i][j] = __builtin_amdgcn_mfma_f32_16x16x32_fp8_fp8(af.x, bf[j].x, acc[i][j], 0, 0, 0);
        acc[i][j] = __builtin_amdgcn_mfma_f32_16x16x32_fp8_fp8(af.y, bf[j].y, acc[i][j], 0, 0, 0);
      }
    }
    __syncthreads();
    cur ^= 1;
  }
#undef STAGE_F

  // epilogue (QK fused; acc scaled by 1/256). C/D layout: col=lane&15, row=(lane>>4)*4+r.
  const int rbase = (lane >> 4) * 4;
  const bool isK = (bn >= DIMV);  // block-uniform
  const int h = ((bn + wcn) >> 6) & (NHEADS - 1);
  int lc[4];
  float bb[4];
#pragma unroll
  for (int j = 0; j < 4; ++j) {
    lc[j] = (bn + wcn + j * 16 + l15) & (DIMV - 1);
    bb[j] = isK ? biasK[lc[j]] : biasQ[lc[j]];
  }
  float csum[4] = {0.f, 0.f, 0.f, 0.f};
#pragma unroll
  for (int i = 0; i < 8; ++i) {
#pragma unroll
    for (int r = 0; r < 4; ++r) {
      const int row = bm + wr + i * 16 + rbase + r;
      const float invdp = 1.0f / denom[(size_t)h * N_NODES + row];
      float den = 0.f, mk = 0.f;
      if (isK) {
        den = clampabs(2.0f * invdp - 1.0f, 1e-10f);
        mk = mask[row];
      }
#pragma unroll
      for (int j = 0; j < 4; ++j) {
        float val = elup1_fast((acc[i][j][r] * 0.00390625f + bb[j]) * invdp);
        if (isK) {
          val = den * val * mk;
          csum[j] += val;
          Ck[(size_t)row * DIMV + lc[j]] = f2b(val);
        } else {
          Cq[(size_t)row * DIMV + lc[j]] = f2b(val);
        }
      }
    }
  }
  if (isK) {
#pragma unroll
    for (int j = 0; j < 4; ++j) atomicAdd(&v2sum[lc[j]], csum[j]);
  }
}

// ---------- vscale: per-row mobius+kappa scalars from stats; emits scaleV + denom ----------
__global__ __launch_bounds__(256) void vscale_kernel(const float* __restrict__ xnormsq,
                                                     const float* __restrict__ mxhsq,
                                                     const float* __restrict__ reluhsq,
                                                     float* __restrict__ scaleV,
                                                     float* __restrict__ denom) {
  const int row = blockIdx.x * 256 + threadIdx.x;
  float sm = 0.f, sr = 0.f;
  float hs[NHEADS];
#pragma unroll
  for (int h = 0; h < NHEADS; ++h) {
    sm += mxhsq[(size_t)h * N_NODES + row];
    hs[h] = reluhsq[(size_t)h * N_NODES + row];
    sr += hs[h];
  }
  float sx = xnormsq[row];
  float xn = fmaxf(sqrtf(sx), 1e-15f);
  float mxn = fmaxf(sqrtf(sm), 1e-15f);
  float cx = fminf(xn, 1.0f - 1e-7f);
  float t1 = tanhf(mxn / xn * atanhf(cx));
  float s1 = t1 / mxn;
  float yn = fmaxf(fabsf(t1), 1e-15f);
  float a = atanhf(fminf(yn, 1.0f - 1e-7f)) / yn;
  float k1 = a * s1;
  float un = fmaxf(k1 * sqrtf(sr), 1e-15f);
  float t2 = tanhf(un);
  float s2 = t2 / un;
  if (t2 > 0.996f) s2 *= 0.996f / t2;
  float sV = s2 * k1;
  scaleV[row] = sV;
#pragma unroll
  for (int h = 0; h < NHEADS; ++h)
    denom[(size_t)h * N_NODES + row] = fmaxf(1.0f - sV * sV * hs[h], 1e-15f);
}

// ---------- row transform (final): mobius_matvec tail + kappa_relu ----------
__global__ __launch_bounds__(256) void rowtrans_kernel(const ushort_t* __restrict__ msrc,
                                                       const float* __restrict__ rowsq,
                                                       float* __restrict__ dstv) {
  __shared__ float red[4];
  const int row = blockIdx.x;
  const int t = threadIdx.x;
  uint2 mraw = ((const uint2*)(msrc + (size_t)row * DIMV))[t];
  ushort_t* mh = (ushort_t*)&mraw;
  float4 m4 = make_float4(b2f(mh[0]), b2f(mh[1]), b2f(mh[2]), b2f(mh[3]));
  float sm = m4.x * m4.x + m4.y * m4.y + m4.z * m4.z + m4.w * m4.w;
  sm = blockReduceSum(sm, red);
  float sx = rowsq[row];

  float xn = fmaxf(sqrtf(sx), 1e-15f);
  float mxn = fmaxf(sqrtf(sm), 1e-15f);
  float cx = fminf(xn, 1.0f - 1e-7f);
  float t1 = tanhf(mxn / xn * atanhf(cx));
  float s1 = t1 / mxn;

  float yn = fmaxf(fabsf(t1), 1e-15f);
  float a = atanhf(fminf(yn, 1.0f - 1e-7f)) / yn;
  float k1 = a * s1;
  float4 u = make_float4(fmaxf(k1 * m4.x, 0.0f), fmaxf(k1 * m4.y, 0.0f),
                         fmaxf(k1 * m4.z, 0.0f), fmaxf(k1 * m4.w, 0.0f));
  float su = u.x * u.x + u.y * u.y + u.z * u.z + u.w * u.w;
  su = blockReduceSum(su, red);

  float un = fmaxf(sqrtf(su), 1e-15f);
  float t2 = tanhf(un);
  float s2 = t2 / un;
  if (t2 > 0.996f) s2 *= 0.996f / t2;
  float4 o = make_float4(s2 * u.x, s2 * u.y, s2 * u.z, s2 * u.w);
  ((float4*)(dstv + (size_t)row * DIMV))[t] = o;
}

// ---------- context (MFMA): ctxT[h][e][d] = sum_n v2[h,n,d]*(c1*relu(mx))[h,n,e] ----------
__global__ __launch_bounds__(256) void context_kernel(const ushort_t* __restrict__ v2buf,
                                                      const ushort_t* __restrict__ mxVbuf,
                                                      const float* __restrict__ scaleV,
                                                      const float* __restrict__ denom,
                                                      const float* __restrict__ mask,
                                                      float* __restrict__ ctxT) {
  __shared__ ushort_t s2T[64 * 64];  // [d][n-swz], 8 KB
  __shared__ ushort_t sxT[64 * 64];  // [e][n-swz], 8 KB
  const int h = blockIdx.y;
  const int t = threadIdx.x;
  const int w = t >> 6, lane = t & 63, l15 = lane & 15, g = lane >> 4;
  const int e7 = l15 & 7;
  const int uo0 = (g ^ e7) * 8;        // ks=0 swizzled unit offset (elems)
  const int uo1 = ((4 + g) ^ e7) * 8;  // ks=1

  f32x4 acc[4];
#pragma unroll
  for (int j = 0; j < 4; ++j) acc[j] = (f32x4){0.f, 0.f, 0.f, 0.f};

  const int rbase = blockIdx.x * 512;
  for (int c = 0; c < 8; ++c) {
#pragma unroll
    for (int i = 0; i < 4; ++i) {
      int f = i * 256 + t;
      int r = f >> 4;          // n within chunk (0..63)
      int cc = (f & 15) * 4;   // d/e base
      int row = rbase + c * 64 + r;
      uint2 araw = *(const uint2*)(v2buf + (size_t)row * DIMV + h * HEADD + cc);
      ushort_t* ah = (ushort_t*)&araw;
      float dp = denom[(size_t)h * N_NODES + row];
      float gamma = 2.0f / dp;
      float den = clampabs(gamma - 1.0f, 1e-10f);
      float c1 = gamma / den * mask[row] * scaleV[row];
      uint2 braw = *(const uint2*)(mxVbuf + (size_t)row * DIMV + h * HEADD + cc);
      ushort_t* bh = (ushort_t*)&braw;
      const int rhi = r >> 3, rlo = r & 7;
#pragma unroll
      for (int q = 0; q < 4; ++q) {
        const int d = cc + q;
        const int pos = d * 64 + ((rhi ^ (d & 7)) << 3) + rlo;
        s2T[pos] = ah[q];
        sxT[pos] = f2b(c1 * fmaxf(b2f(bh[q]), 0.f));
      }
    }
    __syncthreads();
#pragma unroll
    for (int ks = 0; ks < 2; ++ks) {
      const int uo = ks ? uo1 : uo0;
      short8 af = *(const short8*)&s2T[(w * 16 + l15) * 64 + uo];
#pragma unroll
      for (int j = 0; j < 4; ++j) {
        short8 bfv = *(const short8*)&sxT[(j * 16 + l15) * 64 + uo];
        acc[j] = __builtin_amdgcn_mfma_f32_16x16x32_bf16(af, bfv, acc[j], 0, 0, 0);
      }
    }
    __syncthreads();
  }
#pragma unroll
  for (int j = 0; j < 4; ++j)
#pragma unroll
    for (int r = 0; r < 4; ++r)
      atomicAdd(&ctxT[h * 4096 + (j * 16 + l15) * 64 + w * 16 + g * 4 + r], acc[j][r]);
}

// ---------- out (MFMA): [out|D] = v1 @ [ctx|v2sum]; tail; emit combHi + rownorm atomics ----------
__global__ __launch_bounds__(256) void out_mfma_kernel(const ushort_t* __restrict__ v1bf,
                                                       const float* __restrict__ v2sum,
                                                       const float* __restrict__ ctxT,
                                                       ushort_t* __restrict__ combHi,
                                                       float* __restrict__ combnorm) {
  __shared__ ushort_t Blds[80][88];
  const int h = blockIdx.y;
  const int bm = blockIdx.x * 256;
  const int t = threadIdx.x;
  const int w = t >> 6, lane = t & 63, l15 = lane & 15;
  const int kk = (lane >> 4) * 8;

  for (int idx = t; idx < 80 * 64; idx += 256) {
    int e = idx >> 6, d = idx & 63;
    float v = 0.0f;
    if (e < 64) v = ctxT[h * 4096 + e * 64 + d];
    else if (e == 64) v = v2sum[h * 64 + d];
    Blds[e][d] = f2b(v);
  }
  __syncthreads();

  f32x4 acc[4][5];
#pragma unroll
  for (int i = 0; i < 4; ++i)
#pragma unroll
    for (int j = 0; j < 5; ++j) acc[i][j] = (f32x4){0.f, 0.f, 0.f, 0.f};
#pragma unroll
  for (int ks = 0; ks < 2; ++ks) {
    short8 bfr[5];
#pragma unroll
    for (int j = 0; j < 5; ++j) bfr[j] = *(const short8*)&Blds[j * 16 + l15][ks * 32 + kk];
#pragma unroll
    for (int i = 0; i < 4; ++i) {
      short8 af = *(const short8*)(v1bf + (size_t)(bm + w * 64 + i * 16 + l15) * DIMV +
                                   h * HEADD + ks * 32 + kk);
#pragma unroll
      for (int j = 0; j < 5; ++j)
        acc[i][j] = __builtin_amdgcn_mfma_f32_16x16x32_bf16(af, bfr[j], acc[i][j], 0, 0, 0);
    }
  }

  const int g4 = (lane >> 4) * 4;
#pragma unroll
  for (int i = 0; i < 4; ++i) {
#pragma unroll
    for (int r = 0; r < 4; ++r) {
      const int row = bm + w * 64 + i * 16 + g4 + r;
      float D = __shfl(acc[i][4][r], lane & 48);
      float Dinv = 1.0f / (D == 0.0f ? 1e-5f : D);
      float o[4];
      float s = 0.0f;
#pragma unroll
      for (int j = 0; j < 4; ++j) {
        o[j] = acc[i][j][r] * Dinv;
        s = fmaf(o[j], o[j], s);
      }
      s += __shfl_xor(s, 1); s += __shfl_xor(s, 2);
      s += __shfl_xor(s, 4); s += __shfl_xor(s, 8);
      float n1 = fmaxf(sqrtf(s), 1e-15f);
      float sc = 1.0f;
      if (n1 > 0.996f) sc = 0.996f / n1;
      float xn = fmaxf(fminf(n1, 0.996f), 1e-15f);
      float cx = fminf(xn, 1.0f - 1e-7f);
      // tanh(0.5*atanh(cx)) == cx / (1 + sqrt(1 - cx^2)); t2 <= 0.915 -> no reprojection.
      float t2 = cx / (1.0f + sqrtf(1.0f - cx * cx));
      sc *= t2 / xn;
      if (l15 == 0) atomicAdd(&combnorm[row], s * sc * sc);
#pragma unroll
      for (int j = 0; j < 4; ++j) {
        float ov = o[j] * sc;
        combHi[(size_t)row * DIMV + h * HEADD + j * 16 + l15] = f2b(ov);
      }
    }
  }
}

// ---------- launch ----------

extern "C" void kernel_launch(void* const* d_in, const int* in_sizes, int n_in,
                              void* d_out, int out_size, void* d_ws, size_t ws_size,
                              hipStream_t stream) {
  const float* X = (const float*)d_in[0];
  const float* mask = (const float*)d_in[1];
  const float* Wq = (const float*)d_in[2];
  const float* bq = (const float*)d_in[3];
  const float* Wk = (const float*)d_in[4];
  const float* bk = (const float*)d_in[5];
  const float* Wv = (const float*)d_in[6];
  const float* Wff = (const float*)d_in[7];
  float* out = (float*)d_out;

  const size_t MAT = (size_t)N_NODES * DIMV;
  char* p = (char*)d_ws;
  // R1 (64MB): first half v1bf (QK epi out); second half mxV bf16, later combnorm
  ushort_t* v1bf = (ushort_t*)p;
  ushort_t* mxV = (ushort_t*)(p + MAT * 2);
  float* combnorm = (float*)(p + MAT * 2);
  p += MAT * 4;
  // R2 (64MB): xnormsq (early) / v2bf (QK epi out)
  float* xnormsq = (float*)p;
  ushort_t* v2bf = (ushort_t*)p;
  p += MAT * 4;
  // R3 (32MB): combHi (out_mfma out)
  ushort_t* combHi = (ushort_t*)p;
  p += MAT * 2;
  // R4 (32MB): Xbf; later outBf (final gemm out)
  ushort_t* Xbf = (ushort_t*)p;
  ushort_t* outBf = Xbf;
  p += MAT * 2;
  float* denom = (float*)p;   p += (size_t)NHEADS * N_NODES * 4;
  float* v2sum = (float*)p;   p += 1024 * 4;
  float* ctxT = (float*)p;    p += (size_t)NHEADS * 4096 * 4;
  float* mxhsq = (float*)p;   p += (size_t)NHEADS * N_NODES * 4;
  float* reluhsq = (float*)p; p += (size_t)NHEADS * N_NODES * 4;
  float* scaleV = (float*)p;  p += (size_t)N_NODES * 4;
  const size_t need = (size_t)(p - (char*)d_ws);
  if (ws_size < need) return;

  // scratch inside d_out (64MB; all consumed before the final rowtrans writes it):
  uchar_t* Wq8 = (uchar_t*)d_out;                       // [0,1M) fp8 Wq^T (16x, permuted)
  uchar_t* Wk8 = Wq8 + (size_t)DIMV * DIMV;             // [1M,2M) fp8 Wk^T (stacked QK rows)
  ushort_t* WtV = (ushort_t*)(Wq8 + 2 * (size_t)DIMV * DIMV);   // [2M,4M) bf16 Wv^T
  ushort_t* WffT = WtV + (size_t)DIMV * DIMV;           // [4M,6M) bf16 Wff^T
  uchar_t* Xf8 = (uchar_t*)d_out + 8 * 1024 * 1024;     // [8M,24M) fp8 X (16x, permuted)

  cvt_norm_kernel<<<N_NODES, 256, 0, stream>>>(X, Xbf, Xf8, xnormsq);
  transW4_kernel<<<dim3(32, 32, 4), 256, 0, stream>>>(Wq, Wk, Wv, Wff, Wq8, Wk8, WtV, WffT);
  // V path: mxV bf16 + per-(row,head) stats; then closed-form scaleV + denom
  gemm_bf<4, 4><<<256, 512, 0, stream>>>(Xbf, WtV, mxhsq, reluhsq, mxV);
  vscale_kernel<<<N_NODES / 256, 256, 0, stream>>>(xnormsq, mxhsq, reluhsq, scaleV, denom);
  // zero v2sum + ctxT (contiguous)
  hipMemsetAsync(v2sum, 0, (1024 + 4096 * NHEADS) * sizeof(float), stream);
  // QK fused (fp8): stacked [Wq8;Wk8]; emits v1 (cols<1024) and v2 + v2sum (cols>=1024)
  gemm_f8qk<8><<<512, 512, 0, stream>>>(Xf8, Wq8, bq, bk, denom, mask, v2sum, v1bf, v2bf);
  // context (MFMA; reads mxV with inline sV*relu)
  context_kernel<<<dim3(32, NHEADS), 256, 0, stream>>>(v2bf, mxV, scaleV, denom, mask, ctxT);
  // combnorm aliases mxV: zero only after context consumed mxV
  hipMemsetAsync(combnorm, 0, N_NODES * sizeof(float), stream);
  // attention out -> combHi + row norms
  out_mfma_kernel<<<dim3(N_NODES / 256, NHEADS), 256, 0, stream>>>(v1bf, v2sum, ctxT, combHi,
                                                                   combnorm);
  // final: single bf16 GEMM comb@Wff -> outBf, then rowtrans -> d_out
  gemm_bf<0, 4><<<256, 512, 0, stream>>>(combHi, WffT, nullptr, nullptr, outBf);
  rowtrans_kernel<<<N_NODES, 256, 0, stream>>>(outBf, combnorm, out);
}

// Round 18
// 330.502 us; speedup vs baseline: 2.0922x; 1.0349x over previous
//
#include <hip/hip_runtime.h>
#include <hip/hip_bf16.h>
#include <math.h>

#define N_NODES 16384
#define DIMV 1024
#define NHEADS 16
#define HEADD 64

typedef __attribute__((ext_vector_type(8))) short short8;
typedef __attribute__((ext_vector_type(4))) float f32x4;
typedef __attribute__((ext_vector_type(2))) long long2_t;
typedef unsigned short ushort_t;
typedef unsigned char uchar_t;

// async global->LDS, 16B per lane
#define GLD16(gptr, lptr)                                                                 \
  __builtin_amdgcn_global_load_lds((const __attribute__((address_space(1))) void*)(gptr), \
                                   (__attribute__((address_space(3))) void*)(lptr), 16, 0, 0)

// ---------- helpers ----------

__device__ __forceinline__ float waveReduceSum(float v) {
#pragma unroll
  for (int m = 32; m; m >>= 1) v += __shfl_xor(v, m);
  return v;
}

__device__ __forceinline__ float blockReduceSum(float v, float* red) {
  float w = waveReduceSum(v);
  __syncthreads();
  if ((threadIdx.x & 63) == 0) red[threadIdx.x >> 6] = w;
  __syncthreads();
  return red[0] + red[1] + red[2] + red[3];
}

// elu(z)+1: z>0 -> z+1; z<=0 -> expm1(z)+1 == e^z (exact identity).
__device__ __forceinline__ float elup1_fast(float z) {
  return z > 0.0f ? z + 1.0f : __expf(z);
}

__device__ __forceinline__ float clampabs(float x, float eps) {
  float s = (x >= 0.0f) ? 1.0f : -1.0f;
  return s * fmaxf(fabsf(x), eps);
}

// fp32 -> bf16 bits, RNE
__device__ __forceinline__ ushort_t f2b(float x) {
  unsigned u = __float_as_uint(x);
  unsigned r = (u + 0x7FFFu + ((u >> 16) & 1u)) >> 16;
  return (ushort_t)r;
}
__device__ __forceinline__ float b2f(ushort_t h) {
  return __uint_as_float(((unsigned)h) << 16);
}

// fp32 -> OCP e4m3 (RNE, flush-to-zero below 2^-6, clamp at 448). Inputs pre-scaled x16.
__device__ __forceinline__ uchar_t f2e4m3(float x) {
  unsigned u = __float_as_uint(x);
  unsigned s = (u >> 24) & 0x80u;
  unsigned a = u & 0x7fffffffu;
  if (a < 0x3c800000u) return (uchar_t)s;            // |x| < 2^-6 -> 0
  if (a > 0x43e00000u) return (uchar_t)(s | 0x7eu);  // clamp to 448
  unsigned lsb = (a >> 20) & 1u;
  a += 0x7ffffu + lsb;                               // RNE into 3-bit mantissa
  unsigned e = (a >> 23) - 120u;                     // -127 + bias 7
  unsigned m = (a >> 20) & 7u;
  return (uchar_t)(s | (e << 3) | m);
}

// ---------- X -> fp8(16x, permuted/swizzled) + row sumsq ----------
// fp8 global layout (per row n, per 64-k block): byte = (g^((n>>1)&3))*16 + ks*8 + e
// where k = k64*64 + ks*32 + g*8 + e. This IS the LDS layout -> GLD16 stays linear,
// and b128 fragment reads are 2 lanes/bank (free).
__global__ __launch_bounds__(256) void cvt_norm_kernel(const float* __restrict__ src,
                                                       uchar_t* __restrict__ xf8,
                                                       float* __restrict__ rowsq) {
  __shared__ float red[4];
  const int row = blockIdx.x;
  const int t = threadIdx.x;
  float4 x4 = ((const float4*)(src + (size_t)row * DIMV))[t];
  unsigned pk = (unsigned)f2e4m3(x4.x * 16.f) | ((unsigned)f2e4m3(x4.y * 16.f) << 8) |
                ((unsigned)f2e4m3(x4.z * 16.f) << 16) | ((unsigned)f2e4m3(x4.w * 16.f) << 24);
  const int g = (t >> 1) & 3, ks = (t >> 3) & 1, k64 = t >> 4, e0 = (t & 1) << 2;
  *(unsigned*)(xf8 + (size_t)row * DIMV + k64 * 64 + ((g ^ ((row >> 1) & 3)) << 4) +
               (ks << 3) + e0) = pk;
  float s = x4.x * x4.x + x4.y * x4.y + x4.z * x4.z + x4.w * x4.w;
  s = blockReduceSum(s, red);
  if (t == 0) rowsq[row] = s;
}

// fused quad transpose: z in {0,1,2} -> fp8(16x, permuted) {Wq,Wk,Wv}; z=3 -> bf16 Wff
__global__ __launch_bounds__(256) void transW4_kernel(const float* __restrict__ s0,
                                                      const float* __restrict__ s1,
                                                      const float* __restrict__ s2,
                                                      const float* __restrict__ s3,
                                                      uchar_t* __restrict__ d0,
                                                      uchar_t* __restrict__ d1,
                                                      uchar_t* __restrict__ d2,
                                                      ushort_t* __restrict__ d3) {
  __shared__ float tile[32][33];
  const int z = blockIdx.z;
  const float* src = (z == 0) ? s0 : (z == 1) ? s1 : (z == 2) ? s2 : s3;
  const int bx = blockIdx.x * 32, by = blockIdx.y * 32;
  const int tx = threadIdx.x & 31, ty = threadIdx.x >> 5;
#pragma unroll
  for (int i = 0; i < 32; i += 8) tile[ty + i][tx] = src[(size_t)(by + ty + i) * DIMV + bx + tx];
  __syncthreads();
  if (z < 3) {
    uchar_t* dst = (z == 0) ? d0 : (z == 1) ? d1 : d2;
#pragma unroll
    for (int i = 0; i < 32; i += 8) {
      const int n = bx + ty + i, k = by + tx;
      const size_t byte = (size_t)n * DIMV + ((k >> 6) << 6) +
                          ((((k >> 3) & 3) ^ ((n >> 1) & 3)) << 4) + (((k >> 5) & 1) << 3) +
                          (k & 7);
      dst[byte] = f2e4m3(16.f * tile[tx][ty + i]);
    }
  } else {
#pragma unroll
    for (int i = 0; i < 32; i += 8)
      d3[(size_t)(bx + ty + i) * DIMV + by + tx] = f2b(tile[tx][ty + i]);
  }
}

// ---------- bf16 MFMA GEMM (final comb@Wff), 256x256, BK=64, 8 waves, dbuf, swizzled ----
template <int NB>
__global__ __launch_bounds__(512, 2) void gemm_bf(const ushort_t* __restrict__ A,
                                                  const ushort_t* __restrict__ Bt,
                                                  ushort_t* __restrict__ Cq) {
  __shared__ ushort_t As[2][256 * 64];  // 32 KB per buf
  __shared__ ushort_t Bs[2][256 * 64];
  const int bid = blockIdx.x;
  const int nwg = NB * 64;
  const int swz = (bid & 7) * (nwg / 8) + (bid >> 3);
  const int bm = (swz / NB) * 256;
  const int bn = (swz % NB) * 256;
  const int t = threadIdx.x;
  const int w = t >> 6, lane = t & 63, l15 = lane & 15;
  const int wr = (w >> 2) * 128;
  const int wcn = (w & 3) * 64;
  const int g4 = lane >> 4;
  const int e7 = l15 & 7;
  const int uo0 = (g4 ^ e7) * 8;
  const int uo1 = ((4 + g4) ^ e7) * 8;

  const int rowin = lane >> 3;
  const int ksh = ((lane & 7) ^ ((lane >> 3) & 7)) * 8;
  const ushort_t *gA[4], *gB[4];
  int lofs[4];
#pragma unroll
  for (int c = 0; c < 4; ++c) {
    const int ch = w + 8 * c;
    lofs[c] = ch * 512;
    gA[c] = A + (size_t)(bm + ch * 8 + rowin) * DIMV + ksh;
    gB[c] = Bt + (size_t)(bn + ch * 8 + rowin) * DIMV + ksh;
  }

#define STAGE_G(buf, k0)                              \
  do {                                                \
    _Pragma("unroll") for (int c = 0; c < 4; ++c) {   \
      GLD16(gA[c] + (k0), &As[buf][lofs[c]]);         \
      GLD16(gB[c] + (k0), &Bs[buf][lofs[c]]);         \
    }                                                 \
  } while (0)

  f32x4 acc[8][4];
#pragma unroll
  for (int i = 0; i < 8; ++i)
#pragma unroll
    for (int j = 0; j < 4; ++j) acc[i][j] = (f32x4){0.f, 0.f, 0.f, 0.f};

  STAGE_G(0, 0);
  __syncthreads();
  int cur = 0;
  for (int k0 = 0; k0 < DIMV; k0 += 64) {
    if (k0 + 64 < DIMV) STAGE_G(cur ^ 1, k0 + 64);
#pragma unroll
    for (int ks = 0; ks < 2; ++ks) {
      const int uo = ks ? uo1 : uo0;
      short8 bf[4];
#pragma unroll
      for (int j = 0; j < 4; ++j)
        bf[j] = *(const short8*)&Bs[cur][(wcn + j * 16 + l15) * 64 + uo];
#pragma unroll
      for (int i = 0; i < 8; ++i) {
        short8 af = *(const short8*)&As[cur][(wr + i * 16 + l15) * 64 + uo];
#pragma unroll
        for (int j = 0; j < 4; ++j)
          acc[i][j] = __builtin_amdgcn_mfma_f32_16x16x32_bf16(af, bf[j], acc[i][j], 0, 0, 0);
      }
    }
    __syncthreads();
    cur ^= 1;
  }
#undef STAGE_G

  const int rbase = (lane >> 4) * 4;
#pragma unroll
  for (int j = 0; j < 4; ++j) {
    const int col = bn + wcn + j * 16 + l15;
#pragma unroll
    for (int i = 0; i < 8; ++i)
#pragma unroll
      for (int r = 0; r < 4; ++r)
        Cq[(size_t)(bm + wr + i * 16 + rbase + r) * DIMV + col] = f2b(acc[i][j][r]);
  }
}

// ---------- fp8 MFMA GEMM: 256x256 tile, BK=64, 8 waves, dbuf 2-phase ----------
// Operands pre-scaled x16 and pre-permuted; acc scaled by 1/256 in epilogue.
// EPI 3 (QK fused): cols<1024 -> Cq=bf16(v1); cols>=1024 -> Ck=bf16(v2)+v2sum atomics.
// EPI 4 (V): Cq = bf16(mx) + per-(row,head) stats {sum mx^2, sum relu(mx)^2}.
template <int EPI, int NB>
__global__ __launch_bounds__(512, 2) void gemm_f8(const uchar_t* __restrict__ Xf8,
                                                  const uchar_t* __restrict__ Bt8,
                                                  const float* __restrict__ biasQ,
                                                  const float* __restrict__ biasK,
                                                  const float* __restrict__ denom,
                                                  const float* __restrict__ mask,
                                                  float* __restrict__ v2sum,
                                                  float* __restrict__ mxhsq,
                                                  float* __restrict__ reluhsq,
                                                  ushort_t* __restrict__ Cq,
                                                  ushort_t* __restrict__ Ck) {
  __shared__ uchar_t LB[65536];  // A: buf*16384, B: 32768 + buf*16384
  const int bid = blockIdx.x;
  const int nwg = NB * 64;
  const int swz = (bid & 7) * (nwg / 8) + (bid >> 3);
  const int bm = (swz / NB) * 256;
  const int bn = (swz % NB) * 256;
  const int t = threadIdx.x;
  const int w = t >> 6, lane = t & 63, l15 = lane & 15;
  const int wr = (w >> 2) * 128;
  const int wcn = (w & 3) * 64;
  const int g = lane >> 4;
  const int aoff = ((g ^ ((l15 >> 1) & 3)) << 4);  // swizzled granule byte offset

  const uchar_t *gA[2], *gB[2];
  int lofs[2];
#pragma unroll
  for (int c = 0; c < 2; ++c) {
    const int row = (t >> 2) + c * 128;
    lofs[c] = t * 16 + c * 8192;
    gA[c] = Xf8 + (size_t)(bm + row) * DIMV + (t & 3) * 16;
    gB[c] = Bt8 + (size_t)(bn + row) * DIMV + (t & 3) * 16;
  }

#define STAGE_F(buf, kb)                                         \
  do {                                                           \
    _Pragma("unroll") for (int c = 0; c < 2; ++c) {              \
      GLD16(gA[c] + (kb), &LB[(buf) * 16384 + lofs[c]]);         \
      GLD16(gB[c] + (kb), &LB[32768 + (buf) * 16384 + lofs[c]]); \
    }                                                            \
  } while (0)

  f32x4 acc[8][4];
#pragma unroll
  for (int i = 0; i < 8; ++i)
#pragma unroll
    for (int j = 0; j < 4; ++j) acc[i][j] = (f32x4){0.f, 0.f, 0.f, 0.f};

  STAGE_F(0, 0);
  __syncthreads();
  int cur = 0;
  for (int kt = 0; kt < 16; ++kt) {
    if (kt < 15) STAGE_F(cur ^ 1, (kt + 1) * 64);
    long2_t bf[4];
#pragma unroll
    for (int j = 0; j < 4; ++j)
      bf[j] = *(const long2_t*)&LB[32768 + cur * 16384 + (wcn + j * 16 + l15) * 64 + aoff];
#pragma unroll
    for (int i = 0; i < 8; ++i) {
      long2_t af = *(const long2_t*)&LB[cur * 16384 + (wr + i * 16 + l15) * 64 + aoff];
#pragma unroll
      for (int j = 0; j < 4; ++j) {
        acc[i][j] = __builtin_amdgcn_mfma_f32_16x16x32_fp8_fp8(af.x, bf[j].x, acc[i][j], 0, 0, 0);
        acc[i][j] = __builtin_amdgcn_mfma_f32_16x16x32_fp8_fp8(af.y, bf[j].y, acc[i][j], 0, 0, 0);
      }
    }
    __syncthreads();
    cur ^= 1;
  }
#undef STAGE_F

  // epilogue (acc scaled by 1/256). C/D layout: col=lane&15, row=(lane>>4)*4+r.
  const int rbase = (lane >> 4) * 4;
  const int h = ((bn + wcn) >> 6) & (NHEADS - 1);
  if (EPI == 4) {
#pragma unroll
    for (int i = 0; i < 8; ++i) {
#pragma unroll
      for (int r = 0; r < 4; ++r) {
        const int row = bm + wr + i * 16 + rbase + r;
        float smx = 0.f, srel = 0.f;
#pragma unroll
        for (int j = 0; j < 4; ++j) {
          float val = acc[i][j][r] * 0.00390625f;
          Cq[(size_t)row * DIMV + bn + wcn + j * 16 + l15] = f2b(val);
          smx = fmaf(val, val, smx);
          float rv = fmaxf(val, 0.f);
          srel = fmaf(rv, rv, srel);
        }
        smx += __shfl_xor(smx, 1); smx += __shfl_xor(smx, 2);
        smx += __shfl_xor(smx, 4); smx += __shfl_xor(smx, 8);
        srel += __shfl_xor(srel, 1); srel += __shfl_xor(srel, 2);
        srel += __shfl_xor(srel, 4); srel += __shfl_xor(srel, 8);
        if (l15 == 0) {
          mxhsq[(size_t)h * N_NODES + row] = smx;
          reluhsq[(size_t)h * N_NODES + row] = srel;
        }
      }
    }
  } else {
    const bool isK = (bn >= DIMV);  // block-uniform
    int lc[4];
    float bb[4];
#pragma unroll
    for (int j = 0; j < 4; ++j) {
      lc[j] = (bn + wcn + j * 16 + l15) & (DIMV - 1);
      bb[j] = isK ? biasK[lc[j]] : biasQ[lc[j]];
    }
    float csum[4] = {0.f, 0.f, 0.f, 0.f};
#pragma unroll
    for (int i = 0; i < 8; ++i) {
#pragma unroll
      for (int r = 0; r < 4; ++r) {
        const int row = bm + wr + i * 16 + rbase + r;
        const float invdp = 1.0f / denom[(size_t)h * N_NODES + row];
        float den = 0.f, mk = 0.f;
        if (isK) {
          den = clampabs(2.0f * invdp - 1.0f, 1e-10f);
          mk = mask[row];
        }
#pragma unroll
        for (int j = 0; j < 4; ++j) {
          float val = elup1_fast((acc[i][j][r] * 0.00390625f + bb[j]) * invdp);
          if (isK) {
            val = den * val * mk;
            csum[j] += val;
            Ck[(size_t)row * DIMV + lc[j]] = f2b(val);
          } else {
            Cq[(size_t)row * DIMV + lc[j]] = f2b(val);
          }
        }
      }
    }
    if (isK) {
#pragma unroll
      for (int j = 0; j < 4; ++j) atomicAdd(&v2sum[lc[j]], csum[j]);
    }
  }
}

// ---------- vscale: per-row mobius+kappa scalars from stats; emits scaleV + denom ----------
__global__ __launch_bounds__(256) void vscale_kernel(const float* __restrict__ xnormsq,
                                                     const float* __restrict__ mxhsq,
                                                     const float* __restrict__ reluhsq,
                                                     float* __restrict__ scaleV,
                                                     float* __restrict__ denom) {
  const int row = blockIdx.x * 256 + threadIdx.x;
  float sm = 0.f, sr = 0.f;
  float hs[NHEADS];
#pragma unroll
  for (int h = 0; h < NHEADS; ++h) {
    sm += mxhsq[(size_t)h * N_NODES + row];
    hs[h] = reluhsq[(size_t)h * N_NODES + row];
    sr += hs[h];
  }
  float sx = xnormsq[row];
  float xn = fmaxf(sqrtf(sx), 1e-15f);
  float mxn = fmaxf(sqrtf(sm), 1e-15f);
  float cx = fminf(xn, 1.0f - 1e-7f);
  float t1 = tanhf(mxn / xn * atanhf(cx));
  float s1 = t1 / mxn;
  float yn = fmaxf(fabsf(t1), 1e-15f);
  float a = atanhf(fminf(yn, 1.0f - 1e-7f)) / yn;
  float k1 = a * s1;
  float un = fmaxf(k1 * sqrtf(sr), 1e-15f);
  float t2 = tanhf(un);
  float s2 = t2 / un;
  if (t2 > 0.996f) s2 *= 0.996f / t2;
  float sV = s2 * k1;
  scaleV[row] = sV;
#pragma unroll
  for (int h = 0; h < NHEADS; ++h)
    denom[(size_t)h * N_NODES + row] = fmaxf(1.0f - sV * sV * hs[h], 1e-15f);
}

// ---------- row transform (final): mobius_matvec tail + kappa_relu ----------
__global__ __launch_bounds__(256) void rowtrans_kernel(const ushort_t* __restrict__ msrc,
                                                       const float* __restrict__ rowsq,
                                                       float* __restrict__ dstv) {
  __shared__ float red[4];
  const int row = blockIdx.x;
  const int t = threadIdx.x;
  uint2 mraw = ((const uint2*)(msrc + (size_t)row * DIMV))[t];
  ushort_t* mh = (ushort_t*)&mraw;
  float4 m4 = make_float4(b2f(mh[0]), b2f(mh[1]), b2f(mh[2]), b2f(mh[3]));
  float sm = m4.x * m4.x + m4.y * m4.y + m4.z * m4.z + m4.w * m4.w;
  sm = blockReduceSum(sm, red);
  float sx = rowsq[row];

  float xn = fmaxf(sqrtf(sx), 1e-15f);
  float mxn = fmaxf(sqrtf(sm), 1e-15f);
  float cx = fminf(xn, 1.0f - 1e-7f);
  float t1 = tanhf(mxn / xn * atanhf(cx));
  float s1 = t1 / mxn;

  float yn = fmaxf(fabsf(t1), 1e-15f);
  float a = atanhf(fminf(yn, 1.0f - 1e-7f)) / yn;
  float k1 = a * s1;
  float4 u = make_float4(fmaxf(k1 * m4.x, 0.0f), fmaxf(k1 * m4.y, 0.0f),
                         fmaxf(k1 * m4.z, 0.0f), fmaxf(k1 * m4.w, 0.0f));
  float su = u.x * u.x + u.y * u.y + u.z * u.z + u.w * u.w;
  su = blockReduceSum(su, red);

  float un = fmaxf(sqrtf(su), 1e-15f);
  float t2 = tanhf(un);
  float s2 = t2 / un;
  if (t2 > 0.996f) s2 *= 0.996f / t2;
  float4 o = make_float4(s2 * u.x, s2 * u.y, s2 * u.z, s2 * u.w);
  ((float4*)(dstv + (size_t)row * DIMV))[t] = o;
}

// ---------- context (MFMA): ctxT[h][e][d] = sum_n v2[h,n,d]*(c1*relu(mx))[h,n,e] ----------
__global__ __launch_bounds__(256) void context_kernel(const ushort_t* __restrict__ v2buf,
                                                      const ushort_t* __restrict__ mxVbuf,
                                                      const float* __restrict__ scaleV,
                                                      const float* __restrict__ denom,
                                                      const float* __restrict__ mask,
                                                      float* __restrict__ ctxT) {
  __shared__ ushort_t s2T[64 * 64];  // [d][n-swz], 8 KB
  __shared__ ushort_t sxT[64 * 64];  // [e][n-swz], 8 KB
  const int h = blockIdx.y;
  const int t = threadIdx.x;
  const int w = t >> 6, lane = t & 63, l15 = lane & 15, g = lane >> 4;
  const int e7 = l15 & 7;
  const int uo0 = (g ^ e7) * 8;        // ks=0 swizzled unit offset (elems)
  const int uo1 = ((4 + g) ^ e7) * 8;  // ks=1

  f32x4 acc[4];
#pragma unroll
  for (int j = 0; j < 4; ++j) acc[j] = (f32x4){0.f, 0.f, 0.f, 0.f};

  const int rbase = blockIdx.x * 512;
  for (int c = 0; c < 8; ++c) {
#pragma unroll
    for (int i = 0; i < 4; ++i) {
      int f = i * 256 + t;
      int r = f >> 4;          // n within chunk (0..63)
      int cc = (f & 15) * 4;   // d/e base
      int row = rbase + c * 64 + r;
      uint2 araw = *(const uint2*)(v2buf + (size_t)row * DIMV + h * HEADD + cc);
      ushort_t* ah = (ushort_t*)&araw;
      float dp = denom[(size_t)h * N_NODES + row];
      float gamma = 2.0f / dp;
      float den = clampabs(gamma - 1.0f, 1e-10f);
      float c1 = gamma / den * mask[row] * scaleV[row];
      uint2 braw = *(const uint2*)(mxVbuf + (size_t)row * DIMV + h * HEADD + cc);
      ushort_t* bh = (ushort_t*)&braw;
      const int rhi = r >> 3, rlo = r & 7;
#pragma unroll
      for (int q = 0; q < 4; ++q) {
        const int d = cc + q;
        const int pos = d * 64 + ((rhi ^ (d & 7)) << 3) + rlo;
        s2T[pos] = ah[q];
        sxT[pos] = f2b(c1 * fmaxf(b2f(bh[q]), 0.f));
      }
    }
    __syncthreads();
#pragma unroll
    for (int ks = 0; ks < 2; ++ks) {
      const int uo = ks ? uo1 : uo0;
      short8 af = *(const short8*)&s2T[(w * 16 + l15) * 64 + uo];
#pragma unroll
      for (int j = 0; j < 4; ++j) {
        short8 bfv = *(const short8*)&sxT[(j * 16 + l15) * 64 + uo];
        acc[j] = __builtin_amdgcn_mfma_f32_16x16x32_bf16(af, bfv, acc[j], 0, 0, 0);
      }
    }
    __syncthreads();
  }
#pragma unroll
  for (int j = 0; j < 4; ++j)
#pragma unroll
    for (int r = 0; r < 4; ++r)
      atomicAdd(&ctxT[h * 4096 + (j * 16 + l15) * 64 + w * 16 + g * 4 + r], acc[j][r]);
}

// ---------- out (MFMA): [out|D] = v1 @ [ctx|v2sum]; tail; emit combHi + rownorm atomics ----------
__global__ __launch_bounds__(256) void out_mfma_kernel(const ushort_t* __restrict__ v1bf,
                                                       const float* __restrict__ v2sum,
                                                       const float* __restrict__ ctxT,
                                                       ushort_t* __restrict__ combHi,
                                                       float* __restrict__ combnorm) {
  __shared__ ushort_t Blds[80][88];
  const int h = blockIdx.y;
  const int bm = blockIdx.x * 256;
  const int t = threadIdx.x;
  const int w = t >> 6, lane = t & 63, l15 = lane & 15;
  const int kk = (lane >> 4) * 8;

  for (int idx = t; idx < 80 * 64; idx += 256) {
    int e = idx >> 6, d = idx & 63;
    float v = 0.0f;
    if (e < 64) v = ctxT[h * 4096 + e * 64 + d];
    else if (e == 64) v = v2sum[h * 64 + d];
    Blds[e][d] = f2b(v);
  }
  __syncthreads();

  f32x4 acc[4][5];
#pragma unroll
  for (int i = 0; i < 4; ++i)
#pragma unroll
    for (int j = 0; j < 5; ++j) acc[i][j] = (f32x4){0.f, 0.f, 0.f, 0.f};
#pragma unroll
  for (int ks = 0; ks < 2; ++ks) {
    short8 bfr[5];
#pragma unroll
    for (int j = 0; j < 5; ++j) bfr[j] = *(const short8*)&Blds[j * 16 + l15][ks * 32 + kk];
#pragma unroll
    for (int i = 0; i < 4; ++i) {
      short8 af = *(const short8*)(v1bf + (size_t)(bm + w * 64 + i * 16 + l15) * DIMV +
                                   h * HEADD + ks * 32 + kk);
#pragma unroll
      for (int j = 0; j < 5; ++j)
        acc[i][j] = __builtin_amdgcn_mfma_f32_16x16x32_bf16(af, bfr[j], acc[i][j], 0, 0, 0);
    }
  }

  const int g4 = (lane >> 4) * 4;
#pragma unroll
  for (int i = 0; i < 4; ++i) {
#pragma unroll
    for (int r = 0; r < 4; ++r) {
      const int row = bm + w * 64 + i * 16 + g4 + r;
      float D = __shfl(acc[i][4][r], lane & 48);
      float Dinv = 1.0f / (D == 0.0f ? 1e-5f : D);
      float o[4];
      float s = 0.0f;
#pragma unroll
      for (int j = 0; j < 4; ++j) {
        o[j] = acc[i][j][r] * Dinv;
        s = fmaf(o[j], o[j], s);
      }
      s += __shfl_xor(s, 1); s += __shfl_xor(s, 2);
      s += __shfl_xor(s, 4); s += __shfl_xor(s, 8);
      float n1 = fmaxf(sqrtf(s), 1e-15f);
      float sc = 1.0f;
      if (n1 > 0.996f) sc = 0.996f / n1;
      float xn = fmaxf(fminf(n1, 0.996f), 1e-15f);
      float cx = fminf(xn, 1.0f - 1e-7f);
      // tanh(0.5*atanh(cx)) == cx / (1 + sqrt(1 - cx^2)); t2 <= 0.915 -> no reprojection.
      float t2 = cx / (1.0f + sqrtf(1.0f - cx * cx));
      sc *= t2 / xn;
      if (l15 == 0) atomicAdd(&combnorm[row], s * sc * sc);
#pragma unroll
      for (int j = 0; j < 4; ++j) {
        float ov = o[j] * sc;
        combHi[(size_t)row * DIMV + h * HEADD + j * 16 + l15] = f2b(ov);
      }
    }
  }
}

// ---------- launch ----------

extern "C" void kernel_launch(void* const* d_in, const int* in_sizes, int n_in,
                              void* d_out, int out_size, void* d_ws, size_t ws_size,
                              hipStream_t stream) {
  const float* X = (const float*)d_in[0];
  const float* mask = (const float*)d_in[1];
  const float* Wq = (const float*)d_in[2];
  const float* bq = (const float*)d_in[3];
  const float* Wk = (const float*)d_in[4];
  const float* bk = (const float*)d_in[5];
  const float* Wv = (const float*)d_in[6];
  const float* Wff = (const float*)d_in[7];
  float* out = (float*)d_out;

  const size_t MAT = (size_t)N_NODES * DIMV;
  char* p = (char*)d_ws;
  // R1 (64MB): first half v1bf (QK epi out); second half mxV bf16, later combnorm
  ushort_t* v1bf = (ushort_t*)p;
  ushort_t* mxV = (ushort_t*)(p + MAT * 2);
  float* combnorm = (float*)(p + MAT * 2);
  p += MAT * 4;
  // R2 (64MB): xnormsq (early) / v2bf (QK epi out)
  float* xnormsq = (float*)p;
  ushort_t* v2bf = (ushort_t*)p;
  p += MAT * 4;
  // R3 (32MB): combHi (out_mfma out)
  ushort_t* combHi = (ushort_t*)p;
  p += MAT * 2;
  // R4 (32MB): outBf (final gemm out)
  ushort_t* outBf = (ushort_t*)p;
  p += MAT * 2;
  float* denom = (float*)p;   p += (size_t)NHEADS * N_NODES * 4;
  float* v2sum = (float*)p;   p += 1024 * 4;
  float* ctxT = (float*)p;    p += (size_t)NHEADS * 4096 * 4;
  float* mxhsq = (float*)p;   p += (size_t)NHEADS * N_NODES * 4;
  float* reluhsq = (float*)p; p += (size_t)NHEADS * N_NODES * 4;
  float* scaleV = (float*)p;  p += (size_t)N_NODES * 4;
  const size_t need = (size_t)(p - (char*)d_ws);
  if (ws_size < need) return;

  // scratch inside d_out (64MB; all consumed before the final rowtrans writes it):
  uchar_t* Wq8 = (uchar_t*)d_out;                        // [0,1M) fp8 Wq^T (16x, permuted)
  uchar_t* Wk8 = Wq8 + (size_t)DIMV * DIMV;              // [1M,2M) fp8 Wk^T (stacked QK rows)
  uchar_t* Wv8 = Wk8 + (size_t)DIMV * DIMV;              // [2M,3M) fp8 Wv^T
  ushort_t* WffT = (ushort_t*)(Wv8 + (size_t)DIMV * DIMV);  // [3M,5M) bf16 Wff^T
  uchar_t* Xf8 = (uchar_t*)d_out + 8 * 1024 * 1024;      // [8M,24M) fp8 X (16x, permuted)

  cvt_norm_kernel<<<N_NODES, 256, 0, stream>>>(X, Xf8, xnormsq);
  transW4_kernel<<<dim3(32, 32, 4), 256, 0, stream>>>(Wq, Wk, Wv, Wff, Wq8, Wk8, Wv8, WffT);
  // V path (fp8): mx bf16 + per-(row,head) stats; then closed-form scaleV + denom
  gemm_f8<4, 4><<<256, 512, 0, stream>>>(Xf8, Wv8, nullptr, nullptr, nullptr, nullptr,
                                         nullptr, mxhsq, reluhsq, mxV, nullptr);
  vscale_kernel<<<N_NODES / 256, 256, 0, stream>>>(xnormsq, mxhsq, reluhsq, scaleV, denom);
  // zero v2sum + ctxT (contiguous)
  hipMemsetAsync(v2sum, 0, (1024 + 4096 * NHEADS) * sizeof(float), stream);
  // QK fused (fp8): stacked [Wq8;Wk8]; emits v1 (cols<1024) and v2 + v2sum (cols>=1024)
  gemm_f8<3, 8><<<512, 512, 0, stream>>>(Xf8, Wq8, bq, bk, denom, mask, v2sum, nullptr,
                                         nullptr, v1bf, v2bf);
  // context (MFMA; reads mxV with inline sV*relu)
  context_kernel<<<dim3(32, NHEADS), 256, 0, stream>>>(v2bf, mxV, scaleV, denom, mask, ctxT);
  // combnorm aliases mxV: zero only after context consumed mxV
  hipMemsetAsync(combnorm, 0, N_NODES * sizeof(float), stream);
  // attention out -> combHi + row norms
  out_mfma_kernel<<<dim3(N_NODES / 256, NHEADS), 256, 0, stream>>>(v1bf, v2sum, ctxT, combHi,
                                                                   combnorm);
  // final: single bf16 GEMM comb@Wff -> outBf, then rowtrans -> d_out
  gemm_bf<4><<<256, 512, 0, stream>>>(combHi, WffT, outBf);
  rowtrans_kernel<<<N_NODES, 256, 0, stream>>>(outBf, combnorm, out);
}

// Round 19
// 329.700 us; speedup vs baseline: 2.0973x; 1.0024x over previous
//
#include <hip/hip_runtime.h>
#include <hip/hip_bf16.h>
#include <math.h>

#define N_NODES 16384
#define DIMV 1024
#define NHEADS 16
#define HEADD 64

typedef __attribute__((ext_vector_type(8))) short short8;
typedef __attribute__((ext_vector_type(4))) float f32x4;
typedef __attribute__((ext_vector_type(2))) long long2_t;
typedef unsigned short ushort_t;
typedef unsigned char uchar_t;

// async global->LDS, 16B per lane
#define GLD16(gptr, lptr)                                                                 \
  __builtin_amdgcn_global_load_lds((const __attribute__((address_space(1))) void*)(gptr), \
                                   (__attribute__((address_space(3))) void*)(lptr), 16, 0, 0)

// ---------- helpers ----------

__device__ __forceinline__ float waveReduceSum(float v) {
#pragma unroll
  for (int m = 32; m; m >>= 1) v += __shfl_xor(v, m);
  return v;
}

__device__ __forceinline__ float blockReduceSum(float v, float* red) {
  float w = waveReduceSum(v);
  __syncthreads();
  if ((threadIdx.x & 63) == 0) red[threadIdx.x >> 6] = w;
  __syncthreads();
  return red[0] + red[1] + red[2] + red[3];
}

// elu(z)+1: z>0 -> z+1; z<=0 -> expm1(z)+1 == e^z (exact identity).
__device__ __forceinline__ float elup1_fast(float z) {
  return z > 0.0f ? z + 1.0f : __expf(z);
}

__device__ __forceinline__ float clampabs(float x, float eps) {
  float s = (x >= 0.0f) ? 1.0f : -1.0f;
  return s * fmaxf(fabsf(x), eps);
}

// fp32 -> bf16 bits, RNE
__device__ __forceinline__ ushort_t f2b(float x) {
  unsigned u = __float_as_uint(x);
  unsigned r = (u + 0x7FFFu + ((u >> 16) & 1u)) >> 16;
  return (ushort_t)r;
}
__device__ __forceinline__ float b2f(ushort_t h) {
  return __uint_as_float(((unsigned)h) << 16);
}

// fp32 -> OCP e4m3 (RNE, flush-to-zero below 2^-6, clamp at 448). Inputs pre-scaled x16.
__device__ __forceinline__ uchar_t f2e4m3(float x) {
  unsigned u = __float_as_uint(x);
  unsigned s = (u >> 24) & 0x80u;
  unsigned a = u & 0x7fffffffu;
  if (a < 0x3c800000u) return (uchar_t)s;            // |x| < 2^-6 -> 0
  if (a > 0x43e00000u) return (uchar_t)(s | 0x7eu);  // clamp to 448
  unsigned lsb = (a >> 20) & 1u;
  a += 0x7ffffu + lsb;                               // RNE into 3-bit mantissa
  unsigned e = (a >> 23) - 120u;                     // -127 + bias 7
  unsigned m = (a >> 20) & 7u;
  return (uchar_t)(s | (e << 3) | m);
}

// ---------- X -> fp8(16x, permuted/swizzled) + row sumsq ----------
// fp8 global layout (per row n, per 64-k block): byte = (g^((n>>1)&3))*16 + ks*8 + e
// where k = k64*64 + ks*32 + g*8 + e. This IS the LDS layout -> GLD16 stays linear,
// and b128 fragment reads are 2 lanes/bank (free).
__global__ __launch_bounds__(256) void cvt_norm_kernel(const float* __restrict__ src,
                                                       uchar_t* __restrict__ xf8,
                                                       float* __restrict__ rowsq) {
  __shared__ float red[4];
  const int row = blockIdx.x;
  const int t = threadIdx.x;
  float4 x4 = ((const float4*)(src + (size_t)row * DIMV))[t];
  unsigned pk = (unsigned)f2e4m3(x4.x * 16.f) | ((unsigned)f2e4m3(x4.y * 16.f) << 8) |
                ((unsigned)f2e4m3(x4.z * 16.f) << 16) | ((unsigned)f2e4m3(x4.w * 16.f) << 24);
  const int g = (t >> 1) & 3, ks = (t >> 3) & 1, k64 = t >> 4, e0 = (t & 1) << 2;
  *(unsigned*)(xf8 + (size_t)row * DIMV + k64 * 64 + ((g ^ ((row >> 1) & 3)) << 4) +
               (ks << 3) + e0) = pk;
  float s = x4.x * x4.x + x4.y * x4.y + x4.z * x4.z + x4.w * x4.w;
  s = blockReduceSum(s, red);
  if (t == 0) rowsq[row] = s;
}

// fused quad transpose: z in {0,1,2} -> fp8(16x, permuted) {Wq,Wk,Wv}; z=3 -> bf16 Wff
__global__ __launch_bounds__(256) void transW4_kernel(const float* __restrict__ s0,
                                                      const float* __restrict__ s1,
                                                      const float* __restrict__ s2,
                                                      const float* __restrict__ s3,
                                                      uchar_t* __restrict__ d0,
                                                      uchar_t* __restrict__ d1,
                                                      uchar_t* __restrict__ d2,
                                                      ushort_t* __restrict__ d3) {
  __shared__ float tile[32][33];
  const int z = blockIdx.z;
  const float* src = (z == 0) ? s0 : (z == 1) ? s1 : (z == 2) ? s2 : s3;
  const int bx = blockIdx.x * 32, by = blockIdx.y * 32;
  const int tx = threadIdx.x & 31, ty = threadIdx.x >> 5;
#pragma unroll
  for (int i = 0; i < 32; i += 8) tile[ty + i][tx] = src[(size_t)(by + ty + i) * DIMV + bx + tx];
  __syncthreads();
  if (z < 3) {
    uchar_t* dst = (z == 0) ? d0 : (z == 1) ? d1 : d2;
#pragma unroll
    for (int i = 0; i < 32; i += 8) {
      const int n = bx + ty + i, k = by + tx;
      const size_t byte = (size_t)n * DIMV + ((k >> 6) << 6) +
                          ((((k >> 3) & 3) ^ ((n >> 1) & 3)) << 4) + (((k >> 5) & 1) << 3) +
                          (k & 7);
      dst[byte] = f2e4m3(16.f * tile[tx][ty + i]);
    }
  } else {
#pragma unroll
    for (int i = 0; i < 32; i += 8)
      d3[(size_t)(bx + ty + i) * DIMV + by + tx] = f2b(tile[tx][ty + i]);
  }
}

// ---------- bf16 MFMA GEMM (final comb@Wff), 256x256, BK=64, 8 waves, dbuf, swizzled ----
template <int NB>
__global__ __launch_bounds__(512, 2) void gemm_bf(const ushort_t* __restrict__ A,
                                                  const ushort_t* __restrict__ Bt,
                                                  ushort_t* __restrict__ Cq) {
  __shared__ ushort_t As[2][256 * 64];  // 32 KB per buf
  __shared__ ushort_t Bs[2][256 * 64];
  const int bid = blockIdx.x;
  const int nwg = NB * 64;
  const int swz = (bid & 7) * (nwg / 8) + (bid >> 3);
  const int bm = (swz / NB) * 256;
  const int bn = (swz % NB) * 256;
  const int t = threadIdx.x;
  const int w = t >> 6, lane = t & 63, l15 = lane & 15;
  const int wr = (w >> 2) * 128;
  const int wcn = (w & 3) * 64;
  const int g4 = lane >> 4;
  const int e7 = l15 & 7;
  const int uo0 = (g4 ^ e7) * 8;
  const int uo1 = ((4 + g4) ^ e7) * 8;

  const int rowin = lane >> 3;
  const int ksh = ((lane & 7) ^ ((lane >> 3) & 7)) * 8;
  const ushort_t *gA[4], *gB[4];
  int lofs[4];
#pragma unroll
  for (int c = 0; c < 4; ++c) {
    const int ch = w + 8 * c;
    lofs[c] = ch * 512;
    gA[c] = A + (size_t)(bm + ch * 8 + rowin) * DIMV + ksh;
    gB[c] = Bt + (size_t)(bn + ch * 8 + rowin) * DIMV + ksh;
  }

#define STAGE_G(buf, k0)                              \
  do {                                                \
    _Pragma("unroll") for (int c = 0; c < 4; ++c) {   \
      GLD16(gA[c] + (k0), &As[buf][lofs[c]]);         \
      GLD16(gB[c] + (k0), &Bs[buf][lofs[c]]);         \
    }                                                 \
  } while (0)

  f32x4 acc[8][4];
#pragma unroll
  for (int i = 0; i < 8; ++i)
#pragma unroll
    for (int j = 0; j < 4; ++j) acc[i][j] = (f32x4){0.f, 0.f, 0.f, 0.f};

  STAGE_G(0, 0);
  __syncthreads();
  int cur = 0;
  for (int k0 = 0; k0 < DIMV; k0 += 64) {
    if (k0 + 64 < DIMV) STAGE_G(cur ^ 1, k0 + 64);
#pragma unroll
    for (int ks = 0; ks < 2; ++ks) {
      const int uo = ks ? uo1 : uo0;
      short8 bf[4];
#pragma unroll
      for (int j = 0; j < 4; ++j)
        bf[j] = *(const short8*)&Bs[cur][(wcn + j * 16 + l15) * 64 + uo];
#pragma unroll
      for (int i = 0; i < 8; ++i) {
        short8 af = *(const short8*)&As[cur][(wr + i * 16 + l15) * 64 + uo];
#pragma unroll
        for (int j = 0; j < 4; ++j)
          acc[i][j] = __builtin_amdgcn_mfma_f32_16x16x32_bf16(af, bf[j], acc[i][j], 0, 0, 0);
      }
    }
    __syncthreads();
    cur ^= 1;
  }
#undef STAGE_G

  const int rbase = (lane >> 4) * 4;
#pragma unroll
  for (int j = 0; j < 4; ++j) {
    const int col = bn + wcn + j * 16 + l15;
#pragma unroll
    for (int i = 0; i < 8; ++i)
#pragma unroll
      for (int r = 0; r < 4; ++r)
        Cq[(size_t)(bm + wr + i * 16 + rbase + r) * DIMV + col] = f2b(acc[i][j][r]);
  }
}

// ---------- fp8 MFMA GEMM (QK fused): 256x256 tile, BK=64, 8 waves, dbuf 2-phase ----------
// Operands pre-scaled x16 and pre-permuted; acc scaled by 1/256 in epilogue.
// cols<1024 -> Cq=bf16(v1); cols>=1024 -> Ck=bf16(v2)+v2sum atomics.
template <int NB>
__global__ __launch_bounds__(512, 2) void gemm_f8(const uchar_t* __restrict__ Xf8,
                                                  const uchar_t* __restrict__ Bt8,
                                                  const float* __restrict__ biasQ,
                                                  const float* __restrict__ biasK,
                                                  const float* __restrict__ denom,
                                                  const float* __restrict__ mask,
                                                  float* __restrict__ v2sum,
                                                  ushort_t* __restrict__ Cq,
                                                  ushort_t* __restrict__ Ck) {
  __shared__ uchar_t LB[65536];  // A: buf*16384, B: 32768 + buf*16384
  const int bid = blockIdx.x;
  const int nwg = NB * 64;
  const int swz = (bid & 7) * (nwg / 8) + (bid >> 3);
  const int bm = (swz / NB) * 256;
  const int bn = (swz % NB) * 256;
  const int t = threadIdx.x;
  const int w = t >> 6, lane = t & 63, l15 = lane & 15;
  const int wr = (w >> 2) * 128;
  const int wcn = (w & 3) * 64;
  const int g = lane >> 4;
  const int aoff = ((g ^ ((l15 >> 1) & 3)) << 4);  // swizzled granule byte offset

  const uchar_t *gA[2], *gB[2];
  int lofs[2];
#pragma unroll
  for (int c = 0; c < 2; ++c) {
    const int row = (t >> 2) + c * 128;
    lofs[c] = t * 16 + c * 8192;
    gA[c] = Xf8 + (size_t)(bm + row) * DIMV + (t & 3) * 16;
    gB[c] = Bt8 + (size_t)(bn + row) * DIMV + (t & 3) * 16;
  }

#define STAGE_F(buf, kb)                                         \
  do {                                                           \
    _Pragma("unroll") for (int c = 0; c < 2; ++c) {              \
      GLD16(gA[c] + (kb), &LB[(buf) * 16384 + lofs[c]]);         \
      GLD16(gB[c] + (kb), &LB[32768 + (buf) * 16384 + lofs[c]]); \
    }                                                            \
  } while (0)

  f32x4 acc[8][4];
#pragma unroll
  for (int i = 0; i < 8; ++i)
#pragma unroll
    for (int j = 0; j < 4; ++j) acc[i][j] = (f32x4){0.f, 0.f, 0.f, 0.f};

  STAGE_F(0, 0);
  __syncthreads();
  int cur = 0;
  for (int kt = 0; kt < 16; ++kt) {
    if (kt < 15) STAGE_F(cur ^ 1, (kt + 1) * 64);
    long2_t bf[4];
#pragma unroll
    for (int j = 0; j < 4; ++j)
      bf[j] = *(const long2_t*)&LB[32768 + cur * 16384 + (wcn + j * 16 + l15) * 64 + aoff];
#pragma unroll
    for (int i = 0; i < 8; ++i) {
      long2_t af = *(const long2_t*)&LB[cur * 16384 + (wr + i * 16 + l15) * 64 + aoff];
#pragma unroll
      for (int j = 0; j < 4; ++j) {
        acc[i][j] = __builtin_amdgcn_mfma_f32_16x16x32_fp8_fp8(af.x, bf[j].x, acc[i][j], 0, 0, 0);
        acc[i][j] = __builtin_amdgcn_mfma_f32_16x16x32_fp8_fp8(af.y, bf[j].y, acc[i][j], 0, 0, 0);
      }
    }
    __syncthreads();
    cur ^= 1;
  }
#undef STAGE_F

  // epilogue (acc scaled by 1/256). C/D layout: col=lane&15, row=(lane>>4)*4+r.
  const int rbase = (lane >> 4) * 4;
  const int h = ((bn + wcn) >> 6) & (NHEADS - 1);
  const bool isK = (bn >= DIMV);  // block-uniform
  int lc[4];
  float bb[4];
#pragma unroll
  for (int j = 0; j < 4; ++j) {
    lc[j] = (bn + wcn + j * 16 + l15) & (DIMV - 1);
    bb[j] = isK ? biasK[lc[j]] : biasQ[lc[j]];
  }
  float csum[4] = {0.f, 0.f, 0.f, 0.f};
#pragma unroll
  for (int i = 0; i < 8; ++i) {
#pragma unroll
    for (int r = 0; r < 4; ++r) {
      const int row = bm + wr + i * 16 + rbase + r;
      const float invdp = 1.0f / denom[(size_t)h * N_NODES + row];
      float den = 0.f, mk = 0.f;
      if (isK) {
        den = clampabs(2.0f * invdp - 1.0f, 1e-10f);
        mk = mask[row];
      }
#pragma unroll
      for (int j = 0; j < 4; ++j) {
        float val = elup1_fast((acc[i][j][r] * 0.00390625f + bb[j]) * invdp);
        if (isK) {
          val = den * val * mk;
          csum[j] += val;
          Ck[(size_t)row * DIMV + lc[j]] = f2b(val);
        } else {
          Cq[(size_t)row * DIMV + lc[j]] = f2b(val);
        }
      }
    }
  }
  if (isK) {
#pragma unroll
    for (int j = 0; j < 4; ++j) atomicAdd(&v2sum[lc[j]], csum[j]);
  }
}

// ---------- fp8 MFMA GEMM (V path): 128x256 tile, BK=64, 8 waves, dbuf 2-phase ----------
// grid 512 -> 2 blocks/CU (vs 256-tile's 1/CU): inter-block TLP hides the barrier drain.
// Wave tile 64x64 = acc[4][4]. LDS 48 KB: A 2x8KB, B 2x16KB. Same fp8 layout as gemm_f8.
// Epilogue: Cq = bf16(mx) + per-(row,head) stats {sum mx^2, sum relu(mx)^2}.
__global__ __launch_bounds__(512, 2) void gemm_f8v(const uchar_t* __restrict__ Xf8,
                                                   const uchar_t* __restrict__ Bt8,
                                                   float* __restrict__ mxhsq,
                                                   float* __restrict__ reluhsq,
                                                   ushort_t* __restrict__ Cq) {
  __shared__ uchar_t LB[49152];  // A: buf*8192 in [0,16K); B: 16384 + buf*16384
  const int bid = blockIdx.x;
  const int swz = (bid & 7) * 64 + (bid >> 3);  // nwg = 512
  const int bm = (swz >> 2) * 128;
  const int bn = (swz & 3) * 256;
  const int t = threadIdx.x;
  const int w = t >> 6, lane = t & 63, l15 = lane & 15;
  const int wr = (w >> 2) * 64;   // 2 M-groups of 64
  const int wcn = (w & 3) * 64;   // 4 N-groups of 64
  const int g = lane >> 4;
  const int aoff = ((g ^ ((l15 >> 1) & 3)) << 4);

  const uchar_t* gA = Xf8 + (size_t)(bm + (t >> 2)) * DIMV + (t & 3) * 16;
  const int lofsA = t * 16;
  const uchar_t* gB[2];
  int lofsB[2];
#pragma unroll
  for (int c = 0; c < 2; ++c) {
    gB[c] = Bt8 + (size_t)(bn + (t >> 2) + c * 128) * DIMV + (t & 3) * 16;
    lofsB[c] = t * 16 + c * 8192;
  }

#define STAGE_V(buf, kb)                                          \
  do {                                                            \
    GLD16(gA + (kb), &LB[(buf) * 8192 + lofsA]);                  \
    _Pragma("unroll") for (int c = 0; c < 2; ++c)                 \
        GLD16(gB[c] + (kb), &LB[16384 + (buf) * 16384 + lofsB[c]]); \
  } while (0)

  f32x4 acc[4][4];
#pragma unroll
  for (int i = 0; i < 4; ++i)
#pragma unroll
    for (int j = 0; j < 4; ++j) acc[i][j] = (f32x4){0.f, 0.f, 0.f, 0.f};

  STAGE_V(0, 0);
  __syncthreads();
  int cur = 0;
  for (int kt = 0; kt < 16; ++kt) {
    if (kt < 15) STAGE_V(cur ^ 1, (kt + 1) * 64);
    long2_t bf[4];
#pragma unroll
    for (int j = 0; j < 4; ++j)
      bf[j] = *(const long2_t*)&LB[16384 + cur * 16384 + (wcn + j * 16 + l15) * 64 + aoff];
#pragma unroll
    for (int i = 0; i < 4; ++i) {
      long2_t af = *(const long2_t*)&LB[cur * 8192 + (wr + i * 16 + l15) * 64 + aoff];
#pragma unroll
      for (int j = 0; j < 4; ++j) {
        acc[i][j] = __builtin_amdgcn_mfma_f32_16x16x32_fp8_fp8(af.x, bf[j].x, acc[i][j], 0, 0, 0);
        acc[i][j] = __builtin_amdgcn_mfma_f32_16x16x32_fp8_fp8(af.y, bf[j].y, acc[i][j], 0, 0, 0);
      }
    }
    __syncthreads();
    cur ^= 1;
  }
#undef STAGE_V

  // epilogue: bf16 store + per-(row,head) stats (each (row,head) owned by one wave).
  const int rbase = (lane >> 4) * 4;
  const int h = ((bn + wcn) >> 6) & (NHEADS - 1);
#pragma unroll
  for (int i = 0; i < 4; ++i) {
#pragma unroll
    for (int r = 0; r < 4; ++r) {
      const int row = bm + wr + i * 16 + rbase + r;
      float smx = 0.f, srel = 0.f;
#pragma unroll
      for (int j = 0; j < 4; ++j) {
        float val = acc[i][j][r] * 0.00390625f;
        Cq[(size_t)row * DIMV + bn + wcn + j * 16 + l15] = f2b(val);
        smx = fmaf(val, val, smx);
        float rv = fmaxf(val, 0.f);
        srel = fmaf(rv, rv, srel);
      }
      smx += __shfl_xor(smx, 1); smx += __shfl_xor(smx, 2);
      smx += __shfl_xor(smx, 4); smx += __shfl_xor(smx, 8);
      srel += __shfl_xor(srel, 1); srel += __shfl_xor(srel, 2);
      srel += __shfl_xor(srel, 4); srel += __shfl_xor(srel, 8);
      if (l15 == 0) {
        mxhsq[(size_t)h * N_NODES + row] = smx;
        reluhsq[(size_t)h * N_NODES + row] = srel;
      }
    }
  }
}

// ---------- vscale: per-row mobius+kappa scalars from stats; emits scaleV + denom ----------
__global__ __launch_bounds__(256) void vscale_kernel(const float* __restrict__ xnormsq,
                                                     const float* __restrict__ mxhsq,
                                                     const float* __restrict__ reluhsq,
                                                     float* __restrict__ scaleV,
                                                     float* __restrict__ denom) {
  const int row = blockIdx.x * 256 + threadIdx.x;
  float sm = 0.f, sr = 0.f;
  float hs[NHEADS];
#pragma unroll
  for (int h = 0; h < NHEADS; ++h) {
    sm += mxhsq[(size_t)h * N_NODES + row];
    hs[h] = reluhsq[(size_t)h * N_NODES + row];
    sr += hs[h];
  }
  float sx = xnormsq[row];
  float xn = fmaxf(sqrtf(sx), 1e-15f);
  float mxn = fmaxf(sqrtf(sm), 1e-15f);
  float cx = fminf(xn, 1.0f - 1e-7f);
  float t1 = tanhf(mxn / xn * atanhf(cx));
  float s1 = t1 / mxn;
  float yn = fmaxf(fabsf(t1), 1e-15f);
  float a = atanhf(fminf(yn, 1.0f - 1e-7f)) / yn;
  float k1 = a * s1;
  float un = fmaxf(k1 * sqrtf(sr), 1e-15f);
  float t2 = tanhf(un);
  float s2 = t2 / un;
  if (t2 > 0.996f) s2 *= 0.996f / t2;
  float sV = s2 * k1;
  scaleV[row] = sV;
#pragma unroll
  for (int h = 0; h < NHEADS; ++h)
    denom[(size_t)h * N_NODES + row] = fmaxf(1.0f - sV * sV * hs[h], 1e-15f);
}

// ---------- row transform (final): mobius_matvec tail + kappa_relu ----------
__global__ __launch_bounds__(256) void rowtrans_kernel(const ushort_t* __restrict__ msrc,
                                                       const float* __restrict__ rowsq,
                                                       float* __restrict__ dstv) {
  __shared__ float red[4];
  const int row = blockIdx.x;
  const int t = threadIdx.x;
  uint2 mraw = ((const uint2*)(msrc + (size_t)row * DIMV))[t];
  ushort_t* mh = (ushort_t*)&mraw;
  float4 m4 = make_float4(b2f(mh[0]), b2f(mh[1]), b2f(mh[2]), b2f(mh[3]));
  float sm = m4.x * m4.x + m4.y * m4.y + m4.z * m4.z + m4.w * m4.w;
  sm = blockReduceSum(sm, red);
  float sx = rowsq[row];

  float xn = fmaxf(sqrtf(sx), 1e-15f);
  float mxn = fmaxf(sqrtf(sm), 1e-15f);
  float cx = fminf(xn, 1.0f - 1e-7f);
  float t1 = tanhf(mxn / xn * atanhf(cx));
  float s1 = t1 / mxn;

  float yn = fmaxf(fabsf(t1), 1e-15f);
  float a = atanhf(fminf(yn, 1.0f - 1e-7f)) / yn;
  float k1 = a * s1;
  float4 u = make_float4(fmaxf(k1 * m4.x, 0.0f), fmaxf(k1 * m4.y, 0.0f),
                         fmaxf(k1 * m4.z, 0.0f), fmaxf(k1 * m4.w, 0.0f));
  float su = u.x * u.x + u.y * u.y + u.z * u.z + u.w * u.w;
  su = blockReduceSum(su, red);

  float un = fmaxf(sqrtf(su), 1e-15f);
  float t2 = tanhf(un);
  float s2 = t2 / un;
  if (t2 > 0.996f) s2 *= 0.996f / t2;
  float4 o = make_float4(s2 * u.x, s2 * u.y, s2 * u.z, s2 * u.w);
  ((float4*)(dstv + (size_t)row * DIMV))[t] = o;
}

// ---------- context (MFMA): ctxT[h][e][d] = sum_n v2[h,n,d]*(c1*relu(mx))[h,n,e] ----------
__global__ __launch_bounds__(256) void context_kernel(const ushort_t* __restrict__ v2buf,
                                                      const ushort_t* __restrict__ mxVbuf,
                                                      const float* __restrict__ scaleV,
                                                      const float* __restrict__ denom,
                                                      const float* __restrict__ mask,
                                                      float* __restrict__ ctxT) {
  __shared__ ushort_t s2T[64 * 64];  // [d][n-swz], 8 KB
  __shared__ ushort_t sxT[64 * 64];  // [e][n-swz], 8 KB
  const int h = blockIdx.y;
  const int t = threadIdx.x;
  const int w = t >> 6, lane = t & 63, l15 = lane & 15, g = lane >> 4;
  const int e7 = l15 & 7;
  const int uo0 = (g ^ e7) * 8;        // ks=0 swizzled unit offset (elems)
  const int uo1 = ((4 + g) ^ e7) * 8;  // ks=1

  f32x4 acc[4];
#pragma unroll
  for (int j = 0; j < 4; ++j) acc[j] = (f32x4){0.f, 0.f, 0.f, 0.f};

  const int rbase = blockIdx.x * 512;
  for (int c = 0; c < 8; ++c) {
#pragma unroll
    for (int i = 0; i < 4; ++i) {
      int f = i * 256 + t;
      int r = f >> 4;          // n within chunk (0..63)
      int cc = (f & 15) * 4;   // d/e base
      int row = rbase + c * 64 + r;
      uint2 araw = *(const uint2*)(v2buf + (size_t)row * DIMV + h * HEADD + cc);
      ushort_t* ah = (ushort_t*)&araw;
      float dp = denom[(size_t)h * N_NODES + row];
      float gamma = 2.0f / dp;
      float den = clampabs(gamma - 1.0f, 1e-10f);
      float c1 = gamma / den * mask[row] * scaleV[row];
      uint2 braw = *(const uint2*)(mxVbuf + (size_t)row * DIMV + h * HEADD + cc);
      ushort_t* bh = (ushort_t*)&braw;
      const int rhi = r >> 3, rlo = r & 7;
#pragma unroll
      for (int q = 0; q < 4; ++q) {
        const int d = cc + q;
        const int pos = d * 64 + ((rhi ^ (d & 7)) << 3) + rlo;
        s2T[pos] = ah[q];
        sxT[pos] = f2b(c1 * fmaxf(b2f(bh[q]), 0.f));
      }
    }
    __syncthreads();
#pragma unroll
    for (int ks = 0; ks < 2; ++ks) {
      const int uo = ks ? uo1 : uo0;
      short8 af = *(const short8*)&s2T[(w * 16 + l15) * 64 + uo];
#pragma unroll
      for (int j = 0; j < 4; ++j) {
        short8 bfv = *(const short8*)&sxT[(j * 16 + l15) * 64 + uo];
        acc[j] = __builtin_amdgcn_mfma_f32_16x16x32_bf16(af, bfv, acc[j], 0, 0, 0);
      }
    }
    __syncthreads();
  }
#pragma unroll
  for (int j = 0; j < 4; ++j)
#pragma unroll
    for (int r = 0; r < 4; ++r)
      atomicAdd(&ctxT[h * 4096 + (j * 16 + l15) * 64 + w * 16 + g * 4 + r], acc[j][r]);
}

// ---------- out (MFMA): [out|D] = v1 @ [ctx|v2sum]; tail; emit combHi + rownorm atomics ----------
__global__ __launch_bounds__(256) void out_mfma_kernel(const ushort_t* __restrict__ v1bf,
                                                       const float* __restrict__ v2sum,
                                                       const float* __restrict__ ctxT,
                                                       ushort_t* __restrict__ combHi,
                                                       float* __restrict__ combnorm) {
  __shared__ ushort_t Blds[80][88];
  const int h = blockIdx.y;
  const int bm = blockIdx.x * 256;
  const int t = threadIdx.x;
  const int w = t >> 6, lane = t & 63, l15 = lane & 15;
  const int kk = (lane >> 4) * 8;

  for (int idx = t; idx < 80 * 64; idx += 256) {
    int e = idx >> 6, d = idx & 63;
    float v = 0.0f;
    if (e < 64) v = ctxT[h * 4096 + e * 64 + d];
    else if (e == 64) v = v2sum[h * 64 + d];
    Blds[e][d] = f2b(v);
  }
  __syncthreads();

  f32x4 acc[4][5];
#pragma unroll
  for (int i = 0; i < 4; ++i)
#pragma unroll
    for (int j = 0; j < 5; ++j) acc[i][j] = (f32x4){0.f, 0.f, 0.f, 0.f};
#pragma unroll
  for (int ks = 0; ks < 2; ++ks) {
    short8 bfr[5];
#pragma unroll
    for (int j = 0; j < 5; ++j) bfr[j] = *(const short8*)&Blds[j * 16 + l15][ks * 32 + kk];
#pragma unroll
    for (int i = 0; i < 4; ++i) {
      short8 af = *(const short8*)(v1bf + (size_t)(bm + w * 64 + i * 16 + l15) * DIMV +
                                   h * HEADD + ks * 32 + kk);
#pragma unroll
      for (int j = 0; j < 5; ++j)
        acc[i][j] = __builtin_amdgcn_mfma_f32_16x16x32_bf16(af, bfr[j], acc[i][j], 0, 0, 0);
    }
  }

  const int g4 = (lane >> 4) * 4;
#pragma unroll
  for (int i = 0; i < 4; ++i) {
#pragma unroll
    for (int r = 0; r < 4; ++r) {
      const int row = bm + w * 64 + i * 16 + g4 + r;
      float D = __shfl(acc[i][4][r], lane & 48);
      float Dinv = 1.0f / (D == 0.0f ? 1e-5f : D);
      float o[4];
      float s = 0.0f;
#pragma unroll
      for (int j = 0; j < 4; ++j) {
        o[j] = acc[i][j][r] * Dinv;
        s = fmaf(o[j], o[j], s);
      }
      s += __shfl_xor(s, 1); s += __shfl_xor(s, 2);
      s += __shfl_xor(s, 4); s += __shfl_xor(s, 8);
      float n1 = fmaxf(sqrtf(s), 1e-15f);
      float sc = 1.0f;
      if (n1 > 0.996f) sc = 0.996f / n1;
      float xn = fmaxf(fminf(n1, 0.996f), 1e-15f);
      float cx = fminf(xn, 1.0f - 1e-7f);
      // tanh(0.5*atanh(cx)) == cx / (1 + sqrt(1 - cx^2)); t2 <= 0.915 -> no reprojection.
      float t2 = cx / (1.0f + sqrtf(1.0f - cx * cx));
      sc *= t2 / xn;
      if (l15 == 0) atomicAdd(&combnorm[row], s * sc * sc);
#pragma unroll
      for (int j = 0; j < 4; ++j) {
        float ov = o[j] * sc;
        combHi[(size_t)row * DIMV + h * HEADD + j * 16 + l15] = f2b(ov);
      }
    }
  }
}

// ---------- launch ----------

extern "C" void kernel_launch(void* const* d_in, const int* in_sizes, int n_in,
                              void* d_out, int out_size, void* d_ws, size_t ws_size,
                              hipStream_t stream) {
  const float* X = (const float*)d_in[0];
  const float* mask = (const float*)d_in[1];
  const float* Wq = (const float*)d_in[2];
  const float* bq = (const float*)d_in[3];
  const float* Wk = (const float*)d_in[4];
  const float* bk = (const float*)d_in[5];
  const float* Wv = (const float*)d_in[6];
  const float* Wff = (const float*)d_in[7];
  float* out = (float*)d_out;

  const size_t MAT = (size_t)N_NODES * DIMV;
  char* p = (char*)d_ws;
  // R1 (64MB): first half v1bf (QK epi out); second half mxV bf16, later combnorm
  ushort_t* v1bf = (ushort_t*)p;
  ushort_t* mxV = (ushort_t*)(p + MAT * 2);
  float* combnorm = (float*)(p + MAT * 2);
  p += MAT * 4;
  // R2 (64MB): xnormsq (early) / v2bf (QK epi out)
  float* xnormsq = (float*)p;
  ushort_t* v2bf = (ushort_t*)p;
  p += MAT * 4;
  // R3 (32MB): combHi (out_mfma out)
  ushort_t* combHi = (ushort_t*)p;
  p += MAT * 2;
  // R4 (32MB): outBf (final gemm out)
  ushort_t* outBf = (ushort_t*)p;
  p += MAT * 2;
  float* denom = (float*)p;   p += (size_t)NHEADS * N_NODES * 4;
  float* v2sum = (float*)p;   p += 1024 * 4;
  float* ctxT = (float*)p;    p += (size_t)NHEADS * 4096 * 4;
  float* mxhsq = (float*)p;   p += (size_t)NHEADS * N_NODES * 4;
  float* reluhsq = (float*)p; p += (size_t)NHEADS * N_NODES * 4;
  float* scaleV = (float*)p;  p += (size_t)N_NODES * 4;
  const size_t need = (size_t)(p - (char*)d_ws);
  if (ws_size < need) return;

  // scratch inside d_out (64MB; all consumed before the final rowtrans writes it):
  uchar_t* Wq8 = (uchar_t*)d_out;                        // [0,1M) fp8 Wq^T (16x, permuted)
  uchar_t* Wk8 = Wq8 + (size_t)DIMV * DIMV;              // [1M,2M) fp8 Wk^T (stacked QK rows)
  uchar_t* Wv8 = Wk8 + (size_t)DIMV * DIMV;              // [2M,3M) fp8 Wv^T
  ushort_t* WffT = (ushort_t*)(Wv8 + (size_t)DIMV * DIMV);  // [3M,5M) bf16 Wff^T
  uchar_t* Xf8 = (uchar_t*)d_out + 8 * 1024 * 1024;      // [8M,24M) fp8 X (16x, permuted)

  cvt_norm_kernel<<<N_NODES, 256, 0, stream>>>(X, Xf8, xnormsq);
  transW4_kernel<<<dim3(32, 32, 4), 256, 0, stream>>>(Wq, Wk, Wv, Wff, Wq8, Wk8, Wv8, WffT);
  // V path (fp8, 128x256 tile -> 512 blocks = 2/CU): mx bf16 + stats; then scaleV + denom
  gemm_f8v<<<512, 512, 0, stream>>>(Xf8, Wv8, mxhsq, reluhsq, mxV);
  vscale_kernel<<<N_NODES / 256, 256, 0, stream>>>(xnormsq, mxhsq, reluhsq, scaleV, denom);
  // zero v2sum + ctxT (contiguous)
  hipMemsetAsync(v2sum, 0, (1024 + 4096 * NHEADS) * sizeof(float), stream);
  // QK fused (fp8): stacked [Wq8;Wk8]; emits v1 (cols<1024) and v2 + v2sum (cols>=1024)
  gemm_f8<8><<<512, 512, 0, stream>>>(Xf8, Wq8, bq, bk, denom, mask, v2sum, v1bf, v2bf);
  // context (MFMA; reads mxV with inline sV*relu)
  context_kernel<<<dim3(32, NHEADS), 256, 0, stream>>>(v2bf, mxV, scaleV, denom, mask, ctxT);
  // combnorm aliases mxV: zero only after context consumed mxV
  hipMemsetAsync(combnorm, 0, N_NODES * sizeof(float), stream);
  // attention out -> combHi + row norms
  out_mfma_kernel<<<dim3(N_NODES / 256, NHEADS), 256, 0, stream>>>(v1bf, v2sum, ctxT, combHi,
                                                                   combnorm);
  // final: single bf16 GEMM comb@Wff -> outBf, then rowtrans -> d_out
  gemm_bf<4><<<256, 512, 0, stream>>>(combHi, WffT, outBf);
  rowtrans_kernel<<<N_NODES, 256, 0, stream>>>(outBf, combnorm, out);
}